// Round 1
// baseline (1287.558 us; speedup 1.0000x reference)
//
#include <hip/hip_runtime.h>
#include <hip/hip_bf16.h>
#include <math.h>

#define DM 1024
#define DI 2048
#define DS 16
#define DTR 64
#define NB 2
#define LL 1024
#define MM (NB*LL)   // 2048

__device__ __forceinline__ float sigmoidf_(float x){ return 1.f/(1.f+__expf(-x)); }
__device__ __forceinline__ float siluf_(float x){ return x*sigmoidf_(x); }
__device__ __forceinline__ float softplusf_(float x){ return fmaxf(x,0.f)+log1pf(__expf(-fabsf(x))); }

// Generic guarded fp32 GEMM: C[M x N] = A[M x K] * B[K x N]
// EPI==1: C = softplus(acc + bias[col])
// M is always a multiple of 64, K a multiple of 16. N may be ragged (guarded).
template<int EPI>
__global__ __launch_bounds__(256) void gemm_f32_kern(
    const float* __restrict__ A, int lda,
    const float* __restrict__ B, int ldb,
    float* __restrict__ C, int ldc,
    int N, int K,
    const float* __restrict__ bias)
{
  __shared__ __align__(16) float As[16][64];
  __shared__ __align__(16) float Bs[16][68];
  const int tid  = threadIdx.x;
  const int bm   = blockIdx.y * 64;
  const int bn   = blockIdx.x * 64;
  const int arow = tid >> 2;          // 0..63
  const int acol = (tid & 3) << 2;    // 0,4,8,12
  const int brow = tid >> 4;          // 0..15
  const int bcol = (tid & 15) << 2;   // 0..60
  const int tr   = (tid >> 4) << 2;   // acc row base 0..60
  const int tc   = (tid & 15) << 2;   // acc col base 0..60
  float acc[4][4] = {{0.f,0.f,0.f,0.f},{0.f,0.f,0.f,0.f},
                     {0.f,0.f,0.f,0.f},{0.f,0.f,0.f,0.f}};
  for (int k0 = 0; k0 < K; k0 += 16) {
    float4 av = *(const float4*)(A + (size_t)(bm + arow) * lda + (k0 + acol));
    As[acol+0][arow] = av.x;
    As[acol+1][arow] = av.y;
    As[acol+2][arow] = av.z;
    As[acol+3][arow] = av.w;
    const int bc = bn + bcol;
    float4 bv = make_float4(0.f,0.f,0.f,0.f);
    const float* bp = B + (size_t)(k0 + brow) * ldb;
    if (bc + 3 < N) {
      bv = *(const float4*)(bp + bc);
    } else {
      if (bc+0 < N) bv.x = bp[bc+0];
      if (bc+1 < N) bv.y = bp[bc+1];
      if (bc+2 < N) bv.z = bp[bc+2];
      if (bc+3 < N) bv.w = bp[bc+3];
    }
    *(float4*)&Bs[brow][bcol] = bv;
    __syncthreads();
    #pragma unroll
    for (int k = 0; k < 16; ++k) {
      float4 a4 = *(const float4*)&As[k][tr];
      float4 b4 = *(const float4*)&Bs[k][tc];
      float a_[4] = {a4.x,a4.y,a4.z,a4.w};
      float b_[4] = {b4.x,b4.y,b4.z,b4.w};
      #pragma unroll
      for (int i=0;i<4;i++)
        #pragma unroll
        for (int j=0;j<4;j++)
          acc[i][j] = fmaf(a_[i], b_[j], acc[i][j]);
    }
    __syncthreads();
  }
  #pragma unroll
  for (int i=0;i<4;i++){
    const int row = bm + tr + i;
    #pragma unroll
    for (int j=0;j<4;j++){
      const int col = bn + tc + j;
      if (col < N) {
        float v = acc[i][j];
        if (EPI == 1) v = softplusf_(v + bias[col]);
        C[(size_t)row*ldc + col] = v;
      }
    }
  }
}

// Causal depthwise conv (D_CONV=4) + SiLU. xb lives in xz cols [0,DI).
__global__ __launch_bounds__(256) void conv_silu_kern(
    const float* __restrict__ xz, const float* __restrict__ conv_w,
    const float* __restrict__ conv_b, float* __restrict__ u)
{
  const int idx = blockIdx.x * 256 + threadIdx.x;   // over MM*DI
  const int d  = idx & (DI-1);
  const int ml = idx >> 11;          // DI = 2048 = 2^11
  const int l  = ml & (LL-1);
  const int base = ml - l;           // b*L
  const float4 w4 = *(const float4*)(conv_w + d*4);
  const float wv[4] = {w4.x, w4.y, w4.z, w4.w};
  float acc = conv_b[d];
  #pragma unroll
  for (int j = 0; j < 4; ++j) {
    const int ls = l - 3 + j;
    if (ls >= 0) acc = fmaf(xz[(size_t)(base + ls)*(2*DI) + d], wv[j], acc);
  }
  u[idx] = siluf_(acc);
}

// Selective scan: one 16-lane group per (b,d) chain; n = state index in lane.
// y is written IN-PLACE over the delta buffer (same (b,l,d) element: read
// happens before the lane-0 store within the same wave iteration -> safe).
__global__ __launch_bounds__(256) void scan_kern(
    const float* __restrict__ delta, const float* __restrict__ u,
    const float* __restrict__ params, const float* __restrict__ xz,
    const float* __restrict__ A_log, const float* __restrict__ D_param,
    float* __restrict__ y)
{
  const int tid = threadIdx.x;
  const int g = tid >> 4;            // group within block (16 groups)
  const int n = tid & 15;            // state index
  const int gb = blockIdx.x;         // 256 blocks
  const int b = gb >> 7;             // 128 blocks per batch
  const int d = ((gb & 127) << 4) + g;
  const float a_n = -expf(A_log[d*DS + n]);
  const float Dp  = D_param[d];
  const float* dl = delta + (size_t)b*LL*DI + d;
  const float* uu = u     + (size_t)b*LL*DI + d;
  const float* pr = params + (size_t)b*LL*96;
  const float* zp = xz + (size_t)b*LL*(2*DI) + DI + d;   // zb
  float* yo = y + (size_t)b*LL*DI + d;
  float s = 0.f;
  for (int l = 0; l < LL; ++l) {
    const float dt = dl[(size_t)l*DI];
    const float ut = uu[(size_t)l*DI];
    const float Bt = pr[l*96 + DTR + n];
    const float Ct = pr[l*96 + DTR + DS + n];
    const float da = __expf(dt * a_n);
    s = fmaf(da, s, dt * ut * Bt);
    float part = s * Ct;
    part += __shfl_xor(part, 1);
    part += __shfl_xor(part, 2);
    part += __shfl_xor(part, 4);
    part += __shfl_xor(part, 8);
    if (n == 0) {
      const float z = zp[(size_t)l*(2*DI)];
      yo[(size_t)l*DI] = (part + Dp*ut) * siluf_(z);
    }
  }
}

extern "C" void kernel_launch(void* const* d_in, const int* in_sizes, int n_in,
                              void* d_out, int out_size, void* d_ws, size_t ws_size,
                              hipStream_t stream)
{
  const float* x      = (const float*)d_in[0];
  const float* W_in   = (const float*)d_in[1];
  const float* conv_w = (const float*)d_in[2];
  const float* conv_b = (const float*)d_in[3];
  const float* W_x    = (const float*)d_in[4];
  const float* W_dt   = (const float*)d_in[5];
  const float* b_dt   = (const float*)d_in[6];
  const float* W_out  = (const float*)d_in[7];
  const float* A_log  = (const float*)d_in[8];
  const float* D_par  = (const float*)d_in[9];
  float* out = (float*)d_out;

  float* xz     = (float*)d_ws;             // MM * 4096   (xb | zb)
  float* u      = xz + (size_t)MM*2*DI;     // MM * DI
  float* params = u  + (size_t)MM*DI;       // MM * 96
  float* delta  = params + (size_t)MM*96;   // MM * DI  (y written in-place)

  dim3 blk(256);
  // G1: xz = x @ W_in            [2048 x 4096, K=1024]
  gemm_f32_kern<0><<<dim3(64, 32), blk, 0, stream>>>(x, DM, W_in, 2*DI, xz, 2*DI, 2*DI, DM, nullptr);
  // conv + silu -> u             [2048 x 2048]
  conv_silu_kern<<<(MM*DI)/256, blk, 0, stream>>>(xz, conv_w, conv_b, u);
  // G2: params = u @ W_x         [2048 x 96, K=2048]
  gemm_f32_kern<0><<<dim3(2, 32), blk, 0, stream>>>(u, DI, W_x, 96, params, 96, 96, DI, nullptr);
  // G3: delta = softplus(dlt @ W_dt + b_dt)   [2048 x 2048, K=64]
  gemm_f32_kern<1><<<dim3(32, 32), blk, 0, stream>>>(params, 96, W_dt, DI, delta, DI, DI, DTR, b_dt);
  // scan -> y (in-place over delta)
  scan_kern<<<256, blk, 0, stream>>>(delta, u, params, xz, A_log, D_par, delta);
  // G4: out = y @ W_out          [2048 x 1024, K=2048]
  gemm_f32_kern<0><<<dim3(16, 32), blk, 0, stream>>>(delta, DI, W_out, DM, out, DM, DM, DI, nullptr);
}

// Round 2
// 696.177 us; speedup vs baseline: 1.8495x; 1.8495x over previous
//
#include <hip/hip_runtime.h>
#include <hip/hip_bf16.h>
#include <math.h>

#define DM 1024
#define DI 2048
#define DS 16
#define DTR 64
#define NB 2
#define LL 1024
#define MM (NB*LL)   // 2048
#define NC 8         // scan chunks
#define CL (LL/NC)   // 128

__device__ __forceinline__ float sigmoidf_(float x){ return 1.f/(1.f+__expf(-x)); }
__device__ __forceinline__ float siluf_(float x){ return x*sigmoidf_(x); }
__device__ __forceinline__ float softplusf_(float x){ return fmaxf(x,0.f)+log1pf(__expf(-fabsf(x))); }

// Generic guarded fp32 GEMM: C[M x N] = A[M x K] * B[K x N]
// EPI==1: C = softplus(acc + bias[col])
template<int EPI>
__global__ __launch_bounds__(256) void gemm_f32_kern(
    const float* __restrict__ A, int lda,
    const float* __restrict__ B, int ldb,
    float* __restrict__ C, int ldc,
    int N, int K,
    const float* __restrict__ bias)
{
  __shared__ __align__(16) float As[16][64];
  __shared__ __align__(16) float Bs[16][68];
  const int tid  = threadIdx.x;
  const int bm   = blockIdx.y * 64;
  const int bn   = blockIdx.x * 64;
  const int arow = tid >> 2;
  const int acol = (tid & 3) << 2;
  const int brow = tid >> 4;
  const int bcol = (tid & 15) << 2;
  const int tr   = (tid >> 4) << 2;
  const int tc   = (tid & 15) << 2;
  float acc[4][4] = {{0.f,0.f,0.f,0.f},{0.f,0.f,0.f,0.f},
                     {0.f,0.f,0.f,0.f},{0.f,0.f,0.f,0.f}};
  for (int k0 = 0; k0 < K; k0 += 16) {
    float4 av = *(const float4*)(A + (size_t)(bm + arow) * lda + (k0 + acol));
    As[acol+0][arow] = av.x;
    As[acol+1][arow] = av.y;
    As[acol+2][arow] = av.z;
    As[acol+3][arow] = av.w;
    const int bc = bn + bcol;
    float4 bv = make_float4(0.f,0.f,0.f,0.f);
    const float* bp = B + (size_t)(k0 + brow) * ldb;
    if (bc + 3 < N) {
      bv = *(const float4*)(bp + bc);
    } else {
      if (bc+0 < N) bv.x = bp[bc+0];
      if (bc+1 < N) bv.y = bp[bc+1];
      if (bc+2 < N) bv.z = bp[bc+2];
      if (bc+3 < N) bv.w = bp[bc+3];
    }
    *(float4*)&Bs[brow][bcol] = bv;
    __syncthreads();
    #pragma unroll
    for (int k = 0; k < 16; ++k) {
      float4 a4 = *(const float4*)&As[k][tr];
      float4 b4 = *(const float4*)&Bs[k][tc];
      float a_[4] = {a4.x,a4.y,a4.z,a4.w};
      float b_[4] = {b4.x,b4.y,b4.z,b4.w};
      #pragma unroll
      for (int i=0;i<4;i++)
        #pragma unroll
        for (int j=0;j<4;j++)
          acc[i][j] = fmaf(a_[i], b_[j], acc[i][j]);
    }
    __syncthreads();
  }
  #pragma unroll
  for (int i=0;i<4;i++){
    const int row = bm + tr + i;
    #pragma unroll
    for (int j=0;j<4;j++){
      const int col = bn + tc + j;
      if (col < N) {
        float v = acc[i][j];
        if (EPI == 1) v = softplusf_(v + bias[col]);
        C[(size_t)row*ldc + col] = v;
      }
    }
  }
}

// Causal depthwise conv (D_CONV=4) + SiLU. xb lives in xz cols [0,DI).
__global__ __launch_bounds__(256) void conv_silu_kern(
    const float* __restrict__ xz, const float* __restrict__ conv_w,
    const float* __restrict__ conv_b, float* __restrict__ u)
{
  const int idx = blockIdx.x * 256 + threadIdx.x;   // over MM*DI
  const int d  = idx & (DI-1);
  const int ml = idx >> 11;
  const int l  = ml & (LL-1);
  const int base = ml - l;
  const float4 w4 = *(const float4*)(conv_w + d*4);
  const float wv[4] = {w4.x, w4.y, w4.z, w4.w};
  float acc = conv_b[d];
  #pragma unroll
  for (int j = 0; j < 4; ++j) {
    const int ls = l - 3 + j;
    if (ls >= 0) acc = fmaf(xz[(size_t)(base + ls)*(2*DI) + d], wv[j], acc);
  }
  u[idx] = siluf_(acc);
}

// ---- chunk-parallel selective scan ----
// group (16 lanes) = one (b, chunk c, channel d); lane = state index n.

// Pass A: local scan from s=0 -> per-chunk decay product P and final state F.
__global__ __launch_bounds__(256) void scan_local_kern(
    const float* __restrict__ delta, const float* __restrict__ u,
    const float* __restrict__ params, const float* __restrict__ A_log,
    float* __restrict__ Pc, float* __restrict__ Fc)
{
  const int tid = threadIdx.x;
  const int g = tid >> 4, n = tid & 15;
  const int gid = blockIdx.x * 16 + g;        // (b, c, d)
  const int d  = gid & (DI-1);
  const int bc = gid >> 11;
  const int c  = bc & (NC-1);
  const int b  = bc >> 3;
  const float a_n = -expf(A_log[d*DS + n]);
  const size_t lbase = (size_t)b*LL + (size_t)c*CL;
  const float* dl = delta + lbase*DI + d;
  const float* uu = u     + lbase*DI + d;
  const float* pr = params + lbase*96;
  float s = 0.f, dtsum = 0.f;
  #pragma unroll 4
  for (int l = 0; l < CL; ++l) {
    const float dt = dl[(size_t)l*DI];
    const float ut = uu[(size_t)l*DI];
    const float Bt = pr[l*96 + DTR + n];
    const float da = __expf(dt * a_n);
    dtsum += dt;
    s = fmaf(da, s, dt * ut * Bt);
  }
  const size_t pf = (((size_t)(b*DI + d))*NC + c)*DS + n;
  Pc[pf] = __expf(dtsum * a_n);
  Fc[pf] = s;
}

// Combine: per (b,d,n) sequential over the 8 chunks -> initial states.
__global__ __launch_bounds__(256) void scan_combine_kern(
    const float* __restrict__ Pc, const float* __restrict__ Fc,
    float* __restrict__ Sinit)
{
  const int idx = blockIdx.x * 256 + threadIdx.x;   // over NB*DI*DS
  const size_t base = (size_t)(idx >> 4) * (NC*DS) + (idx & 15);
  float s = 0.f;
  #pragma unroll
  for (int c = 0; c < NC; ++c) {
    Sinit[base + c*DS] = s;
    s = fmaf(Pc[base + c*DS], s, Fc[base + c*DS]);
  }
}

// Pass B: full scan per chunk from Sinit, fused C-reduce + D*u + silu(z) gate.
__global__ __launch_bounds__(256) void scan_apply_kern(
    const float* __restrict__ delta, const float* __restrict__ u,
    const float* __restrict__ params, const float* __restrict__ xz,
    const float* __restrict__ A_log, const float* __restrict__ D_param,
    const float* __restrict__ Sinit, float* __restrict__ y)
{
  const int tid = threadIdx.x;
  const int g = tid >> 4, n = tid & 15;
  const int gid = blockIdx.x * 16 + g;
  const int d  = gid & (DI-1);
  const int bc = gid >> 11;
  const int c  = bc & (NC-1);
  const int b  = bc >> 3;
  const float a_n = -expf(A_log[d*DS + n]);
  const float Dp  = D_param[d];
  const size_t lbase = (size_t)b*LL + (size_t)c*CL;
  const float* dl = delta + lbase*DI + d;
  const float* uu = u     + lbase*DI + d;
  const float* pr = params + lbase*96;
  const float* zp = xz + lbase*(2*DI) + DI + d;
  float* yo = y + lbase*DI + d;
  float s = Sinit[(((size_t)(b*DI + d))*NC + c)*DS + n];
  #pragma unroll 4
  for (int l = 0; l < CL; ++l) {
    const float dt = dl[(size_t)l*DI];
    const float ut = uu[(size_t)l*DI];
    const float Bt = pr[l*96 + DTR + n];
    const float Ct = pr[l*96 + DTR + DS + n];
    const float da = __expf(dt * a_n);
    s = fmaf(da, s, dt * ut * Bt);
    float part = s * Ct;
    part += __shfl_xor(part, 1);
    part += __shfl_xor(part, 2);
    part += __shfl_xor(part, 4);
    part += __shfl_xor(part, 8);
    if (n == 0) {
      const float z = zp[(size_t)l*(2*DI)];
      yo[(size_t)l*DI] = (part + Dp*ut) * siluf_(z);
    }
  }
}

extern "C" void kernel_launch(void* const* d_in, const int* in_sizes, int n_in,
                              void* d_out, int out_size, void* d_ws, size_t ws_size,
                              hipStream_t stream)
{
  const float* x      = (const float*)d_in[0];
  const float* W_in   = (const float*)d_in[1];
  const float* conv_w = (const float*)d_in[2];
  const float* conv_b = (const float*)d_in[3];
  const float* W_x    = (const float*)d_in[4];
  const float* W_dt   = (const float*)d_in[5];
  const float* b_dt   = (const float*)d_in[6];
  const float* W_out  = (const float*)d_in[7];
  const float* A_log  = (const float*)d_in[8];
  const float* D_par  = (const float*)d_in[9];
  float* out = (float*)d_out;

  float* xz     = (float*)d_ws;             // MM * 4096   (xb | zb)
  float* u      = xz + (size_t)MM*2*DI;     // MM * DI
  float* params = u  + (size_t)MM*DI;       // MM * 96
  float* delta  = params + (size_t)MM*96;   // MM * DI  (y written in-place)
  // chunk summaries staged in d_out (fully overwritten by final GEMM):
  const size_t PFN = (size_t)NB*DI*NC*DS;   // 524288 floats each
  float* Pc    = out;                        // 2 MB
  float* Fc    = out + PFN;                  // 2 MB
  float* Sinit = out + 2*PFN;                // 2 MB (of 8 MB total)

  dim3 blk(256);
  // G1: xz = x @ W_in            [2048 x 4096, K=1024]
  gemm_f32_kern<0><<<dim3(64, 32), blk, 0, stream>>>(x, DM, W_in, 2*DI, xz, 2*DI, 2*DI, DM, nullptr);
  // conv + silu -> u             [2048 x 2048]
  conv_silu_kern<<<(MM*DI)/256, blk, 0, stream>>>(xz, conv_w, conv_b, u);
  // G2: params = u @ W_x         [2048 x 96, K=2048]
  gemm_f32_kern<0><<<dim3(2, 32), blk, 0, stream>>>(u, DI, W_x, 96, params, 96, 96, DI, nullptr);
  // G3: delta = softplus(dlt @ W_dt + b_dt)   [2048 x 2048, K=64]
  gemm_f32_kern<1><<<dim3(32, 32), blk, 0, stream>>>(params, 96, W_dt, DI, delta, DI, DI, DTR, b_dt);
  // chunked scan
  scan_local_kern<<<(NB*NC*DI)/16, blk, 0, stream>>>(delta, u, params, A_log, Pc, Fc);
  scan_combine_kern<<<(NB*DI*DS)/256, blk, 0, stream>>>(Pc, Fc, Sinit);
  scan_apply_kern<<<(NB*NC*DI)/16, blk, 0, stream>>>(delta, u, params, xz, A_log, D_par, Sinit, delta);
  // G4: out = y @ W_out          [2048 x 1024, K=2048]
  gemm_f32_kern<0><<<dim3(16, 32), blk, 0, stream>>>(delta, DI, W_out, DM, out, DM, DM, DI, nullptr);
}

// Round 3
// 517.566 us; speedup vs baseline: 2.4877x; 1.3451x over previous
//
#include <hip/hip_runtime.h>
#include <hip/hip_bf16.h>
#include <math.h>

#define DM 1024
#define DI 2048
#define DS 16
#define DTR 64
#define NB 2
#define LL 1024
#define MM (NB*LL)   // 2048
#define NC 8         // scan chunks
#define CL (LL/NC)   // 128

typedef unsigned short u16;
typedef __bf16 bf16x8 __attribute__((ext_vector_type(8)));
typedef float f32x4 __attribute__((ext_vector_type(4)));

__device__ __forceinline__ float sigmoidf_(float x){ return 1.f/(1.f+__expf(-x)); }
__device__ __forceinline__ float siluf_(float x){ return x*sigmoidf_(x); }
__device__ __forceinline__ float softplusf_(float x){ return fmaxf(x,0.f)+log1pf(__expf(-fabsf(x))); }
__device__ __forceinline__ u16 f2b(float f){
  __hip_bfloat16 h = __float2bfloat16(f);
  return __builtin_bit_cast(unsigned short, h);
}

// ---------------- bf16 MFMA GEMM ----------------
// C[M][N] f32 = A[M][K]bf16 * Bt[N][K]bf16^T.  M,N mult of 128, K mult of 32.
// EPI==1: C = softplus(acc + bias[col])
template<int EPI>
__global__ __launch_bounds__(256) void gemm_bf16_kern(
    const u16* __restrict__ A, const u16* __restrict__ Bt,
    float* __restrict__ C, int M, int N, int K,
    const float* __restrict__ bias)
{
  constexpr int LDT = 40;                       // padded LDS stride (bf16)
  __shared__ __attribute__((aligned(16))) u16 As[128*LDT];
  __shared__ __attribute__((aligned(16))) u16 Bs[128*LDT];
  const unsigned tid = threadIdx.x;
  const unsigned l = tid & 63;
  const unsigned wave = tid >> 6;
  const unsigned wm = wave >> 1, wn = wave & 1; // 2x2 wave grid, 64x64 each
  const int bm = blockIdx.y * 128, bn = blockIdx.x * 128;
  const unsigned frow = l & 15, fk = (l >> 4) * 8;
  f32x4 acc[4][4] = {};
  for (int k0 = 0; k0 < K; k0 += 32) {
    int4 ra[2], rb[2];
    #pragma unroll
    for (int i = 0; i < 2; ++i) {
      const unsigned unit = tid*2 + i;
      const unsigned row = unit >> 2, seg = unit & 3;
      ra[i] = *(const int4*)(A  + (size_t)(bm+row)*K + k0 + seg*8);
      rb[i] = *(const int4*)(Bt + (size_t)(bn+row)*K + k0 + seg*8);
    }
    __syncthreads();     // previous iteration's ds_reads complete
    #pragma unroll
    for (int i = 0; i < 2; ++i) {
      const unsigned unit = tid*2 + i;
      const unsigned row = unit >> 2, seg = unit & 3;
      *(int4*)(As + row*LDT + seg*8) = ra[i];
      *(int4*)(Bs + row*LDT + seg*8) = rb[i];
    }
    __syncthreads();
    bf16x8 af[4], bfr[4];
    #pragma unroll
    for (int m = 0; m < 4; ++m)
      af[m] = *(const bf16x8*)(As + (wm*64 + m*16 + frow)*LDT + fk);
    #pragma unroll
    for (int n = 0; n < 4; ++n)
      bfr[n] = *(const bf16x8*)(Bs + (wn*64 + n*16 + frow)*LDT + fk);
    #pragma unroll
    for (int m = 0; m < 4; ++m)
      #pragma unroll
      for (int n = 0; n < 4; ++n)
        acc[m][n] = __builtin_amdgcn_mfma_f32_16x16x32_bf16(af[m], bfr[n], acc[m][n], 0, 0, 0);
  }
  // C/D layout (m89): col = l&15, row = (l>>4)*4 + q
  #pragma unroll
  for (int m = 0; m < 4; ++m) {
    #pragma unroll
    for (int n = 0; n < 4; ++n) {
      const int col = bn + wn*64 + n*16 + (l & 15);
      const float bs = (EPI == 1) ? bias[col] : 0.f;
      #pragma unroll
      for (int q = 0; q < 4; ++q) {
        const int row = bm + wm*64 + m*16 + (l >> 4)*4 + q;
        float v = acc[m][n][q];
        if (EPI == 1) v = softplusf_(v + bs);
        C[(size_t)row*N + col] = v;
      }
    }
  }
}

// transpose + convert: in [R][C] f32 -> out [C][R] bf16. grid(C/32, R/32).
__global__ __launch_bounds__(256) void transpose_cvt_kern(
    const float* __restrict__ in, u16* __restrict__ out, int R, int C)
{
  __shared__ float tile[32][33];
  const int r0 = blockIdx.y*32, c0 = blockIdx.x*32;
  const int tr = threadIdx.x >> 3, tc4 = (threadIdx.x & 7) * 4;
  float4 v = *(const float4*)(in + (size_t)(r0+tr)*C + c0 + tc4);
  tile[tr][tc4+0] = v.x; tile[tr][tc4+1] = v.y;
  tile[tr][tc4+2] = v.z; tile[tr][tc4+3] = v.w;
  __syncthreads();
  ushort4 o;
  o.x = f2b(tile[tc4+0][tr]);
  o.y = f2b(tile[tc4+1][tr]);
  o.z = f2b(tile[tc4+2][tr]);
  o.w = f2b(tile[tc4+3][tr]);
  *(ushort4*)(out + (size_t)(c0+tr)*R + r0 + tc4) = o;
}

// strided convert: out[row][0..C) bf16 = in[row*ld .. +C). C mult of 4.
__global__ __launch_bounds__(256) void cvt_bf16_kern(
    const float* __restrict__ in, int ld, int C, u16* __restrict__ out, int rows)
{
  const int i = blockIdx.x*256 + threadIdx.x;           // over rows*C/4
  if (i >= rows*(C/4)) return;
  const int row = i / (C/4);
  const int cq  = (i % (C/4)) * 4;
  float4 v = *(const float4*)(in + (size_t)row*ld + cq);
  ushort4 o; o.x=f2b(v.x); o.y=f2b(v.y); o.z=f2b(v.z); o.w=f2b(v.w);
  *(ushort4*)(out + (size_t)row*C + cq) = o;
}

// ---------------- fp32 GEMM (kept for G2, N=96) ----------------
template<int EPI>
__global__ __launch_bounds__(256) void gemm_f32_kern(
    const float* __restrict__ A, int lda,
    const float* __restrict__ B, int ldb,
    float* __restrict__ C, int ldc,
    int N, int K,
    const float* __restrict__ bias)
{
  __shared__ __align__(16) float As[16][64];
  __shared__ __align__(16) float Bs[16][68];
  const int tid  = threadIdx.x;
  const int bm   = blockIdx.y * 64;
  const int bn   = blockIdx.x * 64;
  const int arow = tid >> 2;
  const int acol = (tid & 3) << 2;
  const int brow = tid >> 4;
  const int bcol = (tid & 15) << 2;
  const int tr   = (tid >> 4) << 2;
  const int tc   = (tid & 15) << 2;
  float acc[4][4] = {{0.f,0.f,0.f,0.f},{0.f,0.f,0.f,0.f},
                     {0.f,0.f,0.f,0.f},{0.f,0.f,0.f,0.f}};
  for (int k0 = 0; k0 < K; k0 += 16) {
    float4 av = *(const float4*)(A + (size_t)(bm + arow) * lda + (k0 + acol));
    As[acol+0][arow] = av.x;
    As[acol+1][arow] = av.y;
    As[acol+2][arow] = av.z;
    As[acol+3][arow] = av.w;
    const int bc = bn + bcol;
    float4 bv = make_float4(0.f,0.f,0.f,0.f);
    const float* bp = B + (size_t)(k0 + brow) * ldb;
    if (bc + 3 < N) {
      bv = *(const float4*)(bp + bc);
    } else {
      if (bc+0 < N) bv.x = bp[bc+0];
      if (bc+1 < N) bv.y = bp[bc+1];
      if (bc+2 < N) bv.z = bp[bc+2];
      if (bc+3 < N) bv.w = bp[bc+3];
    }
    *(float4*)&Bs[brow][bcol] = bv;
    __syncthreads();
    #pragma unroll
    for (int k = 0; k < 16; ++k) {
      float4 a4 = *(const float4*)&As[k][tr];
      float4 b4 = *(const float4*)&Bs[k][tc];
      float a_[4] = {a4.x,a4.y,a4.z,a4.w};
      float b_[4] = {b4.x,b4.y,b4.z,b4.w};
      #pragma unroll
      for (int i=0;i<4;i++)
        #pragma unroll
        for (int j=0;j<4;j++)
          acc[i][j] = fmaf(a_[i], b_[j], acc[i][j]);
    }
    __syncthreads();
  }
  #pragma unroll
  for (int i=0;i<4;i++){
    const int row = bm + tr + i;
    #pragma unroll
    for (int j=0;j<4;j++){
      const int col = bn + tc + j;
      if (col < N) {
        float v = acc[i][j];
        if (EPI == 1) v = softplusf_(v + bias[col]);
        C[(size_t)row*ldc + col] = v;
      }
    }
  }
}

// Causal depthwise conv (D_CONV=4) + SiLU.
__global__ __launch_bounds__(256) void conv_silu_kern(
    const float* __restrict__ xz, const float* __restrict__ conv_w,
    const float* __restrict__ conv_b, float* __restrict__ u)
{
  const int idx = blockIdx.x * 256 + threadIdx.x;   // over MM*DI
  const int d  = idx & (DI-1);
  const int ml = idx >> 11;
  const int l  = ml & (LL-1);
  const int base = ml - l;
  const float4 w4 = *(const float4*)(conv_w + d*4);
  const float wv[4] = {w4.x, w4.y, w4.z, w4.w};
  float acc = conv_b[d];
  #pragma unroll
  for (int j = 0; j < 4; ++j) {
    const int ls = l - 3 + j;
    if (ls >= 0) acc = fmaf(xz[(size_t)(base + ls)*(2*DI) + d], wv[j], acc);
  }
  u[idx] = siluf_(acc);
}

// ---- chunk-parallel selective scan ----
__global__ __launch_bounds__(256) void scan_local_kern(
    const float* __restrict__ delta, const float* __restrict__ u,
    const float* __restrict__ params, const float* __restrict__ A_log,
    float* __restrict__ Pc, float* __restrict__ Fc)
{
  const int tid = threadIdx.x;
  const int g = tid >> 4, n = tid & 15;
  const int gid = blockIdx.x * 16 + g;
  const int d  = gid & (DI-1);
  const int bc = gid >> 11;
  const int c  = bc & (NC-1);
  const int b  = bc >> 3;
  const float a_n = -expf(A_log[d*DS + n]);
  const size_t lbase = (size_t)b*LL + (size_t)c*CL;
  const float* dl = delta + lbase*DI + d;
  const float* uu = u     + lbase*DI + d;
  const float* pr = params + lbase*96;
  float s = 0.f, dtsum = 0.f;
  #pragma unroll 4
  for (int l = 0; l < CL; ++l) {
    const float dt = dl[(size_t)l*DI];
    const float ut = uu[(size_t)l*DI];
    const float Bt = pr[l*96 + DTR + n];
    const float da = __expf(dt * a_n);
    dtsum += dt;
    s = fmaf(da, s, dt * ut * Bt);
  }
  const size_t pf = (((size_t)(b*DI + d))*NC + c)*DS + n;
  Pc[pf] = __expf(dtsum * a_n);
  Fc[pf] = s;
}

__global__ __launch_bounds__(256) void scan_combine_kern(
    const float* __restrict__ Pc, const float* __restrict__ Fc,
    float* __restrict__ Sinit)
{
  const int idx = blockIdx.x * 256 + threadIdx.x;   // over NB*DI*DS
  const size_t base = (size_t)(idx >> 4) * (NC*DS) + (idx & 15);
  float s = 0.f;
  #pragma unroll
  for (int c = 0; c < NC; ++c) {
    Sinit[base + c*DS] = s;
    s = fmaf(Pc[base + c*DS], s, Fc[base + c*DS]);
  }
}

__global__ __launch_bounds__(256) void scan_apply_kern(
    const float* __restrict__ delta, const float* __restrict__ u,
    const float* __restrict__ params, const float* __restrict__ xz,
    const float* __restrict__ A_log, const float* __restrict__ D_param,
    const float* __restrict__ Sinit, float* __restrict__ y)
{
  const int tid = threadIdx.x;
  const int g = tid >> 4, n = tid & 15;
  const int gid = blockIdx.x * 16 + g;
  const int d  = gid & (DI-1);
  const int bc = gid >> 11;
  const int c  = bc & (NC-1);
  const int b  = bc >> 3;
  const float a_n = -expf(A_log[d*DS + n]);
  const float Dp  = D_param[d];
  const size_t lbase = (size_t)b*LL + (size_t)c*CL;
  const float* dl = delta + lbase*DI + d;
  const float* uu = u     + lbase*DI + d;
  const float* pr = params + lbase*96;
  const float* zp = xz + lbase*(2*DI) + DI + d;
  float* yo = y + lbase*DI + d;
  float s = Sinit[(((size_t)(b*DI + d))*NC + c)*DS + n];
  #pragma unroll 4
  for (int l = 0; l < CL; ++l) {
    const float dt = dl[(size_t)l*DI];
    const float ut = uu[(size_t)l*DI];
    const float Bt = pr[l*96 + DTR + n];
    const float Ct = pr[l*96 + DTR + DS + n];
    const float da = __expf(dt * a_n);
    s = fmaf(da, s, dt * ut * Bt);
    float part = s * Ct;
    part += __shfl_xor(part, 1);
    part += __shfl_xor(part, 2);
    part += __shfl_xor(part, 4);
    part += __shfl_xor(part, 8);
    if (n == 0) {
      const float z = zp[(size_t)l*(2*DI)];
      yo[(size_t)l*DI] = (part + Dp*ut) * siluf_(z);
    }
  }
}

extern "C" void kernel_launch(void* const* d_in, const int* in_sizes, int n_in,
                              void* d_out, int out_size, void* d_ws, size_t ws_size,
                              hipStream_t stream)
{
  const float* x      = (const float*)d_in[0];
  const float* W_in   = (const float*)d_in[1];
  const float* conv_w = (const float*)d_in[2];
  const float* conv_b = (const float*)d_in[3];
  const float* W_x    = (const float*)d_in[4];
  const float* W_dt   = (const float*)d_in[5];
  const float* b_dt   = (const float*)d_in[6];
  const float* W_out  = (const float*)d_in[7];
  const float* A_log  = (const float*)d_in[8];
  const float* D_par  = (const float*)d_in[9];
  float* out = (float*)d_out;

  float* xz     = (float*)d_ws;             // MM*4096 f32 (32MB)
  float* u      = xz + (size_t)MM*2*DI;     // MM*DI f32 (16MB)
  float* params = u  + (size_t)MM*DI;       // MM*96 f32
  float* delta  = params + (size_t)MM*96;   // MM*DI f32 (16MB; y in-place)
  u16*  pool    = (u16*)(delta + (size_t)MM*DI);
  // G1 phase:
  u16* xb16 = pool;                          // 2048*1024 (4MB)
  u16* Wi_t = (u16*)out;                     // 4096*1024 bf16 = 8MB, in d_out
  // post-G1 phase (reuses pool):
  u16* Wd_t   = pool;                        // 2048*64
  u16* dltb16 = pool + (size_t)DI*DTR;       // 2048*64
  u16* Wo_t   = pool + (size_t)2*DI*DTR;     // 1024*2048 (4MB)
  u16* yb16   = (u16*)xz;                    // 2048*2048 bf16 (xz dead by then)
  // scan summaries in d_out (after G1, before final GEMM):
  const size_t PFN = (size_t)NB*DI*NC*DS;
  float* Pc    = out;
  float* Fc    = out + PFN;
  float* Sinit = out + 2*PFN;

  dim3 blk(256);
  // convert x -> bf16; transpose-convert W_in -> [4096][1024] bf16 (in d_out)
  cvt_bf16_kern<<<(MM*DM/4 + 255)/256, blk, 0, stream>>>(x, DM, DM, xb16, MM);
  transpose_cvt_kern<<<dim3(2*DI/32, DM/32), blk, 0, stream>>>(W_in, Wi_t, DM, 2*DI);
  // G1: xz = x @ W_in   [2048 x 4096, K=1024]  (MFMA)
  gemm_bf16_kern<0><<<dim3(2*DI/128, MM/128), blk, 0, stream>>>(xb16, Wi_t, xz, MM, 2*DI, DM, nullptr);
  // conv + silu -> u
  conv_silu_kern<<<(MM*DI)/256, blk, 0, stream>>>(xz, conv_w, conv_b, u);
  // G2: params = u @ W_x  [2048 x 96, K=2048]  (fp32, accuracy-critical B/C)
  gemm_f32_kern<0><<<dim3(2, 32), blk, 0, stream>>>(u, DI, W_x, 96, params, 96, 96, DI, nullptr);
  // G3: delta = softplus(dlt @ W_dt + b_dt)  [2048 x 2048, K=64]  (MFMA)
  cvt_bf16_kern<<<(MM*DTR/4 + 255)/256, blk, 0, stream>>>(params, 96, DTR, dltb16, MM);
  transpose_cvt_kern<<<dim3(DI/32, DTR/32), blk, 0, stream>>>(W_dt, Wd_t, DTR, DI);
  gemm_bf16_kern<1><<<dim3(DI/128, MM/128), blk, 0, stream>>>(dltb16, Wd_t, delta, MM, DI, DTR, b_dt);
  // chunked scan (y in-place over delta)
  scan_local_kern<<<(NB*NC*DI)/16, blk, 0, stream>>>(delta, u, params, A_log, Pc, Fc);
  scan_combine_kern<<<(NB*DI*DS)/256, blk, 0, stream>>>(Pc, Fc, Sinit);
  scan_apply_kern<<<(NB*NC*DI)/16, blk, 0, stream>>>(delta, u, params, xz, A_log, D_par, Sinit, delta);
  // G4: out = y @ W_out  [2048 x 1024, K=2048]  (MFMA)
  cvt_bf16_kern<<<(MM*DI/4 + 255)/256, blk, 0, stream>>>(delta, DI, DI, yb16, MM);
  transpose_cvt_kern<<<dim3(DM/32, DI/32), blk, 0, stream>>>(W_out, Wo_t, DI, DM);
  gemm_bf16_kern<0><<<dim3(DM/128, MM/128), blk, 0, stream>>>(yb16, Wo_t, out, MM, DM, DI, nullptr);
}

// Round 4
// 475.728 us; speedup vs baseline: 2.7065x; 1.0879x over previous
//
#include <hip/hip_runtime.h>
#include <hip/hip_bf16.h>
#include <math.h>

#define DM 1024
#define DI 2048
#define DS 16
#define DTR 64
#define NB 2
#define LL 1024
#define MM (NB*LL)   // 2048
#define NC 8         // scan chunks
#define CL (LL/NC)   // 128

typedef unsigned short u16;
typedef __bf16 bf16x8 __attribute__((ext_vector_type(8)));
typedef float f32x4 __attribute__((ext_vector_type(4)));

__device__ __forceinline__ float sigmoidf_(float x){ return 1.f/(1.f+__expf(-x)); }
__device__ __forceinline__ float siluf_(float x){ return x*sigmoidf_(x); }
__device__ __forceinline__ float softplusf_(float x){ return fmaxf(x,0.f)+log1pf(__expf(-fabsf(x))); }
__device__ __forceinline__ u16 f2b(float f){
  __hip_bfloat16 h = __float2bfloat16(f);
  return __builtin_bit_cast(unsigned short, h);
}

// ---------------- bf16 MFMA GEMM ----------------
// C[M][N] f32 = A[M][K]bf16 * Bt[N][K]bf16^T.  M,N mult of 128, K mult of 32.
// EPI==1: C = softplus(acc + bias[col])
template<int EPI>
__global__ __launch_bounds__(256) void gemm_bf16_kern(
    const u16* __restrict__ A, const u16* __restrict__ Bt,
    float* __restrict__ C, int M, int N, int K,
    const float* __restrict__ bias)
{
  constexpr int LDT = 40;                       // padded LDS stride (bf16)
  __shared__ __attribute__((aligned(16))) u16 As[128*LDT];
  __shared__ __attribute__((aligned(16))) u16 Bs[128*LDT];
  const unsigned tid = threadIdx.x;
  const unsigned l = tid & 63;
  const unsigned wave = tid >> 6;
  const unsigned wm = wave >> 1, wn = wave & 1; // 2x2 wave grid, 64x64 each
  const int bm = blockIdx.y * 128, bn = blockIdx.x * 128;
  const unsigned frow = l & 15, fk = (l >> 4) * 8;
  f32x4 acc[4][4] = {};
  for (int k0 = 0; k0 < K; k0 += 32) {
    int4 ra[2], rb[2];
    #pragma unroll
    for (int i = 0; i < 2; ++i) {
      const unsigned unit = tid*2 + i;
      const unsigned row = unit >> 2, seg = unit & 3;
      ra[i] = *(const int4*)(A  + (size_t)(bm+row)*K + k0 + seg*8);
      rb[i] = *(const int4*)(Bt + (size_t)(bn+row)*K + k0 + seg*8);
    }
    __syncthreads();     // previous iteration's ds_reads complete
    #pragma unroll
    for (int i = 0; i < 2; ++i) {
      const unsigned unit = tid*2 + i;
      const unsigned row = unit >> 2, seg = unit & 3;
      *(int4*)(As + row*LDT + seg*8) = ra[i];
      *(int4*)(Bs + row*LDT + seg*8) = rb[i];
    }
    __syncthreads();
    bf16x8 af[4], bfr[4];
    #pragma unroll
    for (int m = 0; m < 4; ++m)
      af[m] = *(const bf16x8*)(As + (wm*64 + m*16 + frow)*LDT + fk);
    #pragma unroll
    for (int n = 0; n < 4; ++n)
      bfr[n] = *(const bf16x8*)(Bs + (wn*64 + n*16 + frow)*LDT + fk);
    #pragma unroll
    for (int m = 0; m < 4; ++m)
      #pragma unroll
      for (int n = 0; n < 4; ++n)
        acc[m][n] = __builtin_amdgcn_mfma_f32_16x16x32_bf16(af[m], bfr[n], acc[m][n], 0, 0, 0);
  }
  // C/D layout (m89): col = l&15, row = (l>>4)*4 + q
  #pragma unroll
  for (int m = 0; m < 4; ++m) {
    #pragma unroll
    for (int n = 0; n < 4; ++n) {
      const int col = bn + wn*64 + n*16 + (l & 15);
      const float bs = (EPI == 1) ? bias[col] : 0.f;
      #pragma unroll
      for (int q = 0; q < 4; ++q) {
        const int row = bm + wm*64 + m*16 + (l >> 4)*4 + q;
        float v = acc[m][n][q];
        if (EPI == 1) v = softplusf_(v + bs);
        C[(size_t)row*N + col] = v;
      }
    }
  }
}

// transpose + convert: in [R][C] f32 -> out [C][R] bf16. grid(C/32, R/32).
__global__ __launch_bounds__(256) void transpose_cvt_kern(
    const float* __restrict__ in, u16* __restrict__ out, int R, int C)
{
  __shared__ float tile[32][33];
  const int r0 = blockIdx.y*32, c0 = blockIdx.x*32;
  const int tr = threadIdx.x >> 3, tc4 = (threadIdx.x & 7) * 4;
  float4 v = *(const float4*)(in + (size_t)(r0+tr)*C + c0 + tc4);
  tile[tr][tc4+0] = v.x; tile[tr][tc4+1] = v.y;
  tile[tr][tc4+2] = v.z; tile[tr][tc4+3] = v.w;
  __syncthreads();
  ushort4 o;
  o.x = f2b(tile[tc4+0][tr]);
  o.y = f2b(tile[tc4+1][tr]);
  o.z = f2b(tile[tc4+2][tr]);
  o.w = f2b(tile[tc4+3][tr]);
  *(ushort4*)(out + (size_t)(c0+tr)*R + r0 + tc4) = o;
}

// strided convert: out[row][0..C) bf16 = in[row*ld .. +C). C mult of 4.
__global__ __launch_bounds__(256) void cvt_bf16_kern(
    const float* __restrict__ in, int ld, int C, u16* __restrict__ out, int rows)
{
  const int i = blockIdx.x*256 + threadIdx.x;           // over rows*C/4
  if (i >= rows*(C/4)) return;
  const int row = i / (C/4);
  const int cq  = (i % (C/4)) * 4;
  float4 v = *(const float4*)(in + (size_t)row*ld + cq);
  ushort4 o; o.x=f2b(v.x); o.y=f2b(v.y); o.z=f2b(v.z); o.w=f2b(v.w);
  *(ushort4*)(out + (size_t)row*C + cq) = o;
}

// ---------------- x-proj (G2): params[M][96] = u[M][2048] @ W_x[2048][96] ----------------
// fp32 (accuracy-critical B/C/dt inputs). 256 blocks x 8 rows; thread owns
// cols {c, c+32, c+64}; u chunks staged in LDS and broadcast-read.
__global__ __launch_bounds__(256) void xproj_kern(
    const float* __restrict__ u, const float* __restrict__ W_x,
    float* __restrict__ params)
{
  __shared__ __align__(16) float As[8][512];   // 16KB
  const int tid = threadIdx.x;
  const int m0 = blockIdx.x * 8;
  const int r = tid >> 5;          // 0..7
  const int c = tid & 31;
  float a0=0.f, a1=0.f, a2=0.f;
  for (int k0 = 0; k0 < DI; k0 += 512) {
    __syncthreads();
    #pragma unroll
    for (int i = 0; i < 4; ++i) {
      const int flat = i*1024 + tid*4;
      const int rr = flat >> 9, cc = flat & 511;
      *(float4*)&As[rr][cc] = *(const float4*)(u + (size_t)(m0+rr)*DI + k0 + cc);
    }
    __syncthreads();
    #pragma unroll 8
    for (int k = 0; k < 512; ++k) {
      const float a = As[r][k];
      const float* w = W_x + (size_t)(k0+k)*96 + c;
      a0 = fmaf(a, w[0],  a0);
      a1 = fmaf(a, w[32], a1);
      a2 = fmaf(a, w[64], a2);
    }
  }
  float* p = params + (size_t)(m0+r)*96 + c;
  p[0]=a0; p[32]=a1; p[64]=a2;
}

// Causal depthwise conv (D_CONV=4) + SiLU.
__global__ __launch_bounds__(256) void conv_silu_kern(
    const float* __restrict__ xz, const float* __restrict__ conv_w,
    const float* __restrict__ conv_b, float* __restrict__ u)
{
  const int idx = blockIdx.x * 256 + threadIdx.x;   // over MM*DI
  const int d  = idx & (DI-1);
  const int ml = idx >> 11;
  const int l  = ml & (LL-1);
  const int base = ml - l;
  const float4 w4 = *(const float4*)(conv_w + d*4);
  const float wv[4] = {w4.x, w4.y, w4.z, w4.w};
  float acc = conv_b[d];
  #pragma unroll
  for (int j = 0; j < 4; ++j) {
    const int ls = l - 3 + j;
    if (ls >= 0) acc = fmaf(xz[(size_t)(base + ls)*(2*DI) + d], wv[j], acc);
  }
  u[idx] = siluf_(acc);
}

// ---- chunk-parallel selective scan ----
__global__ __launch_bounds__(256) void scan_local_kern(
    const float* __restrict__ delta, const float* __restrict__ u,
    const float* __restrict__ params, const float* __restrict__ A_log,
    float* __restrict__ Pc, float* __restrict__ Fc)
{
  const int tid = threadIdx.x;
  const int g = tid >> 4, n = tid & 15;
  const int gid = blockIdx.x * 16 + g;
  const int d  = gid & (DI-1);
  const int bc = gid >> 11;
  const int c  = bc & (NC-1);
  const int b  = bc >> 3;
  const float a_n = -expf(A_log[d*DS + n]);
  const size_t lbase = (size_t)b*LL + (size_t)c*CL;
  const float* dl = delta + lbase*DI + d;
  const float* uu = u     + lbase*DI + d;
  const float* pr = params + lbase*96;
  float s = 0.f, dtsum = 0.f;
  #pragma unroll 4
  for (int l = 0; l < CL; ++l) {
    const float dt = dl[(size_t)l*DI];
    const float ut = uu[(size_t)l*DI];
    const float Bt = pr[l*96 + DTR + n];
    const float da = __expf(dt * a_n);
    dtsum += dt;
    s = fmaf(da, s, dt * ut * Bt);
  }
  const size_t pf = (((size_t)(b*DI + d))*NC + c)*DS + n;
  Pc[pf] = __expf(dtsum * a_n);
  Fc[pf] = s;
}

__global__ __launch_bounds__(256) void scan_combine_kern(
    const float* __restrict__ Pc, const float* __restrict__ Fc,
    float* __restrict__ Sinit)
{
  const int idx = blockIdx.x * 256 + threadIdx.x;   // over NB*DI*DS
  const size_t base = (size_t)(idx >> 4) * (NC*DS) + (idx & 15);
  float s = 0.f;
  #pragma unroll
  for (int c = 0; c < NC; ++c) {
    Sinit[base + c*DS] = s;
    s = fmaf(Pc[base + c*DS], s, Fc[base + c*DS]);
  }
}

// Pass B: fused C-reduce + D*u + silu(z) gate; writes y as bf16 directly.
__global__ __launch_bounds__(256) void scan_apply_kern(
    const float* __restrict__ delta, const float* __restrict__ u,
    const float* __restrict__ params, const float* __restrict__ xz,
    const float* __restrict__ A_log, const float* __restrict__ D_param,
    const float* __restrict__ Sinit, u16* __restrict__ y16)
{
  const int tid = threadIdx.x;
  const int g = tid >> 4, n = tid & 15;
  const int gid = blockIdx.x * 16 + g;
  const int d  = gid & (DI-1);
  const int bc = gid >> 11;
  const int c  = bc & (NC-1);
  const int b  = bc >> 3;
  const float a_n = -expf(A_log[d*DS + n]);
  const float Dp  = D_param[d];
  const size_t lbase = (size_t)b*LL + (size_t)c*CL;
  const float* dl = delta + lbase*DI + d;
  const float* uu = u     + lbase*DI + d;
  const float* pr = params + lbase*96;
  const float* zp = xz + lbase*(2*DI) + DI + d;
  u16* yo = y16 + lbase*DI + d;
  float s = Sinit[(((size_t)(b*DI + d))*NC + c)*DS + n];
  #pragma unroll 4
  for (int l = 0; l < CL; ++l) {
    const float dt = dl[(size_t)l*DI];
    const float ut = uu[(size_t)l*DI];
    const float Bt = pr[l*96 + DTR + n];
    const float Ct = pr[l*96 + DTR + DS + n];
    const float da = __expf(dt * a_n);
    s = fmaf(da, s, dt * ut * Bt);
    float part = s * Ct;
    part += __shfl_xor(part, 1);
    part += __shfl_xor(part, 2);
    part += __shfl_xor(part, 4);
    part += __shfl_xor(part, 8);
    if (n == 0) {
      const float z = zp[(size_t)l*(2*DI)];
      yo[(size_t)l*DI] = f2b((part + Dp*ut) * siluf_(z));
    }
  }
}

extern "C" void kernel_launch(void* const* d_in, const int* in_sizes, int n_in,
                              void* d_out, int out_size, void* d_ws, size_t ws_size,
                              hipStream_t stream)
{
  const float* x      = (const float*)d_in[0];
  const float* W_in   = (const float*)d_in[1];
  const float* conv_w = (const float*)d_in[2];
  const float* conv_b = (const float*)d_in[3];
  const float* W_x    = (const float*)d_in[4];
  const float* W_dt   = (const float*)d_in[5];
  const float* b_dt   = (const float*)d_in[6];
  const float* W_out  = (const float*)d_in[7];
  const float* A_log  = (const float*)d_in[8];
  const float* D_par  = (const float*)d_in[9];
  float* out = (float*)d_out;

  float* xz     = (float*)d_ws;             // MM*4096 f32 (32MB)
  float* u      = xz + (size_t)MM*2*DI;     // MM*DI f32 (16MB)
  float* params = u  + (size_t)MM*DI;       // MM*96 f32 (0.75MB)
  float* delta  = params + (size_t)MM*96;   // MM*DI f32 (16MB)
  u16*  pool    = (u16*)(delta + (size_t)MM*DI);   // 4.5MB region
  // G1 phase:
  u16* xb16 = pool;                          // 2048*1024 (4MB), dead after G1
  u16* Wi_t = (u16*)out;                     // 4096*1024 bf16 = 8MB, in d_out
  // post-G1 phase (reuses pool):
  u16* Wd_t   = pool;                        // 2048*64
  u16* dltb16 = pool + (size_t)DI*DTR;       // 2048*64
  u16* Wo_t   = pool + (size_t)2*DI*DTR;     // 1024*2048 (4MB)
  u16* yb16   = pool + (size_t)2*DI*DTR + (size_t)DM*DI;  // 2048*2048 (8MB)
  // scan summaries in d_out (after G1, before final GEMM):
  const size_t PFN = (size_t)NB*DI*NC*DS;
  float* Pc    = out;
  float* Fc    = out + PFN;
  float* Sinit = out + 2*PFN;

  dim3 blk(256);
  // convert x -> bf16; transpose-convert W_in -> [4096][1024] bf16 (in d_out)
  cvt_bf16_kern<<<(MM*DM/4 + 255)/256, blk, 0, stream>>>(x, DM, DM, xb16, MM);
  transpose_cvt_kern<<<dim3(2*DI/32, DM/32), blk, 0, stream>>>(W_in, Wi_t, DM, 2*DI);
  // G1: xz = x @ W_in   [2048 x 4096, K=1024]  (MFMA)
  gemm_bf16_kern<0><<<dim3(2*DI/128, MM/128), blk, 0, stream>>>(xb16, Wi_t, xz, MM, 2*DI, DM, nullptr);
  // conv + silu -> u
  conv_silu_kern<<<(MM*DI)/256, blk, 0, stream>>>(xz, conv_w, conv_b, u);
  // G2: params = u @ W_x  [2048 x 96, K=2048]  (specialized fp32)
  xproj_kern<<<MM/8, blk, 0, stream>>>(u, W_x, params);
  // G3: delta = softplus(dlt @ W_dt + b_dt)  [2048 x 2048, K=64]  (MFMA)
  cvt_bf16_kern<<<(MM*DTR/4 + 255)/256, blk, 0, stream>>>(params, 96, DTR, dltb16, MM);
  transpose_cvt_kern<<<dim3(DI/32, DTR/32), blk, 0, stream>>>(W_dt, Wd_t, DTR, DI);
  gemm_bf16_kern<1><<<dim3(DI/128, MM/128), blk, 0, stream>>>(dltb16, Wd_t, delta, MM, DI, DTR, b_dt);
  // chunked scan (y written as bf16 to yb16)
  scan_local_kern<<<(NB*NC*DI)/16, blk, 0, stream>>>(delta, u, params, A_log, Pc, Fc);
  scan_combine_kern<<<(NB*DI*DS)/256, blk, 0, stream>>>(Pc, Fc, Sinit);
  scan_apply_kern<<<(NB*NC*DI)/16, blk, 0, stream>>>(delta, u, params, xz, A_log, D_par, Sinit, yb16);
  // G4: out = y @ W_out  [2048 x 1024, K=2048]  (MFMA)
  transpose_cvt_kern<<<dim3(DM/32, DI/32), blk, 0, stream>>>(W_out, Wo_t, DI, DM);
  gemm_bf16_kern<0><<<dim3(DM/128, MM/128), blk, 0, stream>>>(yb16, Wo_t, out, MM, DM, DI, nullptr);
}

// Round 5
// 437.657 us; speedup vs baseline: 2.9419x; 1.0870x over previous
//
#include <hip/hip_runtime.h>
#include <hip/hip_bf16.h>
#include <math.h>

#define DM 1024
#define DI 2048
#define DS 16
#define DTR 64
#define NB 2
#define LL 1024
#define MM (NB*LL)   // 2048
#define NC 8         // scan chunks
#define CL (LL/NC)   // 128
#define XSPLIT 8
#define XKC (DI/XSPLIT)  // 256

typedef unsigned short u16;
typedef __bf16 bf16x8 __attribute__((ext_vector_type(8)));
typedef float f32x4 __attribute__((ext_vector_type(4)));

__device__ __forceinline__ float sigmoidf_(float x){ return 1.f/(1.f+__expf(-x)); }
__device__ __forceinline__ float siluf_(float x){ return x*sigmoidf_(x); }
__device__ __forceinline__ float softplusf_(float x){ return fmaxf(x,0.f)+log1pf(__expf(-fabsf(x))); }
__device__ __forceinline__ u16 f2b(float f){
  __hip_bfloat16 h = __float2bfloat16(f);
  return __builtin_bit_cast(unsigned short, h);
}

// ---------------- bf16 MFMA GEMM ----------------
// C[M][N] f32 = A[M][K]bf16 * Bt[N][K]bf16^T.  M,N mult of 128, K mult of 32.
// EPI==1: C = softplus(acc + bias[col])
template<int EPI>
__global__ __launch_bounds__(256) void gemm_bf16_kern(
    const u16* __restrict__ A, const u16* __restrict__ Bt,
    float* __restrict__ C, int M, int N, int K,
    const float* __restrict__ bias)
{
  constexpr int LDT = 40;                       // padded LDS stride (bf16)
  __shared__ __attribute__((aligned(16))) u16 As[128*LDT];
  __shared__ __attribute__((aligned(16))) u16 Bs[128*LDT];
  const unsigned tid = threadIdx.x;
  const unsigned l = tid & 63;
  const unsigned wave = tid >> 6;
  const unsigned wm = wave >> 1, wn = wave & 1; // 2x2 wave grid, 64x64 each
  const int bm = blockIdx.y * 128, bn = blockIdx.x * 128;
  const unsigned frow = l & 15, fk = (l >> 4) * 8;
  f32x4 acc[4][4] = {};
  for (int k0 = 0; k0 < K; k0 += 32) {
    int4 ra[2], rb[2];
    #pragma unroll
    for (int i = 0; i < 2; ++i) {
      const unsigned unit = tid*2 + i;
      const unsigned row = unit >> 2, seg = unit & 3;
      ra[i] = *(const int4*)(A  + (size_t)(bm+row)*K + k0 + seg*8);
      rb[i] = *(const int4*)(Bt + (size_t)(bn+row)*K + k0 + seg*8);
    }
    __syncthreads();     // previous iteration's ds_reads complete
    #pragma unroll
    for (int i = 0; i < 2; ++i) {
      const unsigned unit = tid*2 + i;
      const unsigned row = unit >> 2, seg = unit & 3;
      *(int4*)(As + row*LDT + seg*8) = ra[i];
      *(int4*)(Bs + row*LDT + seg*8) = rb[i];
    }
    __syncthreads();
    bf16x8 af[4], bfr[4];
    #pragma unroll
    for (int m = 0; m < 4; ++m)
      af[m] = *(const bf16x8*)(As + (wm*64 + m*16 + frow)*LDT + fk);
    #pragma unroll
    for (int n = 0; n < 4; ++n)
      bfr[n] = *(const bf16x8*)(Bs + (wn*64 + n*16 + frow)*LDT + fk);
    #pragma unroll
    for (int m = 0; m < 4; ++m)
      #pragma unroll
      for (int n = 0; n < 4; ++n)
        acc[m][n] = __builtin_amdgcn_mfma_f32_16x16x32_bf16(af[m], bfr[n], acc[m][n], 0, 0, 0);
  }
  // C/D layout (m89): col = l&15, row = (l>>4)*4 + q
  #pragma unroll
  for (int m = 0; m < 4; ++m) {
    #pragma unroll
    for (int n = 0; n < 4; ++n) {
      const int col = bn + wn*64 + n*16 + (l & 15);
      const float bs = (EPI == 1) ? bias[col] : 0.f;
      #pragma unroll
      for (int q = 0; q < 4; ++q) {
        const int row = bm + wm*64 + m*16 + (l >> 4)*4 + q;
        float v = acc[m][n][q];
        if (EPI == 1) v = softplusf_(v + bs);
        C[(size_t)row*N + col] = v;
      }
    }
  }
}

// transpose + convert: in [R][C] f32 -> out [C][R] bf16. grid(C/32, R/32).
__global__ __launch_bounds__(256) void transpose_cvt_kern(
    const float* __restrict__ in, u16* __restrict__ out, int R, int C)
{
  __shared__ float tile[32][33];
  const int r0 = blockIdx.y*32, c0 = blockIdx.x*32;
  const int tr = threadIdx.x >> 3, tc4 = (threadIdx.x & 7) * 4;
  float4 v = *(const float4*)(in + (size_t)(r0+tr)*C + c0 + tc4);
  tile[tr][tc4+0] = v.x; tile[tr][tc4+1] = v.y;
  tile[tr][tc4+2] = v.z; tile[tr][tc4+3] = v.w;
  __syncthreads();
  ushort4 o;
  o.x = f2b(tile[tc4+0][tr]);
  o.y = f2b(tile[tc4+1][tr]);
  o.z = f2b(tile[tc4+2][tr]);
  o.w = f2b(tile[tc4+3][tr]);
  *(ushort4*)(out + (size_t)(c0+tr)*R + r0 + tc4) = o;
}

// strided convert: out[row][0..C) bf16 = in[row*ld .. +C). C mult of 4.
__global__ __launch_bounds__(256) void cvt_bf16_kern(
    const float* __restrict__ in, int ld, int C, u16* __restrict__ out, int rows)
{
  const int i = blockIdx.x*256 + threadIdx.x;           // over rows*C/4
  if (i >= rows*(C/4)) return;
  const int row = i / (C/4);
  const int cq  = (i % (C/4)) * 4;
  float4 v = *(const float4*)(in + (size_t)row*ld + cq);
  ushort4 o; o.x=f2b(v.x); o.y=f2b(v.y); o.z=f2b(v.z); o.w=f2b(v.w);
  *(ushort4*)(out + (size_t)row*C + cq) = o;
}

// ---------------- x-proj (G2), K-split fp32 ----------------
// partials[ks][M][96] += u[m][k0:k0+256] @ W_x[k0:k0+256][96]
__global__ __launch_bounds__(256) void xproj_part_kern(
    const float* __restrict__ u, const float* __restrict__ W_x,
    float* __restrict__ part)
{
  __shared__ __align__(16) float As[8][XKC];   // 8KB
  const int tid = threadIdx.x;
  const int m0 = (blockIdx.x & 255) * 8;
  const int ks = blockIdx.x >> 8;
  const int k0 = ks * XKC;
  #pragma unroll
  for (int i = 0; i < 2; ++i) {
    const int flat = i*1024 + tid*4;
    const int rr = flat >> 8, cc = flat & (XKC-1);
    *(float4*)&As[rr][cc] = *(const float4*)(u + (size_t)(m0+rr)*DI + k0 + cc);
  }
  __syncthreads();
  const int r = tid >> 5, c = tid & 31;
  float a0=0.f, a1=0.f, a2=0.f;
  #pragma unroll 8
  for (int k = 0; k < XKC; ++k) {
    const float a = As[r][k];
    const float* w = W_x + (size_t)(k0+k)*96 + c;
    a0 = fmaf(a, w[0],  a0);
    a1 = fmaf(a, w[32], a1);
    a2 = fmaf(a, w[64], a2);
  }
  float* p = part + ((size_t)ks*MM + m0 + r)*96 + c;
  p[0]=a0; p[32]=a1; p[64]=a2;
}

// fixed-order reduction over the 8 K-chunks (deterministic)
__global__ __launch_bounds__(256) void xproj_reduce_kern(
    const float* __restrict__ part, float* __restrict__ params)
{
  const int i = blockIdx.x*256 + threadIdx.x;   // over MM*96/4
  float4 s = {0.f,0.f,0.f,0.f};
  #pragma unroll
  for (int ks = 0; ks < XSPLIT; ++ks) {
    float4 v = *(const float4*)(part + (size_t)ks*MM*96 + (size_t)i*4);
    s.x+=v.x; s.y+=v.y; s.z+=v.z; s.w+=v.w;
  }
  *(float4*)(params + (size_t)i*4) = s;
}

// Causal depthwise conv (D_CONV=4) + SiLU, float4 over d (4 channels/thread).
__global__ __launch_bounds__(256) void conv_silu_kern(
    const float* __restrict__ xz, const float* __restrict__ conv_w,
    const float* __restrict__ conv_b, float* __restrict__ u)
{
  const int idx = blockIdx.x * 256 + threadIdx.x;   // over MM*DI/4
  const int d4 = (idx & (DI/4 - 1)) * 4;
  const int ml = idx >> 9;
  const int l  = ml & (LL-1);
  const int base = ml - l;
  const float4 w0 = *(const float4*)(conv_w + (d4+0)*4);
  const float4 w1 = *(const float4*)(conv_w + (d4+1)*4);
  const float4 w2 = *(const float4*)(conv_w + (d4+2)*4);
  const float4 w3 = *(const float4*)(conv_w + (d4+3)*4);
  const float wt[4][4] = {{w0.x,w0.y,w0.z,w0.w},{w1.x,w1.y,w1.z,w1.w},
                          {w2.x,w2.y,w2.z,w2.w},{w3.x,w3.y,w3.z,w3.w}};
  float4 acc = *(const float4*)(conv_b + d4);
  #pragma unroll
  for (int j = 0; j < 4; ++j) {
    const int ls = l - 3 + j;
    if (ls >= 0) {
      const float4 v = *(const float4*)(xz + (size_t)(base + ls)*(2*DI) + d4);
      acc.x = fmaf(v.x, wt[0][j], acc.x);
      acc.y = fmaf(v.y, wt[1][j], acc.y);
      acc.z = fmaf(v.z, wt[2][j], acc.z);
      acc.w = fmaf(v.w, wt[3][j], acc.w);
    }
  }
  float4 o;
  o.x = siluf_(acc.x); o.y = siluf_(acc.y);
  o.z = siluf_(acc.z); o.w = siluf_(acc.w);
  *(float4*)(u + (size_t)idx*4) = o;
}

// ---- chunk-parallel selective scan ----
__global__ __launch_bounds__(256) void scan_local_kern(
    const float* __restrict__ delta, const float* __restrict__ u,
    const float* __restrict__ params, const float* __restrict__ A_log,
    float* __restrict__ Pc, float* __restrict__ Fc)
{
  const int tid = threadIdx.x;
  const int g = tid >> 4, n = tid & 15;
  const int gid = blockIdx.x * 16 + g;
  const int d  = gid & (DI-1);
  const int bc = gid >> 11;
  const int c  = bc & (NC-1);
  const int b  = bc >> 3;
  const float a_n = -expf(A_log[d*DS + n]);
  const size_t lbase = (size_t)b*LL + (size_t)c*CL;
  const float* dl = delta + lbase*DI + d;
  const float* uu = u     + lbase*DI + d;
  const float* pr = params + lbase*96;
  float s = 0.f, dtsum = 0.f;
  #pragma unroll 4
  for (int l = 0; l < CL; ++l) {
    const float dt = dl[(size_t)l*DI];
    const float ut = uu[(size_t)l*DI];
    const float Bt = pr[l*96 + DTR + n];
    const float da = __expf(dt * a_n);
    dtsum += dt;
    s = fmaf(da, s, dt * ut * Bt);
  }
  const size_t pf = (((size_t)(b*DI + d))*NC + c)*DS + n;
  Pc[pf] = __expf(dtsum * a_n);
  Fc[pf] = s;
}

__global__ __launch_bounds__(256) void scan_combine_kern(
    const float* __restrict__ Pc, const float* __restrict__ Fc,
    float* __restrict__ Sinit)
{
  const int idx = blockIdx.x * 256 + threadIdx.x;   // over NB*DI*DS
  const size_t base = (size_t)(idx >> 4) * (NC*DS) + (idx & 15);
  float s = 0.f;
  #pragma unroll
  for (int c = 0; c < NC; ++c) {
    Sinit[base + c*DS] = s;
    s = fmaf(Pc[base + c*DS], s, Fc[base + c*DS]);
  }
}

// Pass B: fused C-reduce + D*u + silu(z) gate; writes y as bf16 directly.
__global__ __launch_bounds__(256) void scan_apply_kern(
    const float* __restrict__ delta, const float* __restrict__ u,
    const float* __restrict__ params, const float* __restrict__ xz,
    const float* __restrict__ A_log, const float* __restrict__ D_param,
    const float* __restrict__ Sinit, u16* __restrict__ y16)
{
  const int tid = threadIdx.x;
  const int g = tid >> 4, n = tid & 15;
  const int gid = blockIdx.x * 16 + g;
  const int d  = gid & (DI-1);
  const int bc = gid >> 11;
  const int c  = bc & (NC-1);
  const int b  = bc >> 3;
  const float a_n = -expf(A_log[d*DS + n]);
  const float Dp  = D_param[d];
  const size_t lbase = (size_t)b*LL + (size_t)c*CL;
  const float* dl = delta + lbase*DI + d;
  const float* uu = u     + lbase*DI + d;
  const float* pr = params + lbase*96;
  const float* zp = xz + lbase*(2*DI) + DI + d;
  u16* yo = y16 + lbase*DI + d;
  float s = Sinit[(((size_t)(b*DI + d))*NC + c)*DS + n];
  #pragma unroll 4
  for (int l = 0; l < CL; ++l) {
    const float dt = dl[(size_t)l*DI];
    const float ut = uu[(size_t)l*DI];
    const float Bt = pr[l*96 + DTR + n];
    const float Ct = pr[l*96 + DTR + DS + n];
    const float da = __expf(dt * a_n);
    s = fmaf(da, s, dt * ut * Bt);
    float part = s * Ct;
    part += __shfl_xor(part, 1);
    part += __shfl_xor(part, 2);
    part += __shfl_xor(part, 4);
    part += __shfl_xor(part, 8);
    if (n == 0) {
      const float z = zp[(size_t)l*(2*DI)];
      yo[(size_t)l*DI] = f2b((part + Dp*ut) * siluf_(z));
    }
  }
}

extern "C" void kernel_launch(void* const* d_in, const int* in_sizes, int n_in,
                              void* d_out, int out_size, void* d_ws, size_t ws_size,
                              hipStream_t stream)
{
  const float* x      = (const float*)d_in[0];
  const float* W_in   = (const float*)d_in[1];
  const float* conv_w = (const float*)d_in[2];
  const float* conv_b = (const float*)d_in[3];
  const float* W_x    = (const float*)d_in[4];
  const float* W_dt   = (const float*)d_in[5];
  const float* b_dt   = (const float*)d_in[6];
  const float* W_out  = (const float*)d_in[7];
  const float* A_log  = (const float*)d_in[8];
  const float* D_par  = (const float*)d_in[9];
  float* out = (float*)d_out;

  float* xz     = (float*)d_ws;             // MM*4096 f32 (32MB)
  float* u      = xz + (size_t)MM*2*DI;     // MM*DI f32 (16MB)
  float* params = u  + (size_t)MM*DI;       // MM*96 f32 (0.75MB)
  float* delta  = params + (size_t)MM*96;   // MM*DI f32 (16MB)
  u16*  pool    = (u16*)(delta + (size_t)MM*DI);
  // G1 phase:
  u16* xb16 = pool;                          // 2048*1024 (4MB), dead after G1
  u16* Wi_t = (u16*)out;                     // 4096*1024 bf16 = 8MB, in d_out
  // post-G1 phase (reuses pool):
  u16* Wd_t   = pool;                        // 2048*64
  u16* dltb16 = pool + (size_t)DI*DTR;       // 2048*64
  u16* Wo_t   = pool + (size_t)2*DI*DTR;     // 1024*2048 (4MB)
  u16* yb16   = pool + (size_t)2*DI*DTR + (size_t)DM*DI;  // 2048*2048 (8MB)
  // d_out staging (all dead before the final GEMM writes out):
  float* xpart = out;                        // [8][2048][96] f32 = 6.3MB (after G1)
  const size_t PFN = (size_t)NB*DI*NC*DS;
  float* Pc    = out;                        // scan phase
  float* Fc    = out + PFN;
  float* Sinit = out + 2*PFN;

  dim3 blk(256);
  // convert x -> bf16; transpose-convert W_in -> [4096][1024] bf16 (in d_out)
  cvt_bf16_kern<<<(MM*DM/4 + 255)/256, blk, 0, stream>>>(x, DM, DM, xb16, MM);
  transpose_cvt_kern<<<dim3(2*DI/32, DM/32), blk, 0, stream>>>(W_in, Wi_t, DM, 2*DI);
  // G1: xz = x @ W_in   [2048 x 4096, K=1024]  (MFMA)
  gemm_bf16_kern<0><<<dim3(2*DI/128, MM/128), blk, 0, stream>>>(xb16, Wi_t, xz, MM, 2*DI, DM, nullptr);
  // conv + silu -> u
  conv_silu_kern<<<(MM*DI/4)/256, blk, 0, stream>>>(xz, conv_w, conv_b, u);
  // G2: params = u @ W_x  [2048 x 96, K=2048]  (fp32, K-split + reduce)
  xproj_part_kern<<<256*XSPLIT, blk, 0, stream>>>(u, W_x, xpart);
  xproj_reduce_kern<<<(MM*96/4)/256, blk, 0, stream>>>(xpart, params);
  // G3: delta = softplus(dlt @ W_dt + b_dt)  [2048 x 2048, K=64]  (MFMA)
  cvt_bf16_kern<<<(MM*DTR/4 + 255)/256, blk, 0, stream>>>(params, 96, DTR, dltb16, MM);
  transpose_cvt_kern<<<dim3(DI/32, DTR/32), blk, 0, stream>>>(W_dt, Wd_t, DTR, DI);
  gemm_bf16_kern<1><<<dim3(DI/128, MM/128), blk, 0, stream>>>(dltb16, Wd_t, delta, MM, DI, DTR, b_dt);
  // chunked scan (y written as bf16 to yb16)
  scan_local_kern<<<(NB*NC*DI)/16, blk, 0, stream>>>(delta, u, params, A_log, Pc, Fc);
  scan_combine_kern<<<(NB*DI*DS)/256, blk, 0, stream>>>(Pc, Fc, Sinit);
  scan_apply_kern<<<(NB*NC*DI)/16, blk, 0, stream>>>(delta, u, params, xz, A_log, D_par, Sinit, yb16);
  // G4: out = y @ W_out  [2048 x 1024, K=2048]  (MFMA)
  transpose_cvt_kern<<<dim3(DM/32, DI/32), blk, 0, stream>>>(W_out, Wo_t, DI, DM);
  gemm_bf16_kern<0><<<dim3(DM/128, MM/128), blk, 0, stream>>>(yb16, Wo_t, out, MM, DM, DI, nullptr);
}

// Round 6
// 378.466 us; speedup vs baseline: 3.4020x; 1.1564x over previous
//
#include <hip/hip_runtime.h>
#include <hip/hip_bf16.h>
#include <math.h>

#define DM 1024
#define DI 2048
#define DS 16
#define DTR 64
#define NB 2
#define LL 1024
#define MM (NB*LL)   // 2048
#define NC 16        // scan chunks
#define CL (LL/NC)   // 64
#define XSPLIT 8
#define XKC (DI/XSPLIT)  // 256

typedef unsigned short u16;
typedef __bf16 bf16x8 __attribute__((ext_vector_type(8)));
typedef float f32x4 __attribute__((ext_vector_type(4)));

__device__ __forceinline__ float sigmoidf_(float x){ return 1.f/(1.f+__expf(-x)); }
__device__ __forceinline__ float siluf_(float x){ return x*sigmoidf_(x); }
__device__ __forceinline__ float softplusf_(float x){ return fmaxf(x,0.f)+log1pf(__expf(-fabsf(x))); }
__device__ __forceinline__ u16 f2b(float f){
  __hip_bfloat16 h = __float2bfloat16(f);
  return __builtin_bit_cast(unsigned short, h);
}

// ---------------- bf16 MFMA GEMM ----------------
// C[M][N] f32 = A[M][K]bf16 * Bt[N][K]bf16^T.  M,N mult of 128, K mult of 32.
// EPI==1: C = softplus(acc + bias[col])
template<int EPI>
__global__ __launch_bounds__(256) void gemm_bf16_kern(
    const u16* __restrict__ A, const u16* __restrict__ Bt,
    float* __restrict__ C, int M, int N, int K,
    const float* __restrict__ bias)
{
  constexpr int LDT = 40;                       // padded LDS stride (bf16)
  __shared__ __attribute__((aligned(16))) u16 As[128*LDT];
  __shared__ __attribute__((aligned(16))) u16 Bs[128*LDT];
  const unsigned tid = threadIdx.x;
  const unsigned l = tid & 63;
  const unsigned wave = tid >> 6;
  const unsigned wm = wave >> 1, wn = wave & 1; // 2x2 wave grid, 64x64 each
  const int bm = blockIdx.y * 128, bn = blockIdx.x * 128;
  const unsigned frow = l & 15, fk = (l >> 4) * 8;
  f32x4 acc[4][4] = {};
  for (int k0 = 0; k0 < K; k0 += 32) {
    int4 ra[2], rb[2];
    #pragma unroll
    for (int i = 0; i < 2; ++i) {
      const unsigned unit = tid*2 + i;
      const unsigned row = unit >> 2, seg = unit & 3;
      ra[i] = *(const int4*)(A  + (size_t)(bm+row)*K + k0 + seg*8);
      rb[i] = *(const int4*)(Bt + (size_t)(bn+row)*K + k0 + seg*8);
    }
    __syncthreads();     // previous iteration's ds_reads complete
    #pragma unroll
    for (int i = 0; i < 2; ++i) {
      const unsigned unit = tid*2 + i;
      const unsigned row = unit >> 2, seg = unit & 3;
      *(int4*)(As + row*LDT + seg*8) = ra[i];
      *(int4*)(Bs + row*LDT + seg*8) = rb[i];
    }
    __syncthreads();
    bf16x8 af[4], bfr[4];
    #pragma unroll
    for (int m = 0; m < 4; ++m)
      af[m] = *(const bf16x8*)(As + (wm*64 + m*16 + frow)*LDT + fk);
    #pragma unroll
    for (int n = 0; n < 4; ++n)
      bfr[n] = *(const bf16x8*)(Bs + (wn*64 + n*16 + frow)*LDT + fk);
    #pragma unroll
    for (int m = 0; m < 4; ++m)
      #pragma unroll
      for (int n = 0; n < 4; ++n)
        acc[m][n] = __builtin_amdgcn_mfma_f32_16x16x32_bf16(af[m], bfr[n], acc[m][n], 0, 0, 0);
  }
  // C/D layout (m89): col = l&15, row = (l>>4)*4 + q
  #pragma unroll
  for (int m = 0; m < 4; ++m) {
    #pragma unroll
    for (int n = 0; n < 4; ++n) {
      const int col = bn + wn*64 + n*16 + (l & 15);
      const float bs = (EPI == 1) ? bias[col] : 0.f;
      #pragma unroll
      for (int q = 0; q < 4; ++q) {
        const int row = bm + wm*64 + m*16 + (l >> 4)*4 + q;
        float v = acc[m][n][q];
        if (EPI == 1) v = softplusf_(v + bs);
        C[(size_t)row*N + col] = v;
      }
    }
  }
}

// transpose + convert: in [R][C] f32 -> out [C][R] bf16. grid(C/32, R/32).
__global__ __launch_bounds__(256) void transpose_cvt_kern(
    const float* __restrict__ in, u16* __restrict__ out, int R, int C)
{
  __shared__ float tile[32][33];
  const int r0 = blockIdx.y*32, c0 = blockIdx.x*32;
  const int tr = threadIdx.x >> 3, tc4 = (threadIdx.x & 7) * 4;
  float4 v = *(const float4*)(in + (size_t)(r0+tr)*C + c0 + tc4);
  tile[tr][tc4+0] = v.x; tile[tr][tc4+1] = v.y;
  tile[tr][tc4+2] = v.z; tile[tr][tc4+3] = v.w;
  __syncthreads();
  ushort4 o;
  o.x = f2b(tile[tc4+0][tr]);
  o.y = f2b(tile[tc4+1][tr]);
  o.z = f2b(tile[tc4+2][tr]);
  o.w = f2b(tile[tc4+3][tr]);
  *(ushort4*)(out + (size_t)(c0+tr)*R + r0 + tc4) = o;
}

// strided convert: out[row][0..C) bf16 = in[row*ld .. +C). C mult of 4.
__global__ __launch_bounds__(256) void cvt_bf16_kern(
    const float* __restrict__ in, int ld, int C, u16* __restrict__ out, int rows)
{
  const int i = blockIdx.x*256 + threadIdx.x;           // over rows*C/4
  if (i >= rows*(C/4)) return;
  const int row = i / (C/4);
  const int cq  = (i % (C/4)) * 4;
  float4 v = *(const float4*)(in + (size_t)row*ld + cq);
  ushort4 o; o.x=f2b(v.x); o.y=f2b(v.y); o.z=f2b(v.z); o.w=f2b(v.w);
  *(ushort4*)(out + (size_t)row*C + cq) = o;
}

// ---------------- x-proj (G2), K-split fp32 ----------------
__global__ __launch_bounds__(256) void xproj_part_kern(
    const float* __restrict__ u, const float* __restrict__ W_x,
    float* __restrict__ part)
{
  __shared__ __align__(16) float As[8][XKC];   // 8KB
  const int tid = threadIdx.x;
  const int m0 = (blockIdx.x & 255) * 8;
  const int ks = blockIdx.x >> 8;
  const int k0 = ks * XKC;
  #pragma unroll
  for (int i = 0; i < 2; ++i) {
    const int flat = i*1024 + tid*4;
    const int rr = flat >> 8, cc = flat & (XKC-1);
    *(float4*)&As[rr][cc] = *(const float4*)(u + (size_t)(m0+rr)*DI + k0 + cc);
  }
  __syncthreads();
  const int r = tid >> 5, c = tid & 31;
  float a0=0.f, a1=0.f, a2=0.f;
  #pragma unroll 8
  for (int k = 0; k < XKC; ++k) {
    const float a = As[r][k];
    const float* w = W_x + (size_t)(k0+k)*96 + c;
    a0 = fmaf(a, w[0],  a0);
    a1 = fmaf(a, w[32], a1);
    a2 = fmaf(a, w[64], a2);
  }
  float* p = part + ((size_t)ks*MM + m0 + r)*96 + c;
  p[0]=a0; p[32]=a1; p[64]=a2;
}

__global__ __launch_bounds__(256) void xproj_reduce_kern(
    const float* __restrict__ part, float* __restrict__ params)
{
  const int i = blockIdx.x*256 + threadIdx.x;   // over MM*96/4
  float4 s = {0.f,0.f,0.f,0.f};
  #pragma unroll
  for (int ks = 0; ks < XSPLIT; ++ks) {
    float4 v = *(const float4*)(part + (size_t)ks*MM*96 + (size_t)i*4);
    s.x+=v.x; s.y+=v.y; s.z+=v.z; s.w+=v.w;
  }
  *(float4*)(params + (size_t)i*4) = s;
}

// Causal depthwise conv (D_CONV=4) + SiLU, float4 over d (4 channels/thread).
__global__ __launch_bounds__(256) void conv_silu_kern(
    const float* __restrict__ xz, const float* __restrict__ conv_w,
    const float* __restrict__ conv_b, float* __restrict__ u)
{
  const int idx = blockIdx.x * 256 + threadIdx.x;   // over MM*DI/4
  const int d4 = (idx & (DI/4 - 1)) * 4;
  const int ml = idx >> 9;
  const int l  = ml & (LL-1);
  const int base = ml - l;
  const float4 w0 = *(const float4*)(conv_w + (d4+0)*4);
  const float4 w1 = *(const float4*)(conv_w + (d4+1)*4);
  const float4 w2 = *(const float4*)(conv_w + (d4+2)*4);
  const float4 w3 = *(const float4*)(conv_w + (d4+3)*4);
  const float wt[4][4] = {{w0.x,w0.y,w0.z,w0.w},{w1.x,w1.y,w1.z,w1.w},
                          {w2.x,w2.y,w2.z,w2.w},{w3.x,w3.y,w3.z,w3.w}};
  float4 acc = *(const float4*)(conv_b + d4);
  #pragma unroll
  for (int j = 0; j < 4; ++j) {
    const int ls = l - 3 + j;
    if (ls >= 0) {
      const float4 v = *(const float4*)(xz + (size_t)(base + ls)*(2*DI) + d4);
      acc.x = fmaf(v.x, wt[0][j], acc.x);
      acc.y = fmaf(v.y, wt[1][j], acc.y);
      acc.z = fmaf(v.z, wt[2][j], acc.z);
      acc.w = fmaf(v.w, wt[3][j], acc.w);
    }
  }
  float4 o;
  o.x = siluf_(acc.x); o.y = siluf_(acc.y);
  o.z = siluf_(acc.z); o.w = siluf_(acc.w);
  *(float4*)(u + (size_t)idx*4) = o;
}

// ---- chunk-parallel selective scan: 4 lanes/channel, 4 states/lane ----
// flat thread: q = lanes-in-channel (states n = q*4..q*4+3), ch = (b,c,d).
__global__ __launch_bounds__(256) void scan_local_kern(
    const float* __restrict__ delta, const float* __restrict__ u,
    const float* __restrict__ params, const float* __restrict__ A_log,
    float* __restrict__ Pc, float* __restrict__ Fc)
{
  const int flat = blockIdx.x*256 + threadIdx.x;
  const int q  = flat & 3;
  const int ch = flat >> 2;
  const int d  = ch & (DI-1);
  const int c  = (ch >> 11) & (NC-1);
  const int b  = ch >> 15;
  const float4 al = *(const float4*)(A_log + d*DS + q*4);
  const float a0=-expf(al.x), a1=-expf(al.y), a2=-expf(al.z), a3=-expf(al.w);
  const size_t lbase = (size_t)b*LL + (size_t)c*CL;
  const float* dl = delta + lbase*DI + d;
  const float* uu = u     + lbase*DI + d;
  const float* pr = params + lbase*96 + DTR + q*4;
  float s0=0.f,s1=0.f,s2=0.f,s3=0.f, dtsum=0.f;
  #pragma unroll 4
  for (int l = 0; l < CL; ++l) {
    const float dt = dl[(size_t)l*DI];
    const float ut = uu[(size_t)l*DI];
    const float4 B4 = *(const float4*)(pr + l*96);
    const float dtu = dt*ut;
    s0 = fmaf(__expf(dt*a0), s0, dtu*B4.x);
    s1 = fmaf(__expf(dt*a1), s1, dtu*B4.y);
    s2 = fmaf(__expf(dt*a2), s2, dtu*B4.z);
    s3 = fmaf(__expf(dt*a3), s3, dtu*B4.w);
    dtsum += dt;
  }
  const size_t base = (((size_t)(b*DI + d))*NC + c)*DS + q*4;
  float4 P4; P4.x=__expf(dtsum*a0); P4.y=__expf(dtsum*a1);
  P4.z=__expf(dtsum*a2); P4.w=__expf(dtsum*a3);
  *(float4*)(Pc + base) = P4;
  *(float4*)(Fc + base) = make_float4(s0,s1,s2,s3);
}

// Combine: per (b,d,n), sequential over NC chunks. PS doubles as Pc-in /
// Sinit-out (read P,F into regs BEFORE overwriting -> alias-safe).
__global__ __launch_bounds__(256) void scan_combine_kern(
    float* __restrict__ PS, const float* __restrict__ Fc)
{
  const int idx = blockIdx.x*256 + threadIdx.x;   // over NB*DI*DS
  const size_t base = (size_t)(idx >> 4) * (NC*DS) + (idx & 15);
  float s = 0.f;
  #pragma unroll
  for (int c = 0; c < NC; ++c) {
    const size_t a = base + c*DS;
    const float P = PS[a], F = Fc[a];
    PS[a] = s;
    s = fmaf(P, s, F);
  }
}

// Pass B: rescan chunk from Sinit; fused C-dot + D*u + silu(z) gate -> y bf16.
__global__ __launch_bounds__(256) void scan_apply_kern(
    const float* __restrict__ delta, const float* __restrict__ u,
    const float* __restrict__ params, const float* __restrict__ xz,
    const float* __restrict__ A_log, const float* __restrict__ D_param,
    const float* __restrict__ Sinit, u16* __restrict__ y16)
{
  const int flat = blockIdx.x*256 + threadIdx.x;
  const int q  = flat & 3;
  const int ch = flat >> 2;
  const int d  = ch & (DI-1);
  const int c  = (ch >> 11) & (NC-1);
  const int b  = ch >> 15;
  const float4 al = *(const float4*)(A_log + d*DS + q*4);
  const float a0=-expf(al.x), a1=-expf(al.y), a2=-expf(al.z), a3=-expf(al.w);
  const float Dp = D_param[d];
  const size_t lbase = (size_t)b*LL + (size_t)c*CL;
  const float* dl = delta + lbase*DI + d;
  const float* uu = u     + lbase*DI + d;
  const float* pb = params + lbase*96 + DTR + q*4;
  const float* pc = params + lbase*96 + DTR + DS + q*4;
  const float* zp = xz + lbase*(2*DI) + DI + d;
  u16* yo = y16 + lbase*DI + d;
  const size_t base = (((size_t)(b*DI + d))*NC + c)*DS + q*4;
  const float4 s4 = *(const float4*)(Sinit + base);
  float s0=s4.x, s1=s4.y, s2=s4.z, s3=s4.w;
  #pragma unroll 4
  for (int l = 0; l < CL; ++l) {
    const float dt = dl[(size_t)l*DI];
    const float ut = uu[(size_t)l*DI];
    const float4 B4 = *(const float4*)(pb + l*96);
    const float4 C4 = *(const float4*)(pc + l*96);
    const float dtu = dt*ut;
    s0 = fmaf(__expf(dt*a0), s0, dtu*B4.x);
    s1 = fmaf(__expf(dt*a1), s1, dtu*B4.y);
    s2 = fmaf(__expf(dt*a2), s2, dtu*B4.z);
    s3 = fmaf(__expf(dt*a3), s3, dtu*B4.w);
    float part = s0*C4.x + s1*C4.y + s2*C4.z + s3*C4.w;
    part += __shfl_xor(part, 1);
    part += __shfl_xor(part, 2);
    if (q == 0) {
      const float z = zp[(size_t)l*(2*DI)];
      yo[(size_t)l*DI] = f2b((part + Dp*ut) * siluf_(z));
    }
  }
}

extern "C" void kernel_launch(void* const* d_in, const int* in_sizes, int n_in,
                              void* d_out, int out_size, void* d_ws, size_t ws_size,
                              hipStream_t stream)
{
  const float* x      = (const float*)d_in[0];
  const float* W_in   = (const float*)d_in[1];
  const float* conv_w = (const float*)d_in[2];
  const float* conv_b = (const float*)d_in[3];
  const float* W_x    = (const float*)d_in[4];
  const float* W_dt   = (const float*)d_in[5];
  const float* b_dt   = (const float*)d_in[6];
  const float* W_out  = (const float*)d_in[7];
  const float* A_log  = (const float*)d_in[8];
  const float* D_par  = (const float*)d_in[9];
  float* out = (float*)d_out;

  float* xz     = (float*)d_ws;             // MM*4096 f32 (32MB)
  float* u      = xz + (size_t)MM*2*DI;     // MM*DI f32 (16MB)
  float* params = u  + (size_t)MM*DI;       // MM*96 f32 (0.75MB)
  float* delta  = params + (size_t)MM*96;   // MM*DI f32 (16MB)
  u16*  pool    = (u16*)(delta + (size_t)MM*DI);
  // G1 phase:
  u16* xb16 = pool;                          // 2048*1024 (4MB), dead after G1
  u16* Wi_t = (u16*)out;                     // 4096*1024 bf16 = 8MB, in d_out
  // post-G1 phase (reuses pool):
  u16* Wd_t   = pool;                        // 2048*64
  u16* dltb16 = pool + (size_t)DI*DTR;       // 2048*64
  u16* Wo_t   = pool + (size_t)2*DI*DTR;     // 1024*2048 (4MB)
  u16* yb16   = pool + (size_t)2*DI*DTR + (size_t)DM*DI;  // 2048*2048 (8MB)
  // d_out staging (all dead before the final GEMM writes out):
  float* xpart = out;                        // [8][2048][96] f32 = 6.3MB (after G1)
  const size_t PFN = (size_t)NB*DI*NC*DS;    // 1048576 floats
  float* Pc    = out;                        // scan phase; becomes Sinit in-place
  float* Fc    = out + PFN;                  // Pc+Fc = exactly out_size floats

  dim3 blk(256);
  // convert x -> bf16; transpose-convert W_in -> [4096][1024] bf16 (in d_out)
  cvt_bf16_kern<<<(MM*DM/4 + 255)/256, blk, 0, stream>>>(x, DM, DM, xb16, MM);
  transpose_cvt_kern<<<dim3(2*DI/32, DM/32), blk, 0, stream>>>(W_in, Wi_t, DM, 2*DI);
  // G1: xz = x @ W_in   [2048 x 4096, K=1024]  (MFMA)
  gemm_bf16_kern<0><<<dim3(2*DI/128, MM/128), blk, 0, stream>>>(xb16, Wi_t, xz, MM, 2*DI, DM, nullptr);
  // conv + silu -> u
  conv_silu_kern<<<(MM*DI/4)/256, blk, 0, stream>>>(xz, conv_w, conv_b, u);
  // G2: params = u @ W_x  [2048 x 96, K=2048]  (fp32, K-split + reduce)
  xproj_part_kern<<<256*XSPLIT, blk, 0, stream>>>(u, W_x, xpart);
  xproj_reduce_kern<<<(MM*96/4)/256, blk, 0, stream>>>(xpart, params);
  // G3: delta = softplus(dlt @ W_dt + b_dt)  [2048 x 2048, K=64]  (MFMA)
  cvt_bf16_kern<<<(MM*DTR/4 + 255)/256, blk, 0, stream>>>(params, 96, DTR, dltb16, MM);
  transpose_cvt_kern<<<dim3(DI/32, DTR/32), blk, 0, stream>>>(W_dt, Wd_t, DTR, DI);
  gemm_bf16_kern<1><<<dim3(DI/128, MM/128), blk, 0, stream>>>(dltb16, Wd_t, delta, MM, DI, DTR, b_dt);
  // chunked scan (y written as bf16 to yb16)
  scan_local_kern<<<(NB*NC*DI*4)/256, blk, 0, stream>>>(delta, u, params, A_log, Pc, Fc);
  scan_combine_kern<<<(NB*DI*DS)/256, blk, 0, stream>>>(Pc, Fc);
  scan_apply_kern<<<(NB*NC*DI*4)/256, blk, 0, stream>>>(delta, u, params, xz, A_log, D_par, Pc, yb16);
  // G4: out = y @ W_out  [2048 x 1024, K=2048]  (MFMA)
  transpose_cvt_kern<<<dim3(DM/32, DI/32), blk, 0, stream>>>(W_out, Wo_t, DI, DM);
  gemm_bf16_kern<0><<<dim3(DM/128, MM/128), blk, 0, stream>>>(yb16, Wo_t, out, MM, DM, DI, nullptr);
}

// Round 7
// 249.098 us; speedup vs baseline: 5.1689x; 1.5193x over previous
//
#include <hip/hip_runtime.h>
#include <hip/hip_bf16.h>
#include <math.h>

#define DM 1024
#define DI 2048
#define DS 16
#define DTR 64
#define NB 2
#define LL 1024
#define MM (NB*LL)   // 2048
#define NC 16        // scan chunks
#define CL (LL/NC)   // 64
#define XSPLIT 8
#define XKC (DI/XSPLIT)  // 256

typedef unsigned short u16;
typedef __bf16 bf16x8 __attribute__((ext_vector_type(8)));
typedef float f32x4 __attribute__((ext_vector_type(4)));
typedef const __attribute__((address_space(1))) void gas_void;
typedef __attribute__((address_space(3))) void las_void;

__device__ __forceinline__ float sigmoidf_(float x){ return 1.f/(1.f+__expf(-x)); }
__device__ __forceinline__ float siluf_(float x){ return x*sigmoidf_(x); }
__device__ __forceinline__ float softplusf_(float x){ return fmaxf(x,0.f)+log1pf(__expf(-fabsf(x))); }
__device__ __forceinline__ u16 f2b(float f){
  __hip_bfloat16 h = __float2bfloat16(f);
  return __builtin_bit_cast(unsigned short, h);
}
// CK-style: LDS generic VA low 32 bits = LDS offset; AS(3) ptr is 32-bit.
__device__ __forceinline__ void gld16(const u16* g, u16* l){
  __builtin_amdgcn_global_load_lds(
      reinterpret_cast<gas_void*>((unsigned long long)g),
      reinterpret_cast<las_void*>((unsigned)(unsigned long long)l), 16, 0, 0);
}

// ---------------- bf16 MFMA GEMM, m97 structure ----------------
// C(+zz*M*N)[M][N] f32 = A[M][lda] * Bt[N][lda]^T over K range [zz*KS, (zz+1)*KS).
// 128x128 tile, BK=32, global_load_lds w16, linear LDS, XCD-swizzled 1-D grid.
template<int EPI>
__global__ __launch_bounds__(256) void gemm_mfma_kern(
    const u16* __restrict__ A, const u16* __restrict__ Bt,
    float* __restrict__ C, int M, int N, int lda, int KS, int TN, int TM,
    const float* __restrict__ bias)
{
  __shared__ __attribute__((aligned(16))) u16 As[128*32];
  __shared__ __attribute__((aligned(16))) u16 Bs[128*32];
  const unsigned tid = threadIdx.x;
  const unsigned l = tid & 63;
  const unsigned w = tid >> 6;
  const unsigned wm = w >> 1, wn = w & 1;      // 2x2 wave grid, 64x64 each
  // bijective XCD swizzle (gridDim.x % 8 == 0)
  const int q8  = (int)gridDim.x >> 3;
  const int id2 = ((int)blockIdx.x & 7) * q8 + ((int)blockIdx.x >> 3);
  const int zz  = id2 / (TN*TM);
  const int rr  = id2 % (TN*TM);
  const int bm  = (rr / TN) * 128;
  const int bn  = (rr % TN) * 128;
  const int kbeg = zz * KS;
  // staging: per wave, 2 calls/operand; lane covers 16B; LDS linear [row][32]
  const unsigned srow = l >> 2;                // 0..15 within 16-row group
  const unsigned scol = (l & 3) * 8;
  f32x4 acc[4][4] = {};
  for (int k0 = kbeg; k0 < kbeg + KS; k0 += 32) {
    #pragma unroll
    for (int i = 0; i < 2; ++i) {
      const unsigned rb = (w*2 + i)*16;
      gld16(A  + (size_t)(bm + rb + srow)*lda + k0 + scol, As + (w*2+i)*512);
      gld16(Bt + (size_t)(bn + rb + srow)*lda + k0 + scol, Bs + (w*2+i)*512);
    }
    __syncthreads();                            // vmcnt(0) drained before barrier
    bf16x8 af[4], bfr[4];
    #pragma unroll
    for (int m = 0; m < 4; ++m)
      af[m] = *(const bf16x8*)(As + (wm*64 + m*16 + (l & 15))*32 + (l >> 4)*8);
    #pragma unroll
    for (int n = 0; n < 4; ++n)
      bfr[n] = *(const bf16x8*)(Bs + (wn*64 + n*16 + (l & 15))*32 + (l >> 4)*8);
    #pragma unroll
    for (int m = 0; m < 4; ++m)
      #pragma unroll
      for (int n = 0; n < 4; ++n)
        acc[m][n] = __builtin_amdgcn_mfma_f32_16x16x32_bf16(af[m], bfr[n], acc[m][n], 0, 0, 0);
    __syncthreads();                            // reads done before next overwrite
  }
  float* Cz = C + (size_t)zz*M*N;
  #pragma unroll
  for (int m = 0; m < 4; ++m) {
    #pragma unroll
    for (int n = 0; n < 4; ++n) {
      const int col = bn + wn*64 + n*16 + (l & 15);
      const float bs = (EPI == 1) ? bias[col] : 0.f;
      #pragma unroll
      for (int q = 0; q < 4; ++q) {
        const int row = bm + wm*64 + m*16 + (l >> 4)*4 + q;
        float v = acc[m][n][q];
        if (EPI == 1) v = softplusf_(v + bs);
        Cz[(size_t)row*N + col] = v;
      }
    }
  }
}

// fixed-order sum of 4 split-K partials (deterministic)
__global__ __launch_bounds__(256) void reduce4_kern(
    const float* __restrict__ part, float* __restrict__ out)
{
  const size_t i = ((size_t)blockIdx.x*256 + threadIdx.x) * 4;
  float4 s = *(const float4*)(part + i);
  #pragma unroll
  for (int ks = 1; ks < 4; ++ks) {
    const float4 v = *(const float4*)(part + (size_t)ks*MM*DM + i);
    s.x+=v.x; s.y+=v.y; s.z+=v.z; s.w+=v.w;
  }
  *(float4*)(out + i) = s;
}

// transpose + convert: in [R][C] f32 -> out [C][R] bf16. grid(C/32, R/32).
__global__ __launch_bounds__(256) void transpose_cvt_kern(
    const float* __restrict__ in, u16* __restrict__ out, int R, int C)
{
  __shared__ float tile[32][33];
  const int r0 = blockIdx.y*32, c0 = blockIdx.x*32;
  const int tr = threadIdx.x >> 3, tc4 = (threadIdx.x & 7) * 4;
  float4 v = *(const float4*)(in + (size_t)(r0+tr)*C + c0 + tc4);
  tile[tr][tc4+0] = v.x; tile[tr][tc4+1] = v.y;
  tile[tr][tc4+2] = v.z; tile[tr][tc4+3] = v.w;
  __syncthreads();
  ushort4 o;
  o.x = f2b(tile[tc4+0][tr]);
  o.y = f2b(tile[tc4+1][tr]);
  o.z = f2b(tile[tc4+2][tr]);
  o.w = f2b(tile[tc4+3][tr]);
  *(ushort4*)(out + (size_t)(c0+tr)*R + r0 + tc4) = o;
}

// strided convert: out[row][0..C) bf16 = in[row*ld .. +C). C mult of 4.
__global__ __launch_bounds__(256) void cvt_bf16_kern(
    const float* __restrict__ in, int ld, int C, u16* __restrict__ out, int rows)
{
  const int i = blockIdx.x*256 + threadIdx.x;           // over rows*C/4
  if (i >= rows*(C/4)) return;
  const int row = i / (C/4);
  const int cq  = (i % (C/4)) * 4;
  float4 v = *(const float4*)(in + (size_t)row*ld + cq);
  ushort4 o; o.x=f2b(v.x); o.y=f2b(v.y); o.z=f2b(v.z); o.w=f2b(v.w);
  *(ushort4*)(out + (size_t)row*C + cq) = o;
}

// ---------------- x-proj (G2), K-split fp32 ----------------
__global__ __launch_bounds__(256) void xproj_part_kern(
    const float* __restrict__ u, const float* __restrict__ W_x,
    float* __restrict__ part)
{
  __shared__ __align__(16) float As[8][XKC];   // 8KB
  const int tid = threadIdx.x;
  const int m0 = (blockIdx.x & 255) * 8;
  const int ks = blockIdx.x >> 8;
  const int k0 = ks * XKC;
  #pragma unroll
  for (int i = 0; i < 2; ++i) {
    const int flat = i*1024 + tid*4;
    const int rr = flat >> 8, cc = flat & (XKC-1);
    *(float4*)&As[rr][cc] = *(const float4*)(u + (size_t)(m0+rr)*DI + k0 + cc);
  }
  __syncthreads();
  const int r = tid >> 5, c = tid & 31;
  float a0=0.f, a1=0.f, a2=0.f;
  #pragma unroll 8
  for (int k = 0; k < XKC; ++k) {
    const float a = As[r][k];
    const float* w = W_x + (size_t)(k0+k)*96 + c;
    a0 = fmaf(a, w[0],  a0);
    a1 = fmaf(a, w[32], a1);
    a2 = fmaf(a, w[64], a2);
  }
  float* p = part + ((size_t)ks*MM + m0 + r)*96 + c;
  p[0]=a0; p[32]=a1; p[64]=a2;
}

__global__ __launch_bounds__(256) void xproj_reduce_kern(
    const float* __restrict__ part, float* __restrict__ params)
{
  const int i = blockIdx.x*256 + threadIdx.x;   // over MM*96/4
  float4 s = {0.f,0.f,0.f,0.f};
  #pragma unroll
  for (int ks = 0; ks < XSPLIT; ++ks) {
    float4 v = *(const float4*)(part + (size_t)ks*MM*96 + (size_t)i*4);
    s.x+=v.x; s.y+=v.y; s.z+=v.z; s.w+=v.w;
  }
  *(float4*)(params + (size_t)i*4) = s;
}

// Causal depthwise conv (D_CONV=4) + SiLU, float4 over d (4 channels/thread).
__global__ __launch_bounds__(256) void conv_silu_kern(
    const float* __restrict__ xz, const float* __restrict__ conv_w,
    const float* __restrict__ conv_b, float* __restrict__ u)
{
  const int idx = blockIdx.x * 256 + threadIdx.x;   // over MM*DI/4
  const int d4 = (idx & (DI/4 - 1)) * 4;
  const int ml = idx >> 9;
  const int l  = ml & (LL-1);
  const int base = ml - l;
  const float4 w0 = *(const float4*)(conv_w + (d4+0)*4);
  const float4 w1 = *(const float4*)(conv_w + (d4+1)*4);
  const float4 w2 = *(const float4*)(conv_w + (d4+2)*4);
  const float4 w3 = *(const float4*)(conv_w + (d4+3)*4);
  const float wt[4][4] = {{w0.x,w0.y,w0.z,w0.w},{w1.x,w1.y,w1.z,w1.w},
                          {w2.x,w2.y,w2.z,w2.w},{w3.x,w3.y,w3.z,w3.w}};
  float4 acc = *(const float4*)(conv_b + d4);
  #pragma unroll
  for (int j = 0; j < 4; ++j) {
    const int ls = l - 3 + j;
    if (ls >= 0) {
      const float4 v = *(const float4*)(xz + (size_t)(base + ls)*(2*DI) + d4);
      acc.x = fmaf(v.x, wt[0][j], acc.x);
      acc.y = fmaf(v.y, wt[1][j], acc.y);
      acc.z = fmaf(v.z, wt[2][j], acc.z);
      acc.w = fmaf(v.w, wt[3][j], acc.w);
    }
  }
  float4 o;
  o.x = siluf_(acc.x); o.y = siluf_(acc.y);
  o.z = siluf_(acc.z); o.w = siluf_(acc.w);
  *(float4*)(u + (size_t)idx*4) = o;
}

// ---- chunk-parallel selective scan: 4 lanes/channel, 4 states/lane ----
__global__ __launch_bounds__(256) void scan_local_kern(
    const float* __restrict__ delta, const float* __restrict__ u,
    const float* __restrict__ params, const float* __restrict__ A_log,
    float* __restrict__ Pc, float* __restrict__ Fc)
{
  const int flat = blockIdx.x*256 + threadIdx.x;
  const int q  = flat & 3;
  const int ch = flat >> 2;
  const int d  = ch & (DI-1);
  const int c  = (ch >> 11) & (NC-1);
  const int b  = ch >> 15;
  const float4 al = *(const float4*)(A_log + d*DS + q*4);
  const float a0=-expf(al.x), a1=-expf(al.y), a2=-expf(al.z), a3=-expf(al.w);
  const size_t lbase = (size_t)b*LL + (size_t)c*CL;
  const float* dl = delta + lbase*DI + d;
  const float* uu = u     + lbase*DI + d;
  const float* pr = params + lbase*96 + DTR + q*4;
  float s0=0.f,s1=0.f,s2=0.f,s3=0.f, dtsum=0.f;
  #pragma unroll 4
  for (int l = 0; l < CL; ++l) {
    const float dt = dl[(size_t)l*DI];
    const float ut = uu[(size_t)l*DI];
    const float4 B4 = *(const float4*)(pr + l*96);
    const float dtu = dt*ut;
    s0 = fmaf(__expf(dt*a0), s0, dtu*B4.x);
    s1 = fmaf(__expf(dt*a1), s1, dtu*B4.y);
    s2 = fmaf(__expf(dt*a2), s2, dtu*B4.z);
    s3 = fmaf(__expf(dt*a3), s3, dtu*B4.w);
    dtsum += dt;
  }
  const size_t base = (((size_t)(b*DI + d))*NC + c)*DS + q*4;
  float4 P4; P4.x=__expf(dtsum*a0); P4.y=__expf(dtsum*a1);
  P4.z=__expf(dtsum*a2); P4.w=__expf(dtsum*a3);
  *(float4*)(Pc + base) = P4;
  *(float4*)(Fc + base) = make_float4(s0,s1,s2,s3);
}

// Combine: per (b,d,n), sequential over NC chunks. PS = Pc-in / Sinit-out.
__global__ __launch_bounds__(256) void scan_combine_kern(
    float* __restrict__ PS, const float* __restrict__ Fc)
{
  const int idx = blockIdx.x*256 + threadIdx.x;   // over NB*DI*DS
  const size_t base = (size_t)(idx >> 4) * (NC*DS) + (idx & 15);
  float s = 0.f;
  #pragma unroll
  for (int c = 0; c < NC; ++c) {
    const size_t a = base + c*DS;
    const float P = PS[a], F = Fc[a];
    PS[a] = s;
    s = fmaf(P, s, F);
  }
}

// Pass B: rescan chunk from Sinit; fused C-dot + D*u + silu(z) gate -> y bf16.
__global__ __launch_bounds__(256) void scan_apply_kern(
    const float* __restrict__ delta, const float* __restrict__ u,
    const float* __restrict__ params, const float* __restrict__ xz,
    const float* __restrict__ A_log, const float* __restrict__ D_param,
    const float* __restrict__ Sinit, u16* __restrict__ y16)
{
  const int flat = blockIdx.x*256 + threadIdx.x;
  const int q  = flat & 3;
  const int ch = flat >> 2;
  const int d  = ch & (DI-1);
  const int c  = (ch >> 11) & (NC-1);
  const int b  = ch >> 15;
  const float4 al = *(const float4*)(A_log + d*DS + q*4);
  const float a0=-expf(al.x), a1=-expf(al.y), a2=-expf(al.z), a3=-expf(al.w);
  const float Dp = D_param[d];
  const size_t lbase = (size_t)b*LL + (size_t)c*CL;
  const float* dl = delta + lbase*DI + d;
  const float* uu = u     + lbase*DI + d;
  const float* pb = params + lbase*96 + DTR + q*4;
  const float* pc = params + lbase*96 + DTR + DS + q*4;
  const float* zp = xz + lbase*(2*DI) + DI + d;
  u16* yo = y16 + lbase*DI + d;
  const size_t base = (((size_t)(b*DI + d))*NC + c)*DS + q*4;
  const float4 s4 = *(const float4*)(Sinit + base);
  float s0=s4.x, s1=s4.y, s2=s4.z, s3=s4.w;
  #pragma unroll 4
  for (int l = 0; l < CL; ++l) {
    const float dt = dl[(size_t)l*DI];
    const float ut = uu[(size_t)l*DI];
    const float4 B4 = *(const float4*)(pb + l*96);
    const float4 C4 = *(const float4*)(pc + l*96);
    const float dtu = dt*ut;
    s0 = fmaf(__expf(dt*a0), s0, dtu*B4.x);
    s1 = fmaf(__expf(dt*a1), s1, dtu*B4.y);
    s2 = fmaf(__expf(dt*a2), s2, dtu*B4.z);
    s3 = fmaf(__expf(dt*a3), s3, dtu*B4.w);
    float part = s0*C4.x + s1*C4.y + s2*C4.z + s3*C4.w;
    part += __shfl_xor(part, 1);
    part += __shfl_xor(part, 2);
    if (q == 0) {
      const float z = zp[(size_t)l*(2*DI)];
      yo[(size_t)l*DI] = f2b((part + Dp*ut) * siluf_(z));
    }
  }
}

extern "C" void kernel_launch(void* const* d_in, const int* in_sizes, int n_in,
                              void* d_out, int out_size, void* d_ws, size_t ws_size,
                              hipStream_t stream)
{
  const float* x      = (const float*)d_in[0];
  const float* W_in   = (const float*)d_in[1];
  const float* conv_w = (const float*)d_in[2];
  const float* conv_b = (const float*)d_in[3];
  const float* W_x    = (const float*)d_in[4];
  const float* W_dt   = (const float*)d_in[5];
  const float* b_dt   = (const float*)d_in[6];
  const float* W_out  = (const float*)d_in[7];
  const float* A_log  = (const float*)d_in[8];
  const float* D_par  = (const float*)d_in[9];
  float* out = (float*)d_out;

  float* xz     = (float*)d_ws;             // MM*4096 f32 (32MB)
  float* u      = xz + (size_t)MM*2*DI;     // MM*DI f32 (16MB)
  float* params = u  + (size_t)MM*DI;       // MM*96 f32 (0.75MB)
  float* delta  = params + (size_t)MM*96;   // MM*DI f32 (16MB)
  u16*  pool    = (u16*)(delta + (size_t)MM*DI);
  // G1 phase:
  u16* xb16 = pool;                          // 2048*1024 (4MB), dead after G1
  u16* Wi_t = (u16*)out;                     // 4096*1024 bf16 = 8MB, in d_out
  // post-G1 phase (reuses pool):
  u16* Wd_t   = pool;                        // 2048*64
  u16* dltb16 = pool + (size_t)DI*DTR;       // 2048*64
  u16* Wo_t   = pool + (size_t)2*DI*DTR;     // 1024*2048 (4MB)
  u16* yb16   = pool + (size_t)2*DI*DTR + (size_t)DM*DI;  // 2048*2048 (8MB)
  // d_out staging (all dead before the final reduce writes out):
  float* xpart = out;                        // [8][2048][96] f32 = 6.3MB (after G1)
  const size_t PFN = (size_t)NB*DI*NC*DS;    // 1048576 floats
  float* Pc    = out;                        // scan phase; becomes Sinit in-place
  float* Fc    = out + PFN;                  // Pc+Fc = exactly out_size floats
  // G4 split-K partials in xz region (dead after scan_apply): 4*MM*DM*4B = 32MB
  float* g4part = xz;

  dim3 blk(256);
  // convert x -> bf16; transpose-convert W_in -> [4096][1024] bf16 (in d_out)
  cvt_bf16_kern<<<(MM*DM/4 + 255)/256, blk, 0, stream>>>(x, DM, DM, xb16, MM);
  transpose_cvt_kern<<<dim3(2*DI/32, DM/32), blk, 0, stream>>>(W_in, Wi_t, DM, 2*DI);
  // G1: xz = x @ W_in   [2048 x 4096, K=1024]  (MFMA, m97 structure)
  gemm_mfma_kern<0><<<512, blk, 0, stream>>>(xb16, Wi_t, xz, MM, 2*DI, DM, DM, 32, 16, nullptr);
  // conv + silu -> u
  conv_silu_kern<<<(MM*DI/4)/256, blk, 0, stream>>>(xz, conv_w, conv_b, u);
  // G2: params = u @ W_x  [2048 x 96, K=2048]  (fp32, K-split + reduce)
  xproj_part_kern<<<256*XSPLIT, blk, 0, stream>>>(u, W_x, xpart);
  xproj_reduce_kern<<<(MM*96/4)/256, blk, 0, stream>>>(xpart, params);
  // G3: delta = softplus(dlt @ W_dt + b_dt)  [2048 x 2048, K=64]  (MFMA)
  cvt_bf16_kern<<<(MM*DTR/4 + 255)/256, blk, 0, stream>>>(params, 96, DTR, dltb16, MM);
  transpose_cvt_kern<<<dim3(DI/32, DTR/32), blk, 0, stream>>>(W_dt, Wd_t, DTR, DI);
  gemm_mfma_kern<1><<<256, blk, 0, stream>>>(dltb16, Wd_t, delta, MM, DI, DTR, DTR, 16, 16, b_dt);
  // chunked scan (y written as bf16 to yb16)
  scan_local_kern<<<(NB*NC*DI*4)/256, blk, 0, stream>>>(delta, u, params, A_log, Pc, Fc);
  scan_combine_kern<<<(NB*DI*DS)/256, blk, 0, stream>>>(Pc, Fc);
  scan_apply_kern<<<(NB*NC*DI*4)/256, blk, 0, stream>>>(delta, u, params, xz, A_log, D_par, Pc, yb16);
  // G4: out = y @ W_out  [2048 x 1024, K=2048]  (MFMA, split-K=4 -> reduce)
  transpose_cvt_kern<<<dim3(DM/32, DI/32), blk, 0, stream>>>(W_out, Wo_t, DI, DM);
  gemm_mfma_kern<0><<<512, blk, 0, stream>>>(yb16, Wo_t, g4part, MM, DM, DI, DI/4, 8, 16, nullptr);
  reduce4_kern<<<(MM*DM/4)/256, blk, 0, stream>>>(g4part, out);
}

// Round 8
// 237.132 us; speedup vs baseline: 5.4297x; 1.0505x over previous
//
#include <hip/hip_runtime.h>
#include <hip/hip_bf16.h>
#include <math.h>

#define DM 1024
#define DI 2048
#define DS 16
#define DTR 64
#define NB 2
#define LL 1024
#define MM (NB*LL)   // 2048
#define NC 16        // scan chunks
#define CL (LL/NC)   // 64
#define XSPLIT 8
#define XKC (DI/XSPLIT)  // 256

typedef unsigned short u16;
typedef __bf16 bf16x8 __attribute__((ext_vector_type(8)));
typedef float f32x4 __attribute__((ext_vector_type(4)));
typedef const __attribute__((address_space(1))) void gas_void;
typedef __attribute__((address_space(3))) void las_void;

__device__ __forceinline__ float sigmoidf_(float x){ return 1.f/(1.f+__expf(-x)); }
__device__ __forceinline__ float siluf_(float x){ return x*sigmoidf_(x); }
__device__ __forceinline__ float softplusf_(float x){ return fmaxf(x,0.f)+__logf(1.f+__expf(-fabsf(x))); }
__device__ __forceinline__ u16 f2b(float f){
  __hip_bfloat16 h = __float2bfloat16(f);
  return __builtin_bit_cast(unsigned short, h);
}
// CK-style: LDS generic VA low 32 bits = LDS offset; AS(3) ptr is 32-bit.
__device__ __forceinline__ void gld16(const u16* g, u16* l){
  __builtin_amdgcn_global_load_lds(
      reinterpret_cast<gas_void*>((unsigned long long)g),
      reinterpret_cast<las_void*>((unsigned)(unsigned long long)l), 16, 0, 0);
}

// ---------------- bf16 MFMA GEMM, m97 structure ----------------
// C(+zz*M*N)[M][N] f32 = A[M][lda] * Bt[N][lda]^T over K range [zz*KS, (zz+1)*KS).
__global__ __launch_bounds__(256) void gemm_mfma_kern(
    const u16* __restrict__ A, const u16* __restrict__ Bt,
    float* __restrict__ C, int M, int N, int lda, int KS, int TN, int TM)
{
  __shared__ __attribute__((aligned(16))) u16 As[128*32];
  __shared__ __attribute__((aligned(16))) u16 Bs[128*32];
  const unsigned tid = threadIdx.x;
  const unsigned l = tid & 63;
  const unsigned w = tid >> 6;
  const unsigned wm = w >> 1, wn = w & 1;      // 2x2 wave grid, 64x64 each
  // bijective XCD swizzle (gridDim.x % 8 == 0)
  const int q8  = (int)gridDim.x >> 3;
  const int id2 = ((int)blockIdx.x & 7) * q8 + ((int)blockIdx.x >> 3);
  const int zz  = id2 / (TN*TM);
  const int rr  = id2 % (TN*TM);
  const int bm  = (rr / TN) * 128;
  const int bn  = (rr % TN) * 128;
  const int kbeg = zz * KS;
  const unsigned srow = l >> 2;
  const unsigned scol = (l & 3) * 8;
  f32x4 acc[4][4] = {};
  for (int k0 = kbeg; k0 < kbeg + KS; k0 += 32) {
    #pragma unroll
    for (int i = 0; i < 2; ++i) {
      const unsigned rb = (w*2 + i)*16;
      gld16(A  + (size_t)(bm + rb + srow)*lda + k0 + scol, As + (w*2+i)*512);
      gld16(Bt + (size_t)(bn + rb + srow)*lda + k0 + scol, Bs + (w*2+i)*512);
    }
    __syncthreads();
    bf16x8 af[4], bfr[4];
    #pragma unroll
    for (int m = 0; m < 4; ++m)
      af[m] = *(const bf16x8*)(As + (wm*64 + m*16 + (l & 15))*32 + (l >> 4)*8);
    #pragma unroll
    for (int n = 0; n < 4; ++n)
      bfr[n] = *(const bf16x8*)(Bs + (wn*64 + n*16 + (l & 15))*32 + (l >> 4)*8);
    #pragma unroll
    for (int m = 0; m < 4; ++m)
      #pragma unroll
      for (int n = 0; n < 4; ++n)
        acc[m][n] = __builtin_amdgcn_mfma_f32_16x16x32_bf16(af[m], bfr[n], acc[m][n], 0, 0, 0);
    __syncthreads();
  }
  float* Cz = C + (size_t)zz*M*N;
  #pragma unroll
  for (int m = 0; m < 4; ++m) {
    #pragma unroll
    for (int n = 0; n < 4; ++n) {
      const int col = bn + wn*64 + n*16 + (l & 15);
      #pragma unroll
      for (int q = 0; q < 4; ++q) {
        const int row = bm + wm*64 + m*16 + (l >> 4)*4 + q;
        Cz[(size_t)row*N + col] = acc[m][n][q];
      }
    }
  }
}

// fixed-order sum of 4 split-K partials (deterministic)
__global__ __launch_bounds__(256) void reduce4_kern(
    const float* __restrict__ part, float* __restrict__ out)
{
  const size_t i = ((size_t)blockIdx.x*256 + threadIdx.x) * 4;
  float4 s = *(const float4*)(part + i);
  #pragma unroll
  for (int ks = 1; ks < 4; ++ks) {
    const float4 v = *(const float4*)(part + (size_t)ks*MM*DM + i);
    s.x+=v.x; s.y+=v.y; s.z+=v.z; s.w+=v.w;
  }
  *(float4*)(out + i) = s;
}

// ---------------- dt-proj (G3), fp32 one-pass ----------------
// delta[M][DI] = softplus(dlt[M][0:64] @ W_dt[64][DI] + b_dt), dlt = params cols 0..63.
// block: 32 rows x 128 cols; K=64 entirely in LDS; 4x4 f32 tile/thread.
__global__ __launch_bounds__(256) void dtproj_kern(
    const float* __restrict__ params, const float* __restrict__ W_dt,
    const float* __restrict__ b_dt, float* __restrict__ delta)
{
  __shared__ __align__(16) float Ad[32][DTR];    // 8KB
  __shared__ __align__(16) float Wd[DTR][128];   // 32KB
  const int tid = threadIdx.x;
  const int m0 = (blockIdx.x >> 4) * 32;
  const int c0 = (blockIdx.x & 15) * 128;
  #pragma unroll
  for (int i = 0; i < 2; ++i) {
    const int fq = i*256 + tid;                  // float4 index, 512 total
    const int r = fq >> 4, q = fq & 15;
    *(float4*)&Ad[r][q*4] = *(const float4*)(params + (size_t)(m0+r)*96 + q*4);
  }
  #pragma unroll
  for (int i = 0; i < 8; ++i) {
    const int fq = i*256 + tid;                  // 2048 total
    const int r = fq >> 5, q = fq & 31;
    *(float4*)&Wd[r][q*4] = *(const float4*)(W_dt + (size_t)r*DI + c0 + q*4);
  }
  __syncthreads();
  const int tr = tid >> 5;                       // 0..7 -> rows tr*4..+3
  const int tc = tid & 31;                       // cols tc*4..+3
  f32x4 acc[4] = {};
  #pragma unroll
  for (int k0 = 0; k0 < DTR; k0 += 4) {
    float4 a[4], wv[4];
    #pragma unroll
    for (int i = 0; i < 4; ++i) a[i] = *(const float4*)&Ad[tr*4+i][k0];
    #pragma unroll
    for (int j = 0; j < 4; ++j) wv[j] = *(const float4*)&Wd[k0+j][tc*4];
    #pragma unroll
    for (int i = 0; i < 4; ++i) {
      const float ai[4] = {a[i].x, a[i].y, a[i].z, a[i].w};
      #pragma unroll
      for (int j = 0; j < 4; ++j) {
        acc[i][0] = fmaf(ai[j], wv[j].x, acc[i][0]);
        acc[i][1] = fmaf(ai[j], wv[j].y, acc[i][1]);
        acc[i][2] = fmaf(ai[j], wv[j].z, acc[i][2]);
        acc[i][3] = fmaf(ai[j], wv[j].w, acc[i][3]);
      }
    }
  }
  const float4 b4 = *(const float4*)(b_dt + c0 + tc*4);
  #pragma unroll
  for (int i = 0; i < 4; ++i) {
    float4 o;
    o.x = softplusf_(acc[i][0] + b4.x);
    o.y = softplusf_(acc[i][1] + b4.y);
    o.z = softplusf_(acc[i][2] + b4.z);
    o.w = softplusf_(acc[i][3] + b4.w);
    *(float4*)(delta + (size_t)(m0 + tr*4 + i)*DI + c0 + tc*4) = o;
  }
}

// transpose + convert: in [R][C] f32 -> out [C][R] bf16. grid(C/32, R/32).
__global__ __launch_bounds__(256) void transpose_cvt_kern(
    const float* __restrict__ in, u16* __restrict__ out, int R, int C)
{
  __shared__ float tile[32][33];
  const int r0 = blockIdx.y*32, c0 = blockIdx.x*32;
  const int tr = threadIdx.x >> 3, tc4 = (threadIdx.x & 7) * 4;
  float4 v = *(const float4*)(in + (size_t)(r0+tr)*C + c0 + tc4);
  tile[tr][tc4+0] = v.x; tile[tr][tc4+1] = v.y;
  tile[tr][tc4+2] = v.z; tile[tr][tc4+3] = v.w;
  __syncthreads();
  ushort4 o;
  o.x = f2b(tile[tc4+0][tr]);
  o.y = f2b(tile[tc4+1][tr]);
  o.z = f2b(tile[tc4+2][tr]);
  o.w = f2b(tile[tc4+3][tr]);
  *(ushort4*)(out + (size_t)(c0+tr)*R + r0 + tc4) = o;
}

// strided convert: out[row][0..C) bf16 = in[row*ld .. +C). C mult of 4.
__global__ __launch_bounds__(256) void cvt_bf16_kern(
    const float* __restrict__ in, int ld, int C, u16* __restrict__ out, int rows)
{
  const int i = blockIdx.x*256 + threadIdx.x;           // over rows*C/4
  if (i >= rows*(C/4)) return;
  const int row = i / (C/4);
  const int cq  = (i % (C/4)) * 4;
  float4 v = *(const float4*)(in + (size_t)row*ld + cq);
  ushort4 o; o.x=f2b(v.x); o.y=f2b(v.y); o.z=f2b(v.z); o.w=f2b(v.w);
  *(ushort4*)(out + (size_t)row*C + cq) = o;
}

// ---------------- x-proj (G2), K-split fp32 ----------------
__global__ __launch_bounds__(256) void xproj_part_kern(
    const float* __restrict__ u, const float* __restrict__ W_x,
    float* __restrict__ part)
{
  __shared__ __align__(16) float As[8][XKC];   // 8KB
  const int tid = threadIdx.x;
  const int m0 = (blockIdx.x & 255) * 8;
  const int ks = blockIdx.x >> 8;
  const int k0 = ks * XKC;
  #pragma unroll
  for (int i = 0; i < 2; ++i) {
    const int flat = i*1024 + tid*4;
    const int rr = flat >> 8, cc = flat & (XKC-1);
    *(float4*)&As[rr][cc] = *(const float4*)(u + (size_t)(m0+rr)*DI + k0 + cc);
  }
  __syncthreads();
  const int r = tid >> 5, c = tid & 31;
  float a0=0.f, a1=0.f, a2=0.f;
  #pragma unroll 8
  for (int k = 0; k < XKC; ++k) {
    const float a = As[r][k];
    const float* w = W_x + (size_t)(k0+k)*96 + c;
    a0 = fmaf(a, w[0],  a0);
    a1 = fmaf(a, w[32], a1);
    a2 = fmaf(a, w[64], a2);
  }
  float* p = part + ((size_t)ks*MM + m0 + r)*96 + c;
  p[0]=a0; p[32]=a1; p[64]=a2;
}

__global__ __launch_bounds__(256) void xproj_reduce_kern(
    const float* __restrict__ part, float* __restrict__ params)
{
  const int i = blockIdx.x*256 + threadIdx.x;   // over MM*96/4
  float4 s = {0.f,0.f,0.f,0.f};
  #pragma unroll
  for (int ks = 0; ks < XSPLIT; ++ks) {
    float4 v = *(const float4*)(part + (size_t)ks*MM*96 + (size_t)i*4);
    s.x+=v.x; s.y+=v.y; s.z+=v.z; s.w+=v.w;
  }
  *(float4*)(params + (size_t)i*4) = s;
}

// Causal depthwise conv (D_CONV=4) + SiLU, float4 over d (4 channels/thread).
__global__ __launch_bounds__(256) void conv_silu_kern(
    const float* __restrict__ xz, const float* __restrict__ conv_w,
    const float* __restrict__ conv_b, float* __restrict__ u)
{
  const int idx = blockIdx.x * 256 + threadIdx.x;   // over MM*DI/4
  const int d4 = (idx & (DI/4 - 1)) * 4;
  const int ml = idx >> 9;
  const int l  = ml & (LL-1);
  const int base = ml - l;
  const float4 w0 = *(const float4*)(conv_w + (d4+0)*4);
  const float4 w1 = *(const float4*)(conv_w + (d4+1)*4);
  const float4 w2 = *(const float4*)(conv_w + (d4+2)*4);
  const float4 w3 = *(const float4*)(conv_w + (d4+3)*4);
  const float wt[4][4] = {{w0.x,w0.y,w0.z,w0.w},{w1.x,w1.y,w1.z,w1.w},
                          {w2.x,w2.y,w2.z,w2.w},{w3.x,w3.y,w3.z,w3.w}};
  float4 acc = *(const float4*)(conv_b + d4);
  #pragma unroll
  for (int j = 0; j < 4; ++j) {
    const int ls = l - 3 + j;
    if (ls >= 0) {
      const float4 v = *(const float4*)(xz + (size_t)(base + ls)*(2*DI) + d4);
      acc.x = fmaf(v.x, wt[0][j], acc.x);
      acc.y = fmaf(v.y, wt[1][j], acc.y);
      acc.z = fmaf(v.z, wt[2][j], acc.z);
      acc.w = fmaf(v.w, wt[3][j], acc.w);
    }
  }
  float4 o;
  o.x = siluf_(acc.x); o.y = siluf_(acc.y);
  o.z = siluf_(acc.z); o.w = siluf_(acc.w);
  *(float4*)(u + (size_t)idx*4) = o;
}

// ---- chunk-parallel selective scan: 4 lanes/channel, 4 states/lane ----
__global__ __launch_bounds__(256) void scan_local_kern(
    const float* __restrict__ delta, const float* __restrict__ u,
    const float* __restrict__ params, const float* __restrict__ A_log,
    float* __restrict__ Pc, float* __restrict__ Fc)
{
  const int flat = blockIdx.x*256 + threadIdx.x;
  const int q  = flat & 3;
  const int ch = flat >> 2;
  const int d  = ch & (DI-1);
  const int c  = (ch >> 11) & (NC-1);
  const int b  = ch >> 15;
  const float4 al = *(const float4*)(A_log + d*DS + q*4);
  const float a0=-expf(al.x), a1=-expf(al.y), a2=-expf(al.z), a3=-expf(al.w);
  const size_t lbase = (size_t)b*LL + (size_t)c*CL;
  const float* dl = delta + lbase*DI + d;
  const float* uu = u     + lbase*DI + d;
  const float* pr = params + lbase*96 + DTR + q*4;
  float s0=0.f,s1=0.f,s2=0.f,s3=0.f, dtsum=0.f;
  #pragma unroll 4
  for (int l = 0; l < CL; ++l) {
    const float dt = dl[(size_t)l*DI];
    const float ut = uu[(size_t)l*DI];
    const float4 B4 = *(const float4*)(pr + l*96);
    const float dtu = dt*ut;
    s0 = fmaf(__expf(dt*a0), s0, dtu*B4.x);
    s1 = fmaf(__expf(dt*a1), s1, dtu*B4.y);
    s2 = fmaf(__expf(dt*a2), s2, dtu*B4.z);
    s3 = fmaf(__expf(dt*a3), s3, dtu*B4.w);
    dtsum += dt;
  }
  const size_t base = (((size_t)(b*DI + d))*NC + c)*DS + q*4;
  float4 P4; P4.x=__expf(dtsum*a0); P4.y=__expf(dtsum*a1);
  P4.z=__expf(dtsum*a2); P4.w=__expf(dtsum*a3);
  *(float4*)(Pc + base) = P4;
  *(float4*)(Fc + base) = make_float4(s0,s1,s2,s3);
}

// Combine: per (b,d,n), sequential over NC chunks. PS = Pc-in / Sinit-out.
__global__ __launch_bounds__(256) void scan_combine_kern(
    float* __restrict__ PS, const float* __restrict__ Fc)
{
  const int idx = blockIdx.x*256 + threadIdx.x;   // over NB*DI*DS
  const size_t base = (size_t)(idx >> 4) * (NC*DS) + (idx & 15);
  float s = 0.f;
  #pragma unroll
  for (int c = 0; c < NC; ++c) {
    const size_t a = base + c*DS;
    const float P = PS[a], F = Fc[a];
    PS[a] = s;
    s = fmaf(P, s, F);
  }
}

// Pass B: rescan chunk from Sinit; fused C-dot + D*u + silu(z) gate -> y bf16.
__global__ __launch_bounds__(256) void scan_apply_kern(
    const float* __restrict__ delta, const float* __restrict__ u,
    const float* __restrict__ params, const float* __restrict__ xz,
    const float* __restrict__ A_log, const float* __restrict__ D_param,
    const float* __restrict__ Sinit, u16* __restrict__ y16)
{
  const int flat = blockIdx.x*256 + threadIdx.x;
  const int q  = flat & 3;
  const int ch = flat >> 2;
  const int d  = ch & (DI-1);
  const int c  = (ch >> 11) & (NC-1);
  const int b  = ch >> 15;
  const float4 al = *(const float4*)(A_log + d*DS + q*4);
  const float a0=-expf(al.x), a1=-expf(al.y), a2=-expf(al.z), a3=-expf(al.w);
  const float Dp = D_param[d];
  const size_t lbase = (size_t)b*LL + (size_t)c*CL;
  const float* dl = delta + lbase*DI + d;
  const float* uu = u     + lbase*DI + d;
  const float* pb = params + lbase*96 + DTR + q*4;
  const float* pc = params + lbase*96 + DTR + DS + q*4;
  const float* zp = xz + lbase*(2*DI) + DI + d;
  u16* yo = y16 + lbase*DI + d;
  const size_t base = (((size_t)(b*DI + d))*NC + c)*DS + q*4;
  const float4 s4 = *(const float4*)(Sinit + base);
  float s0=s4.x, s1=s4.y, s2=s4.z, s3=s4.w;
  #pragma unroll 4
  for (int l = 0; l < CL; ++l) {
    const float dt = dl[(size_t)l*DI];
    const float ut = uu[(size_t)l*DI];
    const float4 B4 = *(const float4*)(pb + l*96);
    const float4 C4 = *(const float4*)(pc + l*96);
    const float dtu = dt*ut;
    s0 = fmaf(__expf(dt*a0), s0, dtu*B4.x);
    s1 = fmaf(__expf(dt*a1), s1, dtu*B4.y);
    s2 = fmaf(__expf(dt*a2), s2, dtu*B4.z);
    s3 = fmaf(__expf(dt*a3), s3, dtu*B4.w);
    float part = s0*C4.x + s1*C4.y + s2*C4.z + s3*C4.w;
    part += __shfl_xor(part, 1);
    part += __shfl_xor(part, 2);
    if (q == 0) {
      const float z = zp[(size_t)l*(2*DI)];
      yo[(size_t)l*DI] = f2b((part + Dp*ut) * siluf_(z));
    }
  }
}

extern "C" void kernel_launch(void* const* d_in, const int* in_sizes, int n_in,
                              void* d_out, int out_size, void* d_ws, size_t ws_size,
                              hipStream_t stream)
{
  const float* x      = (const float*)d_in[0];
  const float* W_in   = (const float*)d_in[1];
  const float* conv_w = (const float*)d_in[2];
  const float* conv_b = (const float*)d_in[3];
  const float* W_x    = (const float*)d_in[4];
  const float* W_dt   = (const float*)d_in[5];
  const float* b_dt   = (const float*)d_in[6];
  const float* W_out  = (const float*)d_in[7];
  const float* A_log  = (const float*)d_in[8];
  const float* D_par  = (const float*)d_in[9];
  float* out = (float*)d_out;

  float* xz     = (float*)d_ws;             // MM*4096 f32 (32MB)
  float* u      = xz + (size_t)MM*2*DI;     // MM*DI f32 (16MB)
  float* params = u  + (size_t)MM*DI;       // MM*96 f32 (0.75MB)
  float* delta  = params + (size_t)MM*96;   // MM*DI f32 (16MB)
  u16*  pool    = (u16*)(delta + (size_t)MM*DI);
  // G1 phase:
  u16* xb16 = pool;                          // 2048*1024 (4MB), dead after G1
  u16* Wi_t = (u16*)out;                     // 4096*1024 bf16 = 8MB, in d_out
  // post-G1 phase (reuses pool):
  u16* Wo_t   = pool;                        // 1024*2048 bf16 (4MB)
  u16* yb16   = pool + (size_t)DM*DI;        // 2048*2048 bf16 (8MB)
  // d_out staging (all dead before the final reduce writes out):
  float* xpart = out;                        // [8][2048][96] f32 = 6.3MB (after G1)
  const size_t PFN = (size_t)NB*DI*NC*DS;    // 1048576 floats
  float* Pc    = out;                        // scan phase; becomes Sinit in-place
  float* Fc    = out + PFN;                  // Pc+Fc = exactly out_size floats
  // G4 split-K partials in xz region (dead after scan_apply): 4*MM*DM*4B = 32MB
  float* g4part = xz;

  dim3 blk(256);
  // convert x -> bf16; transpose-convert W_in -> [4096][1024] bf16 (in d_out)
  cvt_bf16_kern<<<(MM*DM/4 + 255)/256, blk, 0, stream>>>(x, DM, DM, xb16, MM);
  transpose_cvt_kern<<<dim3(2*DI/32, DM/32), blk, 0, stream>>>(W_in, Wi_t, DM, 2*DI);
  // G1: xz = x @ W_in   [2048 x 4096, K=1024]  (MFMA, m97 structure)
  gemm_mfma_kern<<<512, blk, 0, stream>>>(xb16, Wi_t, xz, MM, 2*DI, DM, DM, 32, 16);
  // conv + silu -> u
  conv_silu_kern<<<(MM*DI/4)/256, blk, 0, stream>>>(xz, conv_w, conv_b, u);
  // G2: params = u @ W_x  [2048 x 96, K=2048]  (fp32, K-split + reduce)
  xproj_part_kern<<<256*XSPLIT, blk, 0, stream>>>(u, W_x, xpart);
  xproj_reduce_kern<<<(MM*96/4)/256, blk, 0, stream>>>(xpart, params);
  // G3: delta = softplus(dlt @ W_dt + b_dt)  [2048 x 2048, K=64]  (fp32 one-pass)
  dtproj_kern<<<1024, blk, 0, stream>>>(params, W_dt, b_dt, delta);
  // chunked scan (y written as bf16 to yb16)
  scan_local_kern<<<(NB*NC*DI*4)/256, blk, 0, stream>>>(delta, u, params, A_log, Pc, Fc);
  scan_combine_kern<<<(NB*DI*DS)/256, blk, 0, stream>>>(Pc, Fc);
  scan_apply_kern<<<(NB*NC*DI*4)/256, blk, 0, stream>>>(delta, u, params, xz, A_log, D_par, Pc, yb16);
  // G4: out = y @ W_out  [2048 x 1024, K=2048]  (MFMA, split-K=4 -> reduce)
  transpose_cvt_kern<<<dim3(DM/32, DI/32), blk, 0, stream>>>(W_out, Wo_t, DI, DM);
  gemm_mfma_kern<<<512, blk, 0, stream>>>(yb16, Wo_t, g4part, MM, DM, DI, DI/4, 8, 16);
  reduce4_kern<<<(MM*DM/4)/256, blk, 0, stream>>>(g4part, out);
}

// Round 9
// 213.359 us; speedup vs baseline: 6.0347x; 1.1114x over previous
//
#include <hip/hip_runtime.h>
#include <hip/hip_bf16.h>
#include <math.h>

#define DM 1024
#define DI 2048
#define DS 16
#define DTR 64
#define NB 2
#define LL 1024
#define MM (NB*LL)   // 2048
#define NC 32        // scan chunks
#define CL (LL/NC)   // 32
#define XSPLIT 8
#define XKC (DI/XSPLIT)  // 256

typedef unsigned short u16;
typedef __bf16 bf16x8 __attribute__((ext_vector_type(8)));
typedef float f32x4 __attribute__((ext_vector_type(4)));
typedef const __attribute__((address_space(1))) void gas_void;
typedef __attribute__((address_space(3))) void las_void;

__device__ __forceinline__ float sigmoidf_(float x){ return 1.f/(1.f+__expf(-x)); }
__device__ __forceinline__ float siluf_(float x){ return x*sigmoidf_(x); }
__device__ __forceinline__ float softplusf_(float x){ return fmaxf(x,0.f)+__logf(1.f+__expf(-fabsf(x))); }
__device__ __forceinline__ u16 f2b(float f){
  __hip_bfloat16 h = __float2bfloat16(f);
  return __builtin_bit_cast(unsigned short, h);
}
// P/F summaries live in the dead xb-half of xz (cols 0..2047 of each 4096-col row)
__device__ __forceinline__ size_t smap(size_t i){ return ((i>>11)<<12) + (i&2047); }
// CK-style: LDS generic VA low 32 bits = LDS offset; AS(3) ptr is 32-bit.
__device__ __forceinline__ void gld16(const u16* g, u16* l){
  __builtin_amdgcn_global_load_lds(
      reinterpret_cast<gas_void*>((unsigned long long)g),
      reinterpret_cast<las_void*>((unsigned)(unsigned long long)l), 16, 0, 0);
}

// ---------------- bf16 MFMA GEMM, m97 structure ----------------
// C(+zz*M*N)[M][N] f32 = A[M][lda] * Bt[N][lda]^T over K range [zz*KS, (zz+1)*KS).
__global__ __launch_bounds__(256) void gemm_mfma_kern(
    const u16* __restrict__ A, const u16* __restrict__ Bt,
    float* __restrict__ C, int M, int N, int lda, int KS, int TN, int TM)
{
  __shared__ __attribute__((aligned(16))) u16 As[128*32];
  __shared__ __attribute__((aligned(16))) u16 Bs[128*32];
  const unsigned tid = threadIdx.x;
  const unsigned l = tid & 63;
  const unsigned w = tid >> 6;
  const unsigned wm = w >> 1, wn = w & 1;      // 2x2 wave grid, 64x64 each
  const int q8  = (int)gridDim.x >> 3;
  const int id2 = ((int)blockIdx.x & 7) * q8 + ((int)blockIdx.x >> 3);
  const int zz  = id2 / (TN*TM);
  const int rr  = id2 % (TN*TM);
  const int bm  = (rr / TN) * 128;
  const int bn  = (rr % TN) * 128;
  const int kbeg = zz * KS;
  const unsigned srow = l >> 2;
  const unsigned scol = (l & 3) * 8;
  f32x4 acc[4][4] = {};
  for (int k0 = kbeg; k0 < kbeg + KS; k0 += 32) {
    #pragma unroll
    for (int i = 0; i < 2; ++i) {
      const unsigned rb = (w*2 + i)*16;
      gld16(A  + (size_t)(bm + rb + srow)*lda + k0 + scol, As + (w*2+i)*512);
      gld16(Bt + (size_t)(bn + rb + srow)*lda + k0 + scol, Bs + (w*2+i)*512);
    }
    __syncthreads();
    bf16x8 af[4], bfr[4];
    #pragma unroll
    for (int m = 0; m < 4; ++m)
      af[m] = *(const bf16x8*)(As + (wm*64 + m*16 + (l & 15))*32 + (l >> 4)*8);
    #pragma unroll
    for (int n = 0; n < 4; ++n)
      bfr[n] = *(const bf16x8*)(Bs + (wn*64 + n*16 + (l & 15))*32 + (l >> 4)*8);
    #pragma unroll
    for (int m = 0; m < 4; ++m)
      #pragma unroll
      for (int n = 0; n < 4; ++n)
        acc[m][n] = __builtin_amdgcn_mfma_f32_16x16x32_bf16(af[m], bfr[n], acc[m][n], 0, 0, 0);
    __syncthreads();
  }
  float* Cz = C + (size_t)zz*M*N;
  #pragma unroll
  for (int m = 0; m < 4; ++m) {
    #pragma unroll
    for (int n = 0; n < 4; ++n) {
      const int col = bn + wn*64 + n*16 + (l & 15);
      #pragma unroll
      for (int q = 0; q < 4; ++q) {
        const int row = bm + wm*64 + m*16 + (l >> 4)*4 + q;
        Cz[(size_t)row*N + col] = acc[m][n][q];
      }
    }
  }
}

// fixed-order sum of 4 split-K partials (deterministic)
__global__ __launch_bounds__(256) void reduce4_kern(
    const float* __restrict__ part, float* __restrict__ out)
{
  const size_t i = ((size_t)blockIdx.x*256 + threadIdx.x) * 4;
  float4 s = *(const float4*)(part + i);
  #pragma unroll
  for (int ks = 1; ks < 4; ++ks) {
    const float4 v = *(const float4*)(part + (size_t)ks*MM*DM + i);
    s.x+=v.x; s.y+=v.y; s.z+=v.z; s.w+=v.w;
  }
  *(float4*)(out + i) = s;
}

// ---------------- dt-proj (G3), fp32 one-pass ----------------
__global__ __launch_bounds__(256) void dtproj_kern(
    const float* __restrict__ params, const float* __restrict__ W_dt,
    const float* __restrict__ b_dt, float* __restrict__ delta)
{
  __shared__ __align__(16) float Ad[32][DTR];    // 8KB
  __shared__ __align__(16) float Wd[DTR][128];   // 32KB
  const int tid = threadIdx.x;
  const int m0 = (blockIdx.x >> 4) * 32;
  const int c0 = (blockIdx.x & 15) * 128;
  #pragma unroll
  for (int i = 0; i < 2; ++i) {
    const int fq = i*256 + tid;
    const int r = fq >> 4, q = fq & 15;
    *(float4*)&Ad[r][q*4] = *(const float4*)(params + (size_t)(m0+r)*96 + q*4);
  }
  #pragma unroll
  for (int i = 0; i < 8; ++i) {
    const int fq = i*256 + tid;
    const int r = fq >> 5, q = fq & 31;
    *(float4*)&Wd[r][q*4] = *(const float4*)(W_dt + (size_t)r*DI + c0 + q*4);
  }
  __syncthreads();
  const int tr = tid >> 5;
  const int tc = tid & 31;
  f32x4 acc[4] = {};
  #pragma unroll
  for (int k0 = 0; k0 < DTR; k0 += 4) {
    float4 a[4], wv[4];
    #pragma unroll
    for (int i = 0; i < 4; ++i) a[i] = *(const float4*)&Ad[tr*4+i][k0];
    #pragma unroll
    for (int j = 0; j < 4; ++j) wv[j] = *(const float4*)&Wd[k0+j][tc*4];
    #pragma unroll
    for (int i = 0; i < 4; ++i) {
      const float ai[4] = {a[i].x, a[i].y, a[i].z, a[i].w};
      #pragma unroll
      for (int j = 0; j < 4; ++j) {
        acc[i][0] = fmaf(ai[j], wv[j].x, acc[i][0]);
        acc[i][1] = fmaf(ai[j], wv[j].y, acc[i][1]);
        acc[i][2] = fmaf(ai[j], wv[j].z, acc[i][2]);
        acc[i][3] = fmaf(ai[j], wv[j].w, acc[i][3]);
      }
    }
  }
  const float4 b4 = *(const float4*)(b_dt + c0 + tc*4);
  #pragma unroll
  for (int i = 0; i < 4; ++i) {
    float4 o;
    o.x = softplusf_(acc[i][0] + b4.x);
    o.y = softplusf_(acc[i][1] + b4.y);
    o.z = softplusf_(acc[i][2] + b4.z);
    o.w = softplusf_(acc[i][3] + b4.w);
    *(float4*)(delta + (size_t)(m0 + tr*4 + i)*DI + c0 + tc*4) = o;
  }
}

// transpose + convert: in [R][C] f32 -> out [C][R] bf16. grid(C/32, R/32).
__global__ __launch_bounds__(256) void transpose_cvt_kern(
    const float* __restrict__ in, u16* __restrict__ out, int R, int C)
{
  __shared__ float tile[32][33];
  const int r0 = blockIdx.y*32, c0 = blockIdx.x*32;
  const int tr = threadIdx.x >> 3, tc4 = (threadIdx.x & 7) * 4;
  float4 v = *(const float4*)(in + (size_t)(r0+tr)*C + c0 + tc4);
  tile[tr][tc4+0] = v.x; tile[tr][tc4+1] = v.y;
  tile[tr][tc4+2] = v.z; tile[tr][tc4+3] = v.w;
  __syncthreads();
  ushort4 o;
  o.x = f2b(tile[tc4+0][tr]);
  o.y = f2b(tile[tc4+1][tr]);
  o.z = f2b(tile[tc4+2][tr]);
  o.w = f2b(tile[tc4+3][tr]);
  *(ushort4*)(out + (size_t)(c0+tr)*R + r0 + tc4) = o;
}

// strided convert: out[row][0..C) bf16 = in[row*ld .. +C). C mult of 4.
__global__ __launch_bounds__(256) void cvt_bf16_kern(
    const float* __restrict__ in, int ld, int C, u16* __restrict__ out, int rows)
{
  const int i = blockIdx.x*256 + threadIdx.x;
  if (i >= rows*(C/4)) return;
  const int row = i / (C/4);
  const int cq  = (i % (C/4)) * 4;
  float4 v = *(const float4*)(in + (size_t)row*ld + cq);
  ushort4 o; o.x=f2b(v.x); o.y=f2b(v.y); o.z=f2b(v.z); o.w=f2b(v.w);
  *(ushort4*)(out + (size_t)row*C + cq) = o;
}

// ---------------- x-proj (G2), K-split fp32 ----------------
__global__ __launch_bounds__(256) void xproj_part_kern(
    const float* __restrict__ u, const float* __restrict__ W_x,
    float* __restrict__ part)
{
  __shared__ __align__(16) float As[8][XKC];   // 8KB
  const int tid = threadIdx.x;
  const int m0 = (blockIdx.x & 255) * 8;
  const int ks = blockIdx.x >> 8;
  const int k0 = ks * XKC;
  #pragma unroll
  for (int i = 0; i < 2; ++i) {
    const int flat = i*1024 + tid*4;
    const int rr = flat >> 8, cc = flat & (XKC-1);
    *(float4*)&As[rr][cc] = *(const float4*)(u + (size_t)(m0+rr)*DI + k0 + cc);
  }
  __syncthreads();
  const int r = tid >> 5, c = tid & 31;
  float a0=0.f, a1=0.f, a2=0.f;
  #pragma unroll 8
  for (int k = 0; k < XKC; ++k) {
    const float a = As[r][k];
    const float* w = W_x + (size_t)(k0+k)*96 + c;
    a0 = fmaf(a, w[0],  a0);
    a1 = fmaf(a, w[32], a1);
    a2 = fmaf(a, w[64], a2);
  }
  float* p = part + ((size_t)ks*MM + m0 + r)*96 + c;
  p[0]=a0; p[32]=a1; p[64]=a2;
}

__global__ __launch_bounds__(256) void xproj_reduce_kern(
    const float* __restrict__ part, float* __restrict__ params)
{
  const int i = blockIdx.x*256 + threadIdx.x;
  float4 s = {0.f,0.f,0.f,0.f};
  #pragma unroll
  for (int ks = 0; ks < XSPLIT; ++ks) {
    float4 v = *(const float4*)(part + (size_t)ks*MM*96 + (size_t)i*4);
    s.x+=v.x; s.y+=v.y; s.z+=v.z; s.w+=v.w;
  }
  *(float4*)(params + (size_t)i*4) = s;
}

// Causal depthwise conv (D_CONV=4) + SiLU, float4 over d (4 channels/thread).
__global__ __launch_bounds__(256) void conv_silu_kern(
    const float* __restrict__ xz, const float* __restrict__ conv_w,
    const float* __restrict__ conv_b, float* __restrict__ u)
{
  const int idx = blockIdx.x * 256 + threadIdx.x;   // over MM*DI/4
  const int d4 = (idx & (DI/4 - 1)) * 4;
  const int ml = idx >> 9;
  const int l  = ml & (LL-1);
  const int base = ml - l;
  const float4 w0 = *(const float4*)(conv_w + (d4+0)*4);
  const float4 w1 = *(const float4*)(conv_w + (d4+1)*4);
  const float4 w2 = *(const float4*)(conv_w + (d4+2)*4);
  const float4 w3 = *(const float4*)(conv_w + (d4+3)*4);
  const float wt[4][4] = {{w0.x,w0.y,w0.z,w0.w},{w1.x,w1.y,w1.z,w1.w},
                          {w2.x,w2.y,w2.z,w2.w},{w3.x,w3.y,w3.z,w3.w}};
  float4 acc = *(const float4*)(conv_b + d4);
  #pragma unroll
  for (int j = 0; j < 4; ++j) {
    const int ls = l - 3 + j;
    if (ls >= 0) {
      const float4 v = *(const float4*)(xz + (size_t)(base + ls)*(2*DI) + d4);
      acc.x = fmaf(v.x, wt[0][j], acc.x);
      acc.y = fmaf(v.y, wt[1][j], acc.y);
      acc.z = fmaf(v.z, wt[2][j], acc.z);
      acc.w = fmaf(v.w, wt[3][j], acc.w);
    }
  }
  float4 o;
  o.x = siluf_(acc.x); o.y = siluf_(acc.y);
  o.z = siluf_(acc.z); o.w = siluf_(acc.w);
  *(float4*)(u + (size_t)idx*4) = o;
}

// ---- chunk-parallel selective scan: 4 lanes/channel, 4 states/lane ----
// NC=32 -> 2048 blocks (8/CU, full occupancy). P/F summaries live in the
// dead xb-half of xz via smap().
__global__ __launch_bounds__(256) void scan_local_kern(
    const float* __restrict__ delta, const float* __restrict__ u,
    const float* __restrict__ params, const float* __restrict__ A_log,
    float* __restrict__ Pc, float* __restrict__ Fc)
{
  const int flat = blockIdx.x*256 + threadIdx.x;
  const int q  = flat & 3;
  const int ch = flat >> 2;
  const int d  = ch & (DI-1);
  const int c  = (ch >> 11) & (NC-1);
  const int b  = ch >> 16;
  const float4 al = *(const float4*)(A_log + d*DS + q*4);
  const float a0=-expf(al.x), a1=-expf(al.y), a2=-expf(al.z), a3=-expf(al.w);
  const size_t lbase = (size_t)b*LL + (size_t)c*CL;
  const float* dl = delta + lbase*DI + d;
  const float* uu = u     + lbase*DI + d;
  const float* pr = params + lbase*96 + DTR + q*4;
  float s0=0.f,s1=0.f,s2=0.f,s3=0.f, dtsum=0.f;
  #pragma unroll 4
  for (int l = 0; l < CL; ++l) {
    const float dt = dl[(size_t)l*DI];
    const float ut = uu[(size_t)l*DI];
    const float4 B4 = *(const float4*)(pr + l*96);
    const float dtu = dt*ut;
    s0 = fmaf(__expf(dt*a0), s0, dtu*B4.x);
    s1 = fmaf(__expf(dt*a1), s1, dtu*B4.y);
    s2 = fmaf(__expf(dt*a2), s2, dtu*B4.z);
    s3 = fmaf(__expf(dt*a3), s3, dtu*B4.w);
    dtsum += dt;
  }
  const size_t base = (((size_t)(b*DI + d))*NC + c)*DS + q*4;
  float4 P4; P4.x=__expf(dtsum*a0); P4.y=__expf(dtsum*a1);
  P4.z=__expf(dtsum*a2); P4.w=__expf(dtsum*a3);
  *(float4*)(Pc + smap(base)) = P4;
  *(float4*)(Fc + smap(base)) = make_float4(s0,s1,s2,s3);
}

// Combine: per (b,d,n), sequential over NC chunks. PS = Pc-in / Sinit-out.
__global__ __launch_bounds__(256) void scan_combine_kern(
    float* __restrict__ PS, const float* __restrict__ Fc)
{
  const int idx = blockIdx.x*256 + threadIdx.x;   // over NB*DI*DS
  const size_t base = (size_t)(idx >> 4) * (NC*DS) + (idx & 15);
  float s = 0.f;
  #pragma unroll
  for (int c = 0; c < NC; ++c) {
    const size_t a = smap(base + c*DS);
    const float P = PS[a], F = Fc[a];
    PS[a] = s;
    s = fmaf(P, s, F);
  }
}

// Pass B: rescan chunk from Sinit; fused C-dot + D*u + silu(z) gate -> y bf16.
__global__ __launch_bounds__(256) void scan_apply_kern(
    const float* __restrict__ delta, const float* __restrict__ u,
    const float* __restrict__ params, const float* __restrict__ xz,
    const float* __restrict__ A_log, const float* __restrict__ D_param,
    const float* __restrict__ Sinit, u16* __restrict__ y16)
{
  const int flat = blockIdx.x*256 + threadIdx.x;
  const int q  = flat & 3;
  const int ch = flat >> 2;
  const int d  = ch & (DI-1);
  const int c  = (ch >> 11) & (NC-1);
  const int b  = ch >> 16;
  const float4 al = *(const float4*)(A_log + d*DS + q*4);
  const float a0=-expf(al.x), a1=-expf(al.y), a2=-expf(al.z), a3=-expf(al.w);
  const float Dp = D_param[d];
  const size_t lbase = (size_t)b*LL + (size_t)c*CL;
  const float* dl = delta + lbase*DI + d;
  const float* uu = u     + lbase*DI + d;
  const float* pb = params + lbase*96 + DTR + q*4;
  const float* pc = params + lbase*96 + DTR + DS + q*4;
  const float* zp = xz + lbase*(2*DI) + DI + d;
  u16* yo = y16 + lbase*DI + d;
  const size_t base = (((size_t)(b*DI + d))*NC + c)*DS + q*4;
  const float4 s4 = *(const float4*)(Sinit + smap(base));
  float s0=s4.x, s1=s4.y, s2=s4.z, s3=s4.w;
  #pragma unroll 4
  for (int l = 0; l < CL; ++l) {
    const float dt = dl[(size_t)l*DI];
    const float ut = uu[(size_t)l*DI];
    const float4 B4 = *(const float4*)(pb + l*96);
    const float4 C4 = *(const float4*)(pc + l*96);
    const float dtu = dt*ut;
    s0 = fmaf(__expf(dt*a0), s0, dtu*B4.x);
    s1 = fmaf(__expf(dt*a1), s1, dtu*B4.y);
    s2 = fmaf(__expf(dt*a2), s2, dtu*B4.z);
    s3 = fmaf(__expf(dt*a3), s3, dtu*B4.w);
    float part = s0*C4.x + s1*C4.y + s2*C4.z + s3*C4.w;
    part += __shfl_xor(part, 1);
    part += __shfl_xor(part, 2);
    if (q == 0) {
      const float z = zp[(size_t)l*(2*DI)];
      yo[(size_t)l*DI] = f2b((part + Dp*ut) * siluf_(z));
    }
  }
}

extern "C" void kernel_launch(void* const* d_in, const int* in_sizes, int n_in,
                              void* d_out, int out_size, void* d_ws, size_t ws_size,
                              hipStream_t stream)
{
  const float* x      = (const float*)d_in[0];
  const float* W_in   = (const float*)d_in[1];
  const float* conv_w = (const float*)d_in[2];
  const float* conv_b = (const float*)d_in[3];
  const float* W_x    = (const float*)d_in[4];
  const float* W_dt   = (const float*)d_in[5];
  const float* b_dt   = (const float*)d_in[6];
  const float* W_out  = (const float*)d_in[7];
  const float* A_log  = (const float*)d_in[8];
  const float* D_par  = (const float*)d_in[9];
  float* out = (float*)d_out;

  float* xz     = (float*)d_ws;             // MM*4096 f32 (32MB)
  float* u      = xz + (size_t)MM*2*DI;     // MM*DI f32 (16MB)
  float* params = u  + (size_t)MM*DI;       // MM*96 f32 (0.75MB)
  float* delta  = params + (size_t)MM*96;   // MM*DI f32 (16MB)
  u16*  pool    = (u16*)(delta + (size_t)MM*DI);
  // G1 phase:
  u16* xb16 = pool;                          // 2048*1024 (4MB), dead after G1
  u16* Wi_t = (u16*)out;                     // 4096*1024 bf16 = 8MB, in d_out
  // post-G1 phase (reuses pool):
  u16* Wo_t   = pool;                        // 1024*2048 bf16 (4MB)
  u16* yb16   = pool + (size_t)DM*DI;        // 2048*2048 bf16 (8MB)
  // d_out staging (dead before the final reduce writes out):
  float* xpart = out;                        // [8][2048][96] f32 = 6.3MB (after G1)
  // scan summaries in the dead xb-half of xz (via smap): Pc rows 0..1023,
  // Fc rows 1024..2047 (cols 0..2047). z-half (cols 2048+) untouched.
  float* Pc = xz;                            // smap-addressed, becomes Sinit
  float* Fc = xz + (size_t)1024*4096;
  // G4 split-K partials in xz region (dead after scan_apply): 4*MM*DM*4B = 32MB
  float* g4part = xz;

  dim3 blk(256);
  // convert x -> bf16; transpose-convert W_in -> [4096][1024] bf16 (in d_out)
  cvt_bf16_kern<<<(MM*DM/4 + 255)/256, blk, 0, stream>>>(x, DM, DM, xb16, MM);
  transpose_cvt_kern<<<dim3(2*DI/32, DM/32), blk, 0, stream>>>(W_in, Wi_t, DM, 2*DI);
  // G1: xz = x @ W_in   [2048 x 4096, K=1024]  (MFMA, m97 structure)
  gemm_mfma_kern<<<512, blk, 0, stream>>>(xb16, Wi_t, xz, MM, 2*DI, DM, DM, 32, 16);
  // conv + silu -> u  (last reader of the xb-half of xz)
  conv_silu_kern<<<(MM*DI/4)/256, blk, 0, stream>>>(xz, conv_w, conv_b, u);
  // G2: params = u @ W_x  [2048 x 96, K=2048]  (fp32, K-split + reduce)
  xproj_part_kern<<<256*XSPLIT, blk, 0, stream>>>(u, W_x, xpart);
  xproj_reduce_kern<<<(MM*96/4)/256, blk, 0, stream>>>(xpart, params);
  // G3: delta = softplus(dlt @ W_dt + b_dt)  [2048 x 2048, K=64]  (fp32 one-pass)
  dtproj_kern<<<1024, blk, 0, stream>>>(params, W_dt, b_dt, delta);
  // chunked scan, NC=32 (y written as bf16 to yb16)
  scan_local_kern<<<(NB*NC*DI*4)/256, blk, 0, stream>>>(delta, u, params, A_log, Pc, Fc);
  scan_combine_kern<<<(NB*DI*DS)/256, blk, 0, stream>>>(Pc, Fc);
  scan_apply_kern<<<(NB*NC*DI*4)/256, blk, 0, stream>>>(delta, u, params, xz, A_log, D_par, Pc, yb16);
  // G4: out = y @ W_out  [2048 x 1024, K=2048]  (MFMA, split-K=4 -> reduce)
  transpose_cvt_kern<<<dim3(DM/32, DI/32), blk, 0, stream>>>(W_out, Wo_t, DI, DM);
  gemm_mfma_kern<<<512, blk, 0, stream>>>(yb16, Wo_t, g4part, MM, DM, DI, DI/4, 8, 16);
  reduce4_kern<<<(MM*DM/4)/256, blk, 0, stream>>>(g4part, out);
}

// Round 10
// 192.677 us; speedup vs baseline: 6.6825x; 1.1073x over previous
//
#include <hip/hip_runtime.h>
#include <hip/hip_bf16.h>
#include <math.h>

#define DM 1024
#define DI 2048
#define DS 16
#define DTR 64
#define NB 2
#define LL 1024
#define MM (NB*LL)   // 2048
#define NC 32        // scan chunks
#define CL (LL/NC)   // 32
#define XSPLIT 8
#define XKC (DI/XSPLIT)  // 256

typedef unsigned short u16;
typedef __bf16 bf16x8 __attribute__((ext_vector_type(8)));
typedef float f32x4 __attribute__((ext_vector_type(4)));
typedef const __attribute__((address_space(1))) void gas_void;
typedef __attribute__((address_space(3))) void las_void;

__device__ __forceinline__ float sigmoidf_(float x){ return 1.f/(1.f+__expf(-x)); }
__device__ __forceinline__ float siluf_(float x){ return x*sigmoidf_(x); }
__device__ __forceinline__ float softplusf_(float x){ return fmaxf(x,0.f)+__logf(1.f+__expf(-fabsf(x))); }
__device__ __forceinline__ u16 f2b(float f){
  __hip_bfloat16 h = __float2bfloat16(f);
  return __builtin_bit_cast(unsigned short, h);
}
// P/F summaries live in the dead xb-half of xz (cols 0..2047 of each 4096-col row)
__device__ __forceinline__ size_t smap(size_t i){ return ((i>>11)<<12) + (i&2047); }
// CK-style: LDS generic VA low 32 bits = LDS offset; AS(3) ptr is 32-bit.
__device__ __forceinline__ void gld16(const u16* g, u16* l){
  __builtin_amdgcn_global_load_lds(
      reinterpret_cast<gas_void*>((unsigned long long)g),
      reinterpret_cast<las_void*>((unsigned)(unsigned long long)l), 16, 0, 0);
}

// ---------------- bf16 MFMA GEMM, m97 structure ----------------
// C(+zz*M*N)[M][N] f32 = A[M][lda] * Bt[N][lda]^T over K range [zz*KS, (zz+1)*KS).
__global__ __launch_bounds__(256) void gemm_mfma_kern(
    const u16* __restrict__ A, const u16* __restrict__ Bt,
    float* __restrict__ C, int M, int N, int lda, int KS, int TN, int TM)
{
  __shared__ __attribute__((aligned(16))) u16 As[128*32];
  __shared__ __attribute__((aligned(16))) u16 Bs[128*32];
  const unsigned tid = threadIdx.x;
  const unsigned l = tid & 63;
  const unsigned w = tid >> 6;
  const unsigned wm = w >> 1, wn = w & 1;      // 2x2 wave grid, 64x64 each
  const int q8  = (int)gridDim.x >> 3;
  const int id2 = ((int)blockIdx.x & 7) * q8 + ((int)blockIdx.x >> 3);
  const int zz  = id2 / (TN*TM);
  const int rr  = id2 % (TN*TM);
  const int bm  = (rr / TN) * 128;
  const int bn  = (rr % TN) * 128;
  const int kbeg = zz * KS;
  const unsigned srow = l >> 2;
  const unsigned scol = (l & 3) * 8;
  f32x4 acc[4][4] = {};
  for (int k0 = kbeg; k0 < kbeg + KS; k0 += 32) {
    #pragma unroll
    for (int i = 0; i < 2; ++i) {
      const unsigned rb = (w*2 + i)*16;
      gld16(A  + (size_t)(bm + rb + srow)*lda + k0 + scol, As + (w*2+i)*512);
      gld16(Bt + (size_t)(bn + rb + srow)*lda + k0 + scol, Bs + (w*2+i)*512);
    }
    __syncthreads();
    bf16x8 af[4], bfr[4];
    #pragma unroll
    for (int m = 0; m < 4; ++m)
      af[m] = *(const bf16x8*)(As + (wm*64 + m*16 + (l & 15))*32 + (l >> 4)*8);
    #pragma unroll
    for (int n = 0; n < 4; ++n)
      bfr[n] = *(const bf16x8*)(Bs + (wn*64 + n*16 + (l & 15))*32 + (l >> 4)*8);
    #pragma unroll
    for (int m = 0; m < 4; ++m)
      #pragma unroll
      for (int n = 0; n < 4; ++n)
        acc[m][n] = __builtin_amdgcn_mfma_f32_16x16x32_bf16(af[m], bfr[n], acc[m][n], 0, 0, 0);
    __syncthreads();
  }
  float* Cz = C + (size_t)zz*M*N;
  #pragma unroll
  for (int m = 0; m < 4; ++m) {
    #pragma unroll
    for (int n = 0; n < 4; ++n) {
      const int col = bn + wn*64 + n*16 + (l & 15);
      #pragma unroll
      for (int q = 0; q < 4; ++q) {
        const int row = bm + wm*64 + m*16 + (l >> 4)*4 + q;
        Cz[(size_t)row*N + col] = acc[m][n][q];
      }
    }
  }
}

// fixed-order sum of 4 split-K partials (deterministic)
__global__ __launch_bounds__(256) void reduce4_kern(
    const float* __restrict__ part, float* __restrict__ out)
{
  const size_t i = ((size_t)blockIdx.x*256 + threadIdx.x) * 4;
  float4 s = *(const float4*)(part + i);
  #pragma unroll
  for (int ks = 1; ks < 4; ++ks) {
    const float4 v = *(const float4*)(part + (size_t)ks*MM*DM + i);
    s.x+=v.x; s.y+=v.y; s.z+=v.z; s.w+=v.w;
  }
  *(float4*)(out + i) = s;
}

// ---------------- dt-proj (G3), fp32 one-pass ----------------
__global__ __launch_bounds__(256) void dtproj_kern(
    const float* __restrict__ params, const float* __restrict__ W_dt,
    const float* __restrict__ b_dt, float* __restrict__ delta)
{
  __shared__ __align__(16) float Ad[32][DTR];    // 8KB
  __shared__ __align__(16) float Wd[DTR][128];   // 32KB
  const int tid = threadIdx.x;
  const int m0 = (blockIdx.x >> 4) * 32;
  const int c0 = (blockIdx.x & 15) * 128;
  #pragma unroll
  for (int i = 0; i < 2; ++i) {
    const int fq = i*256 + tid;
    const int r = fq >> 4, q = fq & 15;
    *(float4*)&Ad[r][q*4] = *(const float4*)(params + (size_t)(m0+r)*96 + q*4);
  }
  #pragma unroll
  for (int i = 0; i < 8; ++i) {
    const int fq = i*256 + tid;
    const int r = fq >> 5, q = fq & 31;
    *(float4*)&Wd[r][q*4] = *(const float4*)(W_dt + (size_t)r*DI + c0 + q*4);
  }
  __syncthreads();
  const int tr = tid >> 5;
  const int tc = tid & 31;
  f32x4 acc[4] = {};
  #pragma unroll
  for (int k0 = 0; k0 < DTR; k0 += 4) {
    float4 a[4], wv[4];
    #pragma unroll
    for (int i = 0; i < 4; ++i) a[i] = *(const float4*)&Ad[tr*4+i][k0];
    #pragma unroll
    for (int j = 0; j < 4; ++j) wv[j] = *(const float4*)&Wd[k0+j][tc*4];
    #pragma unroll
    for (int i = 0; i < 4; ++i) {
      const float ai[4] = {a[i].x, a[i].y, a[i].z, a[i].w};
      #pragma unroll
      for (int j = 0; j < 4; ++j) {
        acc[i][0] = fmaf(ai[j], wv[j].x, acc[i][0]);
        acc[i][1] = fmaf(ai[j], wv[j].y, acc[i][1]);
        acc[i][2] = fmaf(ai[j], wv[j].z, acc[i][2]);
        acc[i][3] = fmaf(ai[j], wv[j].w, acc[i][3]);
      }
    }
  }
  const float4 b4 = *(const float4*)(b_dt + c0 + tc*4);
  #pragma unroll
  for (int i = 0; i < 4; ++i) {
    float4 o;
    o.x = softplusf_(acc[i][0] + b4.x);
    o.y = softplusf_(acc[i][1] + b4.y);
    o.z = softplusf_(acc[i][2] + b4.z);
    o.w = softplusf_(acc[i][3] + b4.w);
    *(float4*)(delta + (size_t)(m0 + tr*4 + i)*DI + c0 + tc*4) = o;
  }
}

// transpose + convert: in [R][C] f32 -> out [C][R] bf16. grid(C/32, R/32).
__global__ __launch_bounds__(256) void transpose_cvt_kern(
    const float* __restrict__ in, u16* __restrict__ out, int R, int C)
{
  __shared__ float tile[32][33];
  const int r0 = blockIdx.y*32, c0 = blockIdx.x*32;
  const int tr = threadIdx.x >> 3, tc4 = (threadIdx.x & 7) * 4;
  float4 v = *(const float4*)(in + (size_t)(r0+tr)*C + c0 + tc4);
  tile[tr][tc4+0] = v.x; tile[tr][tc4+1] = v.y;
  tile[tr][tc4+2] = v.z; tile[tr][tc4+3] = v.w;
  __syncthreads();
  ushort4 o;
  o.x = f2b(tile[tc4+0][tr]);
  o.y = f2b(tile[tc4+1][tr]);
  o.z = f2b(tile[tc4+2][tr]);
  o.w = f2b(tile[tc4+3][tr]);
  *(ushort4*)(out + (size_t)(c0+tr)*R + r0 + tc4) = o;
}

// strided convert: out[row][0..C) bf16 = in[row*ld .. +C). C mult of 4.
__global__ __launch_bounds__(256) void cvt_bf16_kern(
    const float* __restrict__ in, int ld, int C, u16* __restrict__ out, int rows)
{
  const int i = blockIdx.x*256 + threadIdx.x;
  if (i >= rows*(C/4)) return;
  const int row = i / (C/4);
  const int cq  = (i % (C/4)) * 4;
  float4 v = *(const float4*)(in + (size_t)row*ld + cq);
  ushort4 o; o.x=f2b(v.x); o.y=f2b(v.y); o.z=f2b(v.z); o.w=f2b(v.w);
  *(ushort4*)(out + (size_t)row*C + cq) = o;
}

// ---------------- x-proj (G2), K-split fp32 ----------------
// 512 blocks = 64 M-tiles(32 rows) x 8 K-chunks. u tile staged k-major in LDS;
// thread (r4,c) computes rows r4*4..+3 x cols {c,c+32,c+64}: per k, 3 W_x
// loads amortize over 4 rows (12 fma).
__global__ __launch_bounds__(256) void xproj_part_kern(
    const float* __restrict__ u, const float* __restrict__ W_x,
    float* __restrict__ part)
{
  __shared__ __align__(16) float Uk[XKC][32];   // 32KB, k-major
  const int tid = threadIdx.x;
  const int m0 = (blockIdx.x & 63) * 32;
  const int ks = blockIdx.x >> 6;
  const int k0 = ks * XKC;
  #pragma unroll
  for (int i = 0; i < 8; ++i) {
    const int fq = i*256 + tid;                  // 2048 float4s
    const int r = fq & 31, kq = fq >> 5;
    const float4 v = *(const float4*)(u + (size_t)(m0+r)*DI + k0 + kq*4);
    Uk[kq*4+0][r] = v.x; Uk[kq*4+1][r] = v.y;
    Uk[kq*4+2][r] = v.z; Uk[kq*4+3][r] = v.w;
  }
  __syncthreads();
  const int r4 = tid >> 5;                       // rows r4*4..+3
  const int c  = tid & 31;
  f32x4 a0 = {}, a1 = {}, a2 = {};
  #pragma unroll 4
  for (int k = 0; k < XKC; ++k) {
    const float* w = W_x + (size_t)(k0+k)*96 + c;
    const float w0 = w[0], w1 = w[32], w2 = w[64];
    const float4 uv = *(const float4*)&Uk[k][r4*4];
    const float ur[4] = {uv.x, uv.y, uv.z, uv.w};
    #pragma unroll
    for (int i = 0; i < 4; ++i) {
      a0[i] = fmaf(ur[i], w0, a0[i]);
      a1[i] = fmaf(ur[i], w1, a1[i]);
      a2[i] = fmaf(ur[i], w2, a2[i]);
    }
  }
  #pragma unroll
  for (int i = 0; i < 4; ++i) {
    float* p = part + ((size_t)ks*MM + m0 + r4*4 + i)*96 + c;
    p[0] = a0[i]; p[32] = a1[i]; p[64] = a2[i];
  }
}

__global__ __launch_bounds__(256) void xproj_reduce_kern(
    const float* __restrict__ part, float* __restrict__ params)
{
  const int i = blockIdx.x*256 + threadIdx.x;
  float4 s = {0.f,0.f,0.f,0.f};
  #pragma unroll
  for (int ks = 0; ks < XSPLIT; ++ks) {
    float4 v = *(const float4*)(part + (size_t)ks*MM*96 + (size_t)i*4);
    s.x+=v.x; s.y+=v.y; s.z+=v.z; s.w+=v.w;
  }
  *(float4*)(params + (size_t)i*4) = s;
}

// Causal depthwise conv (D_CONV=4) + SiLU, float4 over d (4 channels/thread).
__global__ __launch_bounds__(256) void conv_silu_kern(
    const float* __restrict__ xz, const float* __restrict__ conv_w,
    const float* __restrict__ conv_b, float* __restrict__ u)
{
  const int idx = blockIdx.x * 256 + threadIdx.x;   // over MM*DI/4
  const int d4 = (idx & (DI/4 - 1)) * 4;
  const int ml = idx >> 9;
  const int l  = ml & (LL-1);
  const int base = ml - l;
  const float4 w0 = *(const float4*)(conv_w + (d4+0)*4);
  const float4 w1 = *(const float4*)(conv_w + (d4+1)*4);
  const float4 w2 = *(const float4*)(conv_w + (d4+2)*4);
  const float4 w3 = *(const float4*)(conv_w + (d4+3)*4);
  const float wt[4][4] = {{w0.x,w0.y,w0.z,w0.w},{w1.x,w1.y,w1.z,w1.w},
                          {w2.x,w2.y,w2.z,w2.w},{w3.x,w3.y,w3.z,w3.w}};
  float4 acc = *(const float4*)(conv_b + d4);
  #pragma unroll
  for (int j = 0; j < 4; ++j) {
    const int ls = l - 3 + j;
    if (ls >= 0) {
      const float4 v = *(const float4*)(xz + (size_t)(base + ls)*(2*DI) + d4);
      acc.x = fmaf(v.x, wt[0][j], acc.x);
      acc.y = fmaf(v.y, wt[1][j], acc.y);
      acc.z = fmaf(v.z, wt[2][j], acc.z);
      acc.w = fmaf(v.w, wt[3][j], acc.w);
    }
  }
  float4 o;
  o.x = siluf_(acc.x); o.y = siluf_(acc.y);
  o.z = siluf_(acc.z); o.w = siluf_(acc.w);
  *(float4*)(u + (size_t)idx*4) = o;
}

// ---- chunk-parallel selective scan: 4 lanes/channel, 4 states/lane ----
__global__ __launch_bounds__(256) void scan_local_kern(
    const float* __restrict__ delta, const float* __restrict__ u,
    const float* __restrict__ params, const float* __restrict__ A_log,
    float* __restrict__ Pc, float* __restrict__ Fc)
{
  const int flat = blockIdx.x*256 + threadIdx.x;
  const int q  = flat & 3;
  const int ch = flat >> 2;
  const int d  = ch & (DI-1);
  const int c  = (ch >> 11) & (NC-1);
  const int b  = ch >> 16;
  const float4 al = *(const float4*)(A_log + d*DS + q*4);
  const float a0=-expf(al.x), a1=-expf(al.y), a2=-expf(al.z), a3=-expf(al.w);
  const size_t lbase = (size_t)b*LL + (size_t)c*CL;
  const float* dl = delta + lbase*DI + d;
  const float* uu = u     + lbase*DI + d;
  const float* pr = params + lbase*96 + DTR + q*4;
  float s0=0.f,s1=0.f,s2=0.f,s3=0.f, dtsum=0.f;
  #pragma unroll 4
  for (int l = 0; l < CL; ++l) {
    const float dt = dl[(size_t)l*DI];
    const float ut = uu[(size_t)l*DI];
    const float4 B4 = *(const float4*)(pr + l*96);
    const float dtu = dt*ut;
    s0 = fmaf(__expf(dt*a0), s0, dtu*B4.x);
    s1 = fmaf(__expf(dt*a1), s1, dtu*B4.y);
    s2 = fmaf(__expf(dt*a2), s2, dtu*B4.z);
    s3 = fmaf(__expf(dt*a3), s3, dtu*B4.w);
    dtsum += dt;
  }
  const size_t base = (((size_t)(b*DI + d))*NC + c)*DS + q*4;
  float4 P4; P4.x=__expf(dtsum*a0); P4.y=__expf(dtsum*a1);
  P4.z=__expf(dtsum*a2); P4.w=__expf(dtsum*a3);
  *(float4*)(Pc + smap(base)) = P4;
  *(float4*)(Fc + smap(base)) = make_float4(s0,s1,s2,s3);
}

// Combine: per (b,d,n), sequential over NC chunks. PS = Pc-in / Sinit-out.
__global__ __launch_bounds__(256) void scan_combine_kern(
    float* __restrict__ PS, const float* __restrict__ Fc)
{
  const int idx = blockIdx.x*256 + threadIdx.x;   // over NB*DI*DS
  const size_t base = (size_t)(idx >> 4) * (NC*DS) + (idx & 15);
  float s = 0.f;
  #pragma unroll
  for (int c = 0; c < NC; ++c) {
    const size_t a = smap(base + c*DS);
    const float P = PS[a], F = Fc[a];
    PS[a] = s;
    s = fmaf(P, s, F);
  }
}

// Pass B: rescan chunk from Sinit; fused C-dot + D*u + silu(z) gate -> y bf16.
__global__ __launch_bounds__(256) void scan_apply_kern(
    const float* __restrict__ delta, const float* __restrict__ u,
    const float* __restrict__ params, const float* __restrict__ xz,
    const float* __restrict__ A_log, const float* __restrict__ D_param,
    const float* __restrict__ Sinit, u16* __restrict__ y16)
{
  const int flat = blockIdx.x*256 + threadIdx.x;
  const int q  = flat & 3;
  const int ch = flat >> 2;
  const int d  = ch & (DI-1);
  const int c  = (ch >> 11) & (NC-1);
  const int b  = ch >> 16;
  const float4 al = *(const float4*)(A_log + d*DS + q*4);
  const float a0=-expf(al.x), a1=-expf(al.y), a2=-expf(al.z), a3=-expf(al.w);
  const float Dp = D_param[d];
  const size_t lbase = (size_t)b*LL + (size_t)c*CL;
  const float* dl = delta + lbase*DI + d;
  const float* uu = u     + lbase*DI + d;
  const float* pb = params + lbase*96 + DTR + q*4;
  const float* pc = params + lbase*96 + DTR + DS + q*4;
  const float* zp = xz + lbase*(2*DI) + DI + d;
  u16* yo = y16 + lbase*DI + d;
  const size_t base = (((size_t)(b*DI + d))*NC + c)*DS + q*4;
  const float4 s4 = *(const float4*)(Sinit + smap(base));
  float s0=s4.x, s1=s4.y, s2=s4.z, s3=s4.w;
  #pragma unroll 4
  for (int l = 0; l < CL; ++l) {
    const float dt = dl[(size_t)l*DI];
    const float ut = uu[(size_t)l*DI];
    const float4 B4 = *(const float4*)(pb + l*96);
    const float4 C4 = *(const float4*)(pc + l*96);
    const float dtu = dt*ut;
    s0 = fmaf(__expf(dt*a0), s0, dtu*B4.x);
    s1 = fmaf(__expf(dt*a1), s1, dtu*B4.y);
    s2 = fmaf(__expf(dt*a2), s2, dtu*B4.z);
    s3 = fmaf(__expf(dt*a3), s3, dtu*B4.w);
    float part = s0*C4.x + s1*C4.y + s2*C4.z + s3*C4.w;
    part += __shfl_xor(part, 1);
    part += __shfl_xor(part, 2);
    if (q == 0) {
      const float z = zp[(size_t)l*(2*DI)];
      yo[(size_t)l*DI] = f2b((part + Dp*ut) * siluf_(z));
    }
  }
}

extern "C" void kernel_launch(void* const* d_in, const int* in_sizes, int n_in,
                              void* d_out, int out_size, void* d_ws, size_t ws_size,
                              hipStream_t stream)
{
  const float* x      = (const float*)d_in[0];
  const float* W_in   = (const float*)d_in[1];
  const float* conv_w = (const float*)d_in[2];
  const float* conv_b = (const float*)d_in[3];
  const float* W_x    = (const float*)d_in[4];
  const float* W_dt   = (const float*)d_in[5];
  const float* b_dt   = (const float*)d_in[6];
  const float* W_out  = (const float*)d_in[7];
  const float* A_log  = (const float*)d_in[8];
  const float* D_par  = (const float*)d_in[9];
  float* out = (float*)d_out;

  float* xz     = (float*)d_ws;             // MM*4096 f32 (32MB)
  float* u      = xz + (size_t)MM*2*DI;     // MM*DI f32 (16MB)
  float* params = u  + (size_t)MM*DI;       // MM*96 f32 (0.75MB)
  float* delta  = params + (size_t)MM*96;   // MM*DI f32 (16MB)
  u16*  pool    = (u16*)(delta + (size_t)MM*DI);
  // G1 phase:
  u16* xb16 = pool;                          // 2048*1024 (4MB), dead after G1
  u16* Wi_t = (u16*)out;                     // 4096*1024 bf16 = 8MB, in d_out
  // post-G1 phase (reuses pool):
  u16* Wo_t   = pool;                        // 1024*2048 bf16 (4MB)
  u16* yb16   = pool + (size_t)DM*DI;        // 2048*2048 bf16 (8MB)
  // d_out staging (dead before the final reduce writes out):
  float* xpart = out;                        // [8][2048][96] f32 = 6.3MB (after G1)
  // scan summaries in the dead xb-half of xz (via smap)
  float* Pc = xz;                            // smap-addressed, becomes Sinit
  float* Fc = xz + (size_t)1024*4096;
  // G4 split-K partials in xz region (dead after scan_apply): 4*MM*DM*4B = 32MB
  float* g4part = xz;

  dim3 blk(256);
  // convert x -> bf16; transpose-convert W_in -> [4096][1024] bf16 (in d_out)
  cvt_bf16_kern<<<(MM*DM/4 + 255)/256, blk, 0, stream>>>(x, DM, DM, xb16, MM);
  transpose_cvt_kern<<<dim3(2*DI/32, DM/32), blk, 0, stream>>>(W_in, Wi_t, DM, 2*DI);
  // G1: xz = x @ W_in   [2048 x 4096, K=1024]  (MFMA, m97 structure)
  gemm_mfma_kern<<<512, blk, 0, stream>>>(xb16, Wi_t, xz, MM, 2*DI, DM, DM, 32, 16);
  // conv + silu -> u  (last reader of the xb-half of xz)
  conv_silu_kern<<<(MM*DI/4)/256, blk, 0, stream>>>(xz, conv_w, conv_b, u);
  // G2: params = u @ W_x  [2048 x 96, K=2048]  (fp32, K-split + reduce)
  xproj_part_kern<<<64*XSPLIT, blk, 0, stream>>>(u, W_x, xpart);
  xproj_reduce_kern<<<(MM*96/4)/256, blk, 0, stream>>>(xpart, params);
  // G3: delta = softplus(dlt @ W_dt + b_dt)  [2048 x 2048, K=64]  (fp32 one-pass)
  dtproj_kern<<<1024, blk, 0, stream>>>(params, W_dt, b_dt, delta);
  // chunked scan, NC=32 (y written as bf16 to yb16)
  scan_local_kern<<<(NB*NC*DI*4)/256, blk, 0, stream>>>(delta, u, params, A_log, Pc, Fc);
  scan_combine_kern<<<(NB*DI*DS)/256, blk, 0, stream>>>(Pc, Fc);
  scan_apply_kern<<<(NB*NC*DI*4)/256, blk, 0, stream>>>(delta, u, params, xz, A_log, D_par, Pc, yb16);
  // G4: out = y @ W_out  [2048 x 1024, K=2048]  (MFMA, split-K=4 -> reduce)
  transpose_cvt_kern<<<dim3(DM/32, DI/32), blk, 0, stream>>>(W_out, Wo_t, DI, DM);
  gemm_mfma_kern<<<512, blk, 0, stream>>>(yb16, Wo_t, g4part, MM, DM, DI, DI/4, 8, 16);
  reduce4_kern<<<(MM*DM/4)/256, blk, 0, stream>>>(g4part, out);
}

// Round 11
// 186.577 us; speedup vs baseline: 6.9009x; 1.0327x over previous
//
#include <hip/hip_runtime.h>
#include <hip/hip_bf16.h>
#include <math.h>

#define DM 1024
#define DI 2048
#define DS 16
#define DTR 64
#define NB 2
#define LL 1024
#define MM (NB*LL)   // 2048
#define NC 32        // scan chunks
#define CL (LL/NC)   // 32
#define XSPLIT 8
#define XKC (DI/XSPLIT)  // 256

typedef unsigned short u16;
typedef __bf16 bf16x8 __attribute__((ext_vector_type(8)));
typedef float f32x4 __attribute__((ext_vector_type(4)));
typedef const __attribute__((address_space(1))) void gas_void;
typedef __attribute__((address_space(3))) void las_void;

__device__ __forceinline__ float sigmoidf_(float x){ return 1.f/(1.f+__expf(-x)); }
__device__ __forceinline__ float siluf_(float x){ return x*sigmoidf_(x); }
__device__ __forceinline__ float softplusf_(float x){ return fmaxf(x,0.f)+__logf(1.f+__expf(-fabsf(x))); }
__device__ __forceinline__ u16 f2b(float f){
  __hip_bfloat16 h = __float2bfloat16(f);
  return __builtin_bit_cast(unsigned short, h);
}
// P/F summaries live in the dead xb-half of xz (cols 0..2047 of each 4096-col row)
__device__ __forceinline__ size_t smap(size_t i){ return ((i>>11)<<12) + (i&2047); }
// CK-style: LDS generic VA low 32 bits = LDS offset; AS(3) ptr is 32-bit.
__device__ __forceinline__ void gld16(const u16* g, u16* l){
  __builtin_amdgcn_global_load_lds(
      reinterpret_cast<gas_void*>((unsigned long long)g),
      reinterpret_cast<las_void*>((unsigned)(unsigned long long)l), 16, 0, 0);
}

// ---------------- bf16 MFMA GEMM, 8-wave 128x128 tile ----------------
// C(+zz*M*N)[M][N] f32 = A[M][lda] * Bt[N][lda]^T over K range [zz*KS, (zz+1)*KS).
// 512 threads: wave w = (wm = w>>2, wn = w&3) owns 64x32; acc 4x2 frags.
__global__ __launch_bounds__(512) void gemm_mfma_kern(
    const u16* __restrict__ A, const u16* __restrict__ Bt,
    float* __restrict__ C, int M, int N, int lda, int KS, int TN, int TM)
{
  __shared__ __attribute__((aligned(16))) u16 As[128*32];
  __shared__ __attribute__((aligned(16))) u16 Bs[128*32];
  const unsigned t = threadIdx.x;              // 0..511
  const unsigned l = t & 63;
  const unsigned w = t >> 6;                   // 0..7
  const unsigned wm = w >> 2, wn = w & 3;      // 2x4 wave grid, 64x32 each
  // bijective XCD swizzle (gridDim.x % 8 == 0)
  const int q8  = (int)gridDim.x >> 3;
  const int id2 = ((int)blockIdx.x & 7) * q8 + ((int)blockIdx.x >> 3);
  const int zz  = id2 / (TN*TM);
  const int rr  = id2 % (TN*TM);
  const int bm  = (rr / TN) * 128;
  const int bn  = (rr % TN) * 128;
  const int kbeg = zz * KS;
  const unsigned srow = t >> 2;                // 0..127
  const unsigned scol = (t & 3) * 8;
  f32x4 acc[4][2] = {};
  for (int k0 = kbeg; k0 < kbeg + KS; k0 += 32) {
    gld16(A  + (size_t)(bm + srow)*lda + k0 + scol, As + t*8);
    gld16(Bt + (size_t)(bn + srow)*lda + k0 + scol, Bs + t*8);
    __syncthreads();
    bf16x8 af[4], bfr[2];
    #pragma unroll
    for (int m = 0; m < 4; ++m)
      af[m] = *(const bf16x8*)(As + (wm*64 + m*16 + (l & 15))*32 + (l >> 4)*8);
    #pragma unroll
    for (int n = 0; n < 2; ++n)
      bfr[n] = *(const bf16x8*)(Bs + (wn*32 + n*16 + (l & 15))*32 + (l >> 4)*8);
    #pragma unroll
    for (int m = 0; m < 4; ++m)
      #pragma unroll
      for (int n = 0; n < 2; ++n)
        acc[m][n] = __builtin_amdgcn_mfma_f32_16x16x32_bf16(af[m], bfr[n], acc[m][n], 0, 0, 0);
    __syncthreads();
  }
  float* Cz = C + (size_t)zz*M*N;
  #pragma unroll
  for (int m = 0; m < 4; ++m) {
    #pragma unroll
    for (int n = 0; n < 2; ++n) {
      const int col = bn + wn*32 + n*16 + (l & 15);
      #pragma unroll
      for (int q = 0; q < 4; ++q) {
        const int row = bm + wm*64 + m*16 + (l >> 4)*4 + q;
        Cz[(size_t)row*N + col] = acc[m][n][q];
      }
    }
  }
}

// fixed-order sum of 4 split-K partials (deterministic)
__global__ __launch_bounds__(256) void reduce4_kern(
    const float* __restrict__ part, float* __restrict__ out)
{
  const size_t i = ((size_t)blockIdx.x*256 + threadIdx.x) * 4;
  float4 s = *(const float4*)(part + i);
  #pragma unroll
  for (int ks = 1; ks < 4; ++ks) {
    const float4 v = *(const float4*)(part + (size_t)ks*MM*DM + i);
    s.x+=v.x; s.y+=v.y; s.z+=v.z; s.w+=v.w;
  }
  *(float4*)(out + i) = s;
}

// ---------------- dt-proj (G3), fp32 one-pass ----------------
__global__ __launch_bounds__(256) void dtproj_kern(
    const float* __restrict__ params, const float* __restrict__ W_dt,
    const float* __restrict__ b_dt, float* __restrict__ delta)
{
  __shared__ __align__(16) float Ad[32][DTR];    // 8KB
  __shared__ __align__(16) float Wd[DTR][128];   // 32KB
  const int tid = threadIdx.x;
  const int m0 = (blockIdx.x >> 4) * 32;
  const int c0 = (blockIdx.x & 15) * 128;
  #pragma unroll
  for (int i = 0; i < 2; ++i) {
    const int fq = i*256 + tid;
    const int r = fq >> 4, q = fq & 15;
    *(float4*)&Ad[r][q*4] = *(const float4*)(params + (size_t)(m0+r)*96 + q*4);
  }
  #pragma unroll
  for (int i = 0; i < 8; ++i) {
    const int fq = i*256 + tid;
    const int r = fq >> 5, q = fq & 31;
    *(float4*)&Wd[r][q*4] = *(const float4*)(W_dt + (size_t)r*DI + c0 + q*4);
  }
  __syncthreads();
  const int tr = tid >> 5;
  const int tc = tid & 31;
  f32x4 acc[4] = {};
  #pragma unroll
  for (int k0 = 0; k0 < DTR; k0 += 4) {
    float4 a[4], wv[4];
    #pragma unroll
    for (int i = 0; i < 4; ++i) a[i] = *(const float4*)&Ad[tr*4+i][k0];
    #pragma unroll
    for (int j = 0; j < 4; ++j) wv[j] = *(const float4*)&Wd[k0+j][tc*4];
    #pragma unroll
    for (int i = 0; i < 4; ++i) {
      const float ai[4] = {a[i].x, a[i].y, a[i].z, a[i].w};
      #pragma unroll
      for (int j = 0; j < 4; ++j) {
        acc[i][0] = fmaf(ai[j], wv[j].x, acc[i][0]);
        acc[i][1] = fmaf(ai[j], wv[j].y, acc[i][1]);
        acc[i][2] = fmaf(ai[j], wv[j].z, acc[i][2]);
        acc[i][3] = fmaf(ai[j], wv[j].w, acc[i][3]);
      }
    }
  }
  const float4 b4 = *(const float4*)(b_dt + c0 + tc*4);
  #pragma unroll
  for (int i = 0; i < 4; ++i) {
    float4 o;
    o.x = softplusf_(acc[i][0] + b4.x);
    o.y = softplusf_(acc[i][1] + b4.y);
    o.z = softplusf_(acc[i][2] + b4.z);
    o.w = softplusf_(acc[i][3] + b4.w);
    *(float4*)(delta + (size_t)(m0 + tr*4 + i)*DI + c0 + tc*4) = o;
  }
}

// transpose + convert: in [R][C] f32 -> out [C][R] bf16. grid(C/32, R/32).
__global__ __launch_bounds__(256) void transpose_cvt_kern(
    const float* __restrict__ in, u16* __restrict__ out, int R, int C)
{
  __shared__ float tile[32][33];
  const int r0 = blockIdx.y*32, c0 = blockIdx.x*32;
  const int tr = threadIdx.x >> 3, tc4 = (threadIdx.x & 7) * 4;
  float4 v = *(const float4*)(in + (size_t)(r0+tr)*C + c0 + tc4);
  tile[tr][tc4+0] = v.x; tile[tr][tc4+1] = v.y;
  tile[tr][tc4+2] = v.z; tile[tr][tc4+3] = v.w;
  __syncthreads();
  ushort4 o;
  o.x = f2b(tile[tc4+0][tr]);
  o.y = f2b(tile[tc4+1][tr]);
  o.z = f2b(tile[tc4+2][tr]);
  o.w = f2b(tile[tc4+3][tr]);
  *(ushort4*)(out + (size_t)(c0+tr)*R + r0 + tc4) = o;
}

// strided convert: out[row][0..C) bf16 = in[row*ld .. +C). C mult of 4.
__global__ __launch_bounds__(256) void cvt_bf16_kern(
    const float* __restrict__ in, int ld, int C, u16* __restrict__ out, int rows)
{
  const int i = blockIdx.x*256 + threadIdx.x;
  if (i >= rows*(C/4)) return;
  const int row = i / (C/4);
  const int cq  = (i % (C/4)) * 4;
  float4 v = *(const float4*)(in + (size_t)row*ld + cq);
  ushort4 o; o.x=f2b(v.x); o.y=f2b(v.y); o.z=f2b(v.z); o.w=f2b(v.w);
  *(ushort4*)(out + (size_t)row*C + cq) = o;
}

// ---------------- x-proj (G2), K-split fp32 ----------------
__global__ __launch_bounds__(256) void xproj_part_kern(
    const float* __restrict__ u, const float* __restrict__ W_x,
    float* __restrict__ part)
{
  __shared__ __align__(16) float Uk[XKC][32];   // 32KB, k-major
  const int tid = threadIdx.x;
  const int m0 = (blockIdx.x & 63) * 32;
  const int ks = blockIdx.x >> 6;
  const int k0 = ks * XKC;
  #pragma unroll
  for (int i = 0; i < 8; ++i) {
    const int fq = i*256 + tid;                  // 2048 float4s
    const int r = fq & 31, kq = fq >> 5;
    const float4 v = *(const float4*)(u + (size_t)(m0+r)*DI + k0 + kq*4);
    Uk[kq*4+0][r] = v.x; Uk[kq*4+1][r] = v.y;
    Uk[kq*4+2][r] = v.z; Uk[kq*4+3][r] = v.w;
  }
  __syncthreads();
  const int r4 = tid >> 5;                       // rows r4*4..+3
  const int c  = tid & 31;
  f32x4 a0 = {}, a1 = {}, a2 = {};
  #pragma unroll 4
  for (int k = 0; k < XKC; ++k) {
    const float* w = W_x + (size_t)(k0+k)*96 + c;
    const float w0 = w[0], w1 = w[32], w2 = w[64];
    const float4 uv = *(const float4*)&Uk[k][r4*4];
    const float ur[4] = {uv.x, uv.y, uv.z, uv.w};
    #pragma unroll
    for (int i = 0; i < 4; ++i) {
      a0[i] = fmaf(ur[i], w0, a0[i]);
      a1[i] = fmaf(ur[i], w1, a1[i]);
      a2[i] = fmaf(ur[i], w2, a2[i]);
    }
  }
  #pragma unroll
  for (int i = 0; i < 4; ++i) {
    float* p = part + ((size_t)ks*MM + m0 + r4*4 + i)*96 + c;
    p[0] = a0[i]; p[32] = a1[i]; p[64] = a2[i];
  }
}

__global__ __launch_bounds__(256) void xproj_reduce_kern(
    const float* __restrict__ part, float* __restrict__ params)
{
  const int i = blockIdx.x*256 + threadIdx.x;
  float4 s = {0.f,0.f,0.f,0.f};
  #pragma unroll
  for (int ks = 0; ks < XSPLIT; ++ks) {
    float4 v = *(const float4*)(part + (size_t)ks*MM*96 + (size_t)i*4);
    s.x+=v.x; s.y+=v.y; s.z+=v.z; s.w+=v.w;
  }
  *(float4*)(params + (size_t)i*4) = s;
}

// Causal depthwise conv (D_CONV=4) + SiLU, float4 over d (4 channels/thread).
__global__ __launch_bounds__(256) void conv_silu_kern(
    const float* __restrict__ xz, const float* __restrict__ conv_w,
    const float* __restrict__ conv_b, float* __restrict__ u)
{
  const int idx = blockIdx.x * 256 + threadIdx.x;   // over MM*DI/4
  const int d4 = (idx & (DI/4 - 1)) * 4;
  const int ml = idx >> 9;
  const int l  = ml & (LL-1);
  const int base = ml - l;
  const float4 w0 = *(const float4*)(conv_w + (d4+0)*4);
  const float4 w1 = *(const float4*)(conv_w + (d4+1)*4);
  const float4 w2 = *(const float4*)(conv_w + (d4+2)*4);
  const float4 w3 = *(const float4*)(conv_w + (d4+3)*4);
  const float wt[4][4] = {{w0.x,w0.y,w0.z,w0.w},{w1.x,w1.y,w1.z,w1.w},
                          {w2.x,w2.y,w2.z,w2.w},{w3.x,w3.y,w3.z,w3.w}};
  float4 acc = *(const float4*)(conv_b + d4);
  #pragma unroll
  for (int j = 0; j < 4; ++j) {
    const int ls = l - 3 + j;
    if (ls >= 0) {
      const float4 v = *(const float4*)(xz + (size_t)(base + ls)*(2*DI) + d4);
      acc.x = fmaf(v.x, wt[0][j], acc.x);
      acc.y = fmaf(v.y, wt[1][j], acc.y);
      acc.z = fmaf(v.z, wt[2][j], acc.z);
      acc.w = fmaf(v.w, wt[3][j], acc.w);
    }
  }
  float4 o;
  o.x = siluf_(acc.x); o.y = siluf_(acc.y);
  o.z = siluf_(acc.z); o.w = siluf_(acc.w);
  *(float4*)(u + (size_t)idx*4) = o;
}

// ---- chunk-parallel selective scan: 4 lanes/channel, 4 states/lane ----
__global__ __launch_bounds__(256) void scan_local_kern(
    const float* __restrict__ delta, const float* __restrict__ u,
    const float* __restrict__ params, const float* __restrict__ A_log,
    float* __restrict__ Pc, float* __restrict__ Fc)
{
  const int flat = blockIdx.x*256 + threadIdx.x;
  const int q  = flat & 3;
  const int ch = flat >> 2;
  const int d  = ch & (DI-1);
  const int c  = (ch >> 11) & (NC-1);
  const int b  = ch >> 16;
  const float4 al = *(const float4*)(A_log + d*DS + q*4);
  const float a0=-expf(al.x), a1=-expf(al.y), a2=-expf(al.z), a3=-expf(al.w);
  const size_t lbase = (size_t)b*LL + (size_t)c*CL;
  const float* dl = delta + lbase*DI + d;
  const float* uu = u     + lbase*DI + d;
  const float* pr = params + lbase*96 + DTR + q*4;
  float s0=0.f,s1=0.f,s2=0.f,s3=0.f, dtsum=0.f;
  #pragma unroll 4
  for (int l = 0; l < CL; ++l) {
    const float dt = dl[(size_t)l*DI];
    const float ut = uu[(size_t)l*DI];
    const float4 B4 = *(const float4*)(pr + l*96);
    const float dtu = dt*ut;
    s0 = fmaf(__expf(dt*a0), s0, dtu*B4.x);
    s1 = fmaf(__expf(dt*a1), s1, dtu*B4.y);
    s2 = fmaf(__expf(dt*a2), s2, dtu*B4.z);
    s3 = fmaf(__expf(dt*a3), s3, dtu*B4.w);
    dtsum += dt;
  }
  const size_t base = (((size_t)(b*DI + d))*NC + c)*DS + q*4;
  float4 P4; P4.x=__expf(dtsum*a0); P4.y=__expf(dtsum*a1);
  P4.z=__expf(dtsum*a2); P4.w=__expf(dtsum*a3);
  *(float4*)(Pc + smap(base)) = P4;
  *(float4*)(Fc + smap(base)) = make_float4(s0,s1,s2,s3);
}

// Combine: per (b,d,n), sequential over NC chunks. PS = Pc-in / Sinit-out.
__global__ __launch_bounds__(256) void scan_combine_kern(
    float* __restrict__ PS, const float* __restrict__ Fc)
{
  const int idx = blockIdx.x*256 + threadIdx.x;   // over NB*DI*DS
  const size_t base = (size_t)(idx >> 4) * (NC*DS) + (idx & 15);
  float s = 0.f;
  #pragma unroll
  for (int c = 0; c < NC; ++c) {
    const size_t a = smap(base + c*DS);
    const float P = PS[a], F = Fc[a];
    PS[a] = s;
    s = fmaf(P, s, F);
  }
}

// Pass B: rescan chunk from Sinit; fused C-dot + D*u + silu(z) gate -> y bf16.
__global__ __launch_bounds__(256) void scan_apply_kern(
    const float* __restrict__ delta, const float* __restrict__ u,
    const float* __restrict__ params, const float* __restrict__ xz,
    const float* __restrict__ A_log, const float* __restrict__ D_param,
    const float* __restrict__ Sinit, u16* __restrict__ y16)
{
  const int flat = blockIdx.x*256 + threadIdx.x;
  const int q  = flat & 3;
  const int ch = flat >> 2;
  const int d  = ch & (DI-1);
  const int c  = (ch >> 11) & (NC-1);
  const int b  = ch >> 16;
  const float4 al = *(const float4*)(A_log + d*DS + q*4);
  const float a0=-expf(al.x), a1=-expf(al.y), a2=-expf(al.z), a3=-expf(al.w);
  const float Dp = D_param[d];
  const size_t lbase = (size_t)b*LL + (size_t)c*CL;
  const float* dl = delta + lbase*DI + d;
  const float* uu = u     + lbase*DI + d;
  const float* pb = params + lbase*96 + DTR + q*4;
  const float* pc = params + lbase*96 + DTR + DS + q*4;
  const float* zp = xz + lbase*(2*DI) + DI + d;
  u16* yo = y16 + lbase*DI + d;
  const size_t base = (((size_t)(b*DI + d))*NC + c)*DS + q*4;
  const float4 s4 = *(const float4*)(Sinit + smap(base));
  float s0=s4.x, s1=s4.y, s2=s4.z, s3=s4.w;
  #pragma unroll 4
  for (int l = 0; l < CL; ++l) {
    const float dt = dl[(size_t)l*DI];
    const float ut = uu[(size_t)l*DI];
    const float4 B4 = *(const float4*)(pb + l*96);
    const float4 C4 = *(const float4*)(pc + l*96);
    const float dtu = dt*ut;
    s0 = fmaf(__expf(dt*a0), s0, dtu*B4.x);
    s1 = fmaf(__expf(dt*a1), s1, dtu*B4.y);
    s2 = fmaf(__expf(dt*a2), s2, dtu*B4.z);
    s3 = fmaf(__expf(dt*a3), s3, dtu*B4.w);
    float part = s0*C4.x + s1*C4.y + s2*C4.z + s3*C4.w;
    part += __shfl_xor(part, 1);
    part += __shfl_xor(part, 2);
    if (q == 0) {
      const float z = zp[(size_t)l*(2*DI)];
      yo[(size_t)l*DI] = f2b((part + Dp*ut) * siluf_(z));
    }
  }
}

extern "C" void kernel_launch(void* const* d_in, const int* in_sizes, int n_in,
                              void* d_out, int out_size, void* d_ws, size_t ws_size,
                              hipStream_t stream)
{
  const float* x      = (const float*)d_in[0];
  const float* W_in   = (const float*)d_in[1];
  const float* conv_w = (const float*)d_in[2];
  const float* conv_b = (const float*)d_in[3];
  const float* W_x    = (const float*)d_in[4];
  const float* W_dt   = (const float*)d_in[5];
  const float* b_dt   = (const float*)d_in[6];
  const float* W_out  = (const float*)d_in[7];
  const float* A_log  = (const float*)d_in[8];
  const float* D_par  = (const float*)d_in[9];
  float* out = (float*)d_out;

  float* xz     = (float*)d_ws;             // MM*4096 f32 (32MB)
  float* u      = xz + (size_t)MM*2*DI;     // MM*DI f32 (16MB)
  float* params = u  + (size_t)MM*DI;       // MM*96 f32 (0.75MB)
  float* delta  = params + (size_t)MM*96;   // MM*DI f32 (16MB)
  u16*  pool    = (u16*)(delta + (size_t)MM*DI);
  // G1 phase:
  u16* xb16 = pool;                          // 2048*1024 (4MB), dead after G1
  u16* Wi_t = (u16*)out;                     // 4096*1024 bf16 = 8MB, in d_out
  // post-G1 phase (reuses pool):
  u16* Wo_t   = pool;                        // 1024*2048 bf16 (4MB)
  u16* yb16   = pool + (size_t)DM*DI;        // 2048*2048 bf16 (8MB)
  // d_out staging (dead before the final reduce writes out):
  float* xpart = out;                        // [8][2048][96] f32 = 6.3MB (after G1)
  // scan summaries in the dead xb-half of xz (via smap)
  float* Pc = xz;                            // smap-addressed, becomes Sinit
  float* Fc = xz + (size_t)1024*4096;
  // G4 split-K partials in xz region (dead after scan_apply): 4*MM*DM*4B = 32MB
  float* g4part = xz;

  dim3 blk(256);
  dim3 blk512(512);
  // convert x -> bf16; transpose-convert W_in -> [4096][1024] bf16 (in d_out)
  cvt_bf16_kern<<<(MM*DM/4 + 255)/256, blk, 0, stream>>>(x, DM, DM, xb16, MM);
  transpose_cvt_kern<<<dim3(2*DI/32, DM/32), blk, 0, stream>>>(W_in, Wi_t, DM, 2*DI);
  // G1: xz = x @ W_in   [2048 x 4096, K=1024]  (MFMA, 8-wave)
  gemm_mfma_kern<<<512, blk512, 0, stream>>>(xb16, Wi_t, xz, MM, 2*DI, DM, DM, 32, 16);
  // conv + silu -> u  (last reader of the xb-half of xz)
  conv_silu_kern<<<(MM*DI/4)/256, blk, 0, stream>>>(xz, conv_w, conv_b, u);
  // G2: params = u @ W_x  [2048 x 96, K=2048]  (fp32, K-split + reduce)
  xproj_part_kern<<<64*XSPLIT, blk, 0, stream>>>(u, W_x, xpart);
  xproj_reduce_kern<<<(MM*96/4)/256, blk, 0, stream>>>(xpart, params);
  // G3: delta = softplus(dlt @ W_dt + b_dt)  [2048 x 2048, K=64]  (fp32 one-pass)
  dtproj_kern<<<1024, blk, 0, stream>>>(params, W_dt, b_dt, delta);
  // chunked scan, NC=32 (y written as bf16 to yb16)
  scan_local_kern<<<(NB*NC*DI*4)/256, blk, 0, stream>>>(delta, u, params, A_log, Pc, Fc);
  scan_combine_kern<<<(NB*DI*DS)/256, blk, 0, stream>>>(Pc, Fc);
  scan_apply_kern<<<(NB*NC*DI*4)/256, blk, 0, stream>>>(delta, u, params, xz, A_log, D_par, Pc, yb16);
  // G4: out = y @ W_out  [2048 x 1024, K=2048]  (MFMA, 8-wave, split-K=4 -> reduce)
  transpose_cvt_kern<<<dim3(DM/32, DI/32), blk, 0, stream>>>(W_out, Wo_t, DI, DM);
  gemm_mfma_kern<<<512, blk512, 0, stream>>>(yb16, Wo_t, g4part, MM, DM, DI, DI/4, 8, 16);
  reduce4_kern<<<(MM*DM/4)/256, blk, 0, stream>>>(g4part, out);
}